// Round 4
// baseline (679.704 us; speedup 1.0000x reference)
//
#include <hip/hip_runtime.h>

#define CC    48
#define HH    160
#define WWID  160
#define NPIX  25600
#define KK    8

typedef unsigned short u16;

// ws float-offset layout
#define OFF_B0    0        // 48
#define OFF_BK    48       // 12
#define OFF_WKT   60       // 576    wkt[c*12+r] = Wk[r][c]
#define OFF_WRT   636      // 9216   wrt[cp*192 + i] = WR[i][cp]
#define OFF_WLT   9852     // 9216   wlt[cp*192 + i] = WL[i][cp]
#define OFF_SQP   19068    // 25600  ||h[:,p]||^2
#define OFF_EDGE  44668    // int[204800]
#define OFF_S2E   249468   // float[204800]  ||label||^2 per edge
#define OFF_W0V   454268   // float[25600*48]  W0 @ h[:,p]
#define OFF_VT    1683068  // float[25600*192] (aliases PARTD/PARTI; written after merge)
#define OFF_PARTD 1683068  // float[25600*64]
#define OFF_PARTI 3321468  // u16[25600*64]
// high-water: 6,598,268 floats = 25.2 MB

__global__ void prep_kernel(const float* b0, const float* WL, const float* WR,
                            const float* Wk, const float* bk, float* ws) {
    float* b0f  = ws + OFF_B0;
    float* bkf  = ws + OFF_BK;
    float* wkt  = ws + OFF_WKT;
    float* wrt  = ws + OFF_WRT;
    float* wlt  = ws + OFF_WLT;
    int t = blockIdx.x * 256 + threadIdx.x;
    int stride = gridDim.x * 256;
    for (int i = t; i < 9216; i += stride) {
        int cp = i / 192, r = i % 192;
        wrt[i] = WR[r*48 + cp];
        wlt[i] = WL[r*48 + cp];
    }
    for (int i = t; i < 576; i += stride) { int c = i / 12, r = i % 12; wkt[i] = Wk[r*48 + c]; }
    for (int i = t; i < 48; i += stride) { b0f[i] = b0[i]; }
    for (int i = t; i < 12; i += stride) { bkf[i] = bk[i]; }
}

// per-pixel: sq[p] = ||h_p||^2,  W0V[p][o] = sum_c W0[o][c] h[c][p]
__global__ __launch_bounds__(256) void pix_pre(const float* h, const float* W0,
                                               float* w0v, float* sqp) {
    int p = blockIdx.x * 256 + threadIdx.x;
    float f[48];
    float sq = 0.f;
    #pragma unroll
    for (int c = 0; c < 48; c++) { f[c] = h[c*NPIX + p]; sq = fmaf(f[c], f[c], sq); }
    sqp[p] = sq;
    for (int o = 0; o < 48; o++) {
        const float* wr = W0 + o*48;
        float a0 = 0.f, a1 = 0.f, a2 = 0.f, a3 = 0.f;
        #pragma unroll
        for (int c4 = 0; c4 < 12; c4++) {
            a0 = fmaf(wr[c4*4+0], f[c4*4+0], a0);
            a1 = fmaf(wr[c4*4+1], f[c4*4+1], a1);
            a2 = fmaf(wr[c4*4+2], f[c4*4+2], a2);
            a3 = fmaf(wr[c4*4+3], f[c4*4+3], a3);
        }
        w0v[(long)p*48 + o] = (a0 + a1) + (a2 + a3);
    }
}

// per-pixel: VT[p][cp*4+q] = sum_c h[c][p] * WR[4c+q][cp]
__global__ __launch_bounds__(256) void vt_pre(const float* h, const float* ws, float* vt) {
    const float* wrt = ws + OFF_WRT;
    int p = blockIdx.x * 256 + threadIdx.x;
    float f[48];
    #pragma unroll
    for (int c = 0; c < 48; c++) f[c] = h[c*NPIX + p];
    float* vrow = vt + (long)p * 192;
    for (int cp = 0; cp < 48; cp++) {
        const float* wr = wrt + cp * 192;
        float v0 = 0.f, v1 = 0.f, v2 = 0.f, v3 = 0.f;
        #pragma unroll
        for (int c = 0; c < 48; c++) {
            float vc = f[c];
            v0 = fmaf(wr[4*c+0], vc, v0);
            v1 = fmaf(wr[4*c+1], vc, v1);
            v2 = fmaf(wr[4*c+2], vc, v2);
            v3 = fmaf(wr[4*c+3], vc, v3);
        }
        float4 o4 = make_float4(v0, v1, v2, v3);
        *(float4*)&vrow[cp*4] = o4;
    }
}

// ---- topk stage 1: per (window, 256-pixel group, 128-candidate chunk) partial top8 ----
__global__ __launch_bounds__(128) void topk_part(const float* h, float* part_d, u16* part_i) {
    __shared__ float fs[128][52];
    __shared__ float sqs[128];
    int b   = blockIdx.x;
    int ch  = b & 7;
    int pg  = (b >> 3) & 3;
    int win = b >> 5;
    int wi = win / 5, wj = win % 5;
    int tid = threadIdx.x;

    int ml = ch * 128 + tid;
    int mg = (wi*32 + (ml >> 5)) * WWID + (wj*32 + (ml & 31));
    {
        float s = 0.f;
        #pragma unroll
        for (int c = 0; c < 48; c++) {
            float v = h[c*NPIX + mg];
            fs[tid][c] = v;
            s += v * v;
        }
        sqs[tid] = s;
    }
    __syncthreads();

    int nl0 = pg * 256 + tid * 2;
    int rn = nl0 >> 5, cn0 = nl0 & 31;
    int n0 = (wi*32 + rn) * WWID + (wj*32 + cn0);
    float f0[48], f1[48];
    #pragma unroll
    for (int c = 0; c < 48; c++) { f0[c] = h[c*NPIX + n0]; f1[c] = h[c*NPIX + n0 + 1]; }

    float d80[8], d81[8]; int i80[8], i81[8];
    #pragma unroll
    for (int s = 0; s < 8; s++) { d80[s] = 3.0e38f; d81[s] = 3.0e38f; i80[s] = 0; i81[s] = 0; }
    float w0 = 3.0e38f, w1 = 3.0e38f;

    for (int j = 0; j < 128; j++) {
        int mlj = ch * 128 + j;
        int rm = mlj >> 5, cm = mlj & 31;
        float a0 = 0.f, a1 = 0.f, a2 = 0.f, a3 = 0.f;
        float b0_ = 0.f, b1_ = 0.f, b2_ = 0.f, b3_ = 0.f;
        #pragma unroll
        for (int c4 = 0; c4 < 12; c4++) {
            float4 q = *(const float4*)&fs[j][c4*4];
            a0 = fmaf(f0[c4*4+0], q.x, a0); a1 = fmaf(f0[c4*4+1], q.y, a1);
            a2 = fmaf(f0[c4*4+2], q.z, a2); a3 = fmaf(f0[c4*4+3], q.w, a3);
            b0_ = fmaf(f1[c4*4+0], q.x, b0_); b1_ = fmaf(f1[c4*4+1], q.y, b1_);
            b2_ = fmaf(f1[c4*4+2], q.z, b2_); b3_ = fmaf(f1[c4*4+3], q.w, b3_);
        }
        float sq = sqs[j];
        float d0 = sq - 2.f * ((a0 + a1) + (a2 + a3));
        float d1 = sq - 2.f * ((b0_ + b1_) + (b2_ + b3_));
        int dr = rn - rm; dr = dr < 0 ? -dr : dr;
        int dc0 = cn0 - cm; dc0 = dc0 < 0 ? -dc0 : dc0;
        int dc1 = cn0 + 1 - cm; dc1 = dc1 < 0 ? -dc1 : dc1;
        bool ok0 = !(dr <= 1 && dc0 <= 1);
        bool ok1 = !(dr <= 1 && dc1 <= 1);
        if (ok0 && d0 < w0) {
            bool done = false;
            #pragma unroll
            for (int s = 0; s < 8; s++) {
                bool hit = (!done) && (d80[s] == w0);
                if (hit) { d80[s] = d0; i80[s] = mlj; done = true; }
            }
            w0 = d80[0];
            #pragma unroll
            for (int s = 1; s < 8; s++) w0 = fmaxf(w0, d80[s]);
        }
        if (ok1 && d1 < w1) {
            bool done = false;
            #pragma unroll
            for (int s = 0; s < 8; s++) {
                bool hit = (!done) && (d81[s] == w1);
                if (hit) { d81[s] = d1; i81[s] = mlj; done = true; }
            }
            w1 = d81[0];
            #pragma unroll
            for (int s = 1; s < 8; s++) w1 = fmaxf(w1, d81[s]);
        }
    }

    long base0 = (long)n0 * 64 + ch * 8;
    long base1 = (long)(n0 + 1) * 64 + ch * 8;
    #pragma unroll
    for (int s = 0; s < 8; s++) {
        part_d[base0 + s] = d80[s];
        part_i[base0 + s] = (u16)i80[s];
        part_d[base1 + s] = d81[s];
        part_i[base1 + s] = (u16)i81[s];
    }
}

// ---- topk stage 2: merge 8x8 -> top8; emit global edge idx + exact ||label||^2 ----
__global__ __launch_bounds__(256) void topk_merge(const float* part_d, const u16* part_i,
                                                  const float* sqp, int* edge, float* s2e) {
    int n = blockIdx.x * 256 + threadIdx.x;
    const float* pd = part_d + (long)n * 64;
    const u16*   pi = part_i + (long)n * 64;
    float d8[8]; int i8[8];
    #pragma unroll
    for (int s = 0; s < 8; s++) { d8[s] = 3.0e38f; i8[s] = 0; }
    float dworst = 3.0e38f;
    for (int j = 0; j < 64; j++) {
        float d = pd[j];
        if (d < dworst) {
            int idx = (int)pi[j];
            bool done = false;
            #pragma unroll
            for (int s = 0; s < 8; s++) {
                bool hit = (!done) && (d8[s] == dworst);
                if (hit) { d8[s] = d; i8[s] = idx; done = true; }
            }
            dworst = d8[0];
            #pragma unroll
            for (int s = 1; s < 8; s++) dworst = fmaxf(dworst, d8[s]);
        }
    }
    int y = n / WWID, x = n % WWID;
    int wy = (y >> 5) << 5, wx = (x >> 5) << 5;
    float sqn = sqp[n];
    #pragma unroll
    for (int s = 0; s < 8; s++) {
        int ml = i8[s];
        edge[n*8 + s] = (wy + (ml >> 5)) * WWID + (wx + (ml & 31));
        s2e[n*8 + s] = d8[s] + sqn;     // ||m||^2 - 2<m,n> + ||n||^2
    }
}

// ---------------- ecc: one lane per edge; writes 0.5*hNL into d_out ----------------
__global__ __launch_bounds__(128) void ecc_kernel(const float* ws, const int* edge,
                                                  const float* s2e, float* outp) {
    const float* b0f = ws + OFF_B0;
    const float* bkf = ws + OFF_BK;
    const float* wkt = ws + OFF_WKT;
    const float* wlt = ws + OFF_WLT;
    const float* w0v = ws + OFF_W0V;
    const float* vt  = ws + OFF_VT;

    __shared__ float th_s[128][49];   // theta rows; reused as 16x49 out-staging at the end

    int tid = threadIdx.x;
    int gt = blockIdx.x * 128 + tid;  // edge id = n*8+k
    int n = gt >> 3;
    int m = edge[gt];

    // theta = LReLU(W0V[m] - W0V[n] + b0)
    const float* wm = w0v + (long)m * 48;
    const float* wn = w0v + (long)n * 48;
    #pragma unroll
    for (int o = 0; o < 48; o++) {
        float x = wm[o] - wn[o] + b0f[o];
        th_s[tid][o] = (x >= 0.f) ? x : 0.01f * x;
    }
    float gamma = expf(-s2e[gt] * 0.1f);

    // kappa = Wk @ theta + bk
    float kap[12];
    #pragma unroll
    for (int r = 0; r < 12; r++) kap[r] = bkf[r];
    for (int c = 0; c < 48; c++) {
        float t = th_s[tid][c];
        const float* wkc = wkt + c*12;
        #pragma unroll
        for (int r = 0; r < 12; r++) kap[r] = fmaf(wkc[r], t, kap[r]);
    }

    // sR[3q+p] = sum_cp theta[(p+cp)%48] * VT[m][cp][q]
    float sr[12];
    #pragma unroll
    for (int r = 0; r < 12; r++) sr[r] = 0.f;
    const float* vrow = vt + (long)m * 192;
    for (int cp = 0; cp < 48; cp++) {
        float4 v4 = *(const float4*)&vrow[cp*4];
        int i1 = (cp + 1 < 48) ? cp + 1 : cp - 47;
        int i2 = (cp + 2 < 48) ? cp + 2 : cp - 46;
        float t0 = th_s[tid][cp], t1 = th_s[tid][i1], t2 = th_s[tid][i2];
        sr[0] = fmaf(t0, v4.x, sr[0]); sr[1]  = fmaf(t1, v4.x, sr[1]);  sr[2]  = fmaf(t2, v4.x, sr[2]);
        sr[3] = fmaf(t0, v4.y, sr[3]); sr[4]  = fmaf(t1, v4.y, sr[4]);  sr[5]  = fmaf(t2, v4.y, sr[5]);
        sr[6] = fmaf(t0, v4.z, sr[6]); sr[7]  = fmaf(t1, v4.z, sr[7]);  sr[8]  = fmaf(t2, v4.z, sr[8]);
        sr[9] = fmaf(t0, v4.w, sr[9]); sr[10] = fmaf(t1, v4.w, sr[10]); sr[11] = fmaf(t2, v4.w, sr[11]);
    }

    float tmp[12];
    #pragma unroll
    for (int r = 0; r < 12; r++) tmp[r] = kap[r] * sr[r];

    // out[o] = sum_cp sum_q WL[4o+q][cp] * U_q[cp],  U_q[cp] = sum_p tmp[3q+p]*theta[(p+cp)%48]
    float out[48];
    #pragma unroll
    for (int o = 0; o < 48; o++) out[o] = 0.f;
    for (int cp = 0; cp < 48; cp++) {
        int i1 = (cp + 1 < 48) ? cp + 1 : cp - 47;
        int i2 = (cp + 2 < 48) ? cp + 2 : cp - 46;
        float t0 = th_s[tid][cp], t1 = th_s[tid][i1], t2 = th_s[tid][i2];
        float u0 = tmp[0]*t0 + tmp[1]*t1 + tmp[2]*t2;
        float u1 = tmp[3]*t0 + tmp[4]*t1 + tmp[5]*t2;
        float u2 = tmp[6]*t0 + tmp[7]*t1 + tmp[8]*t2;
        float u3 = tmp[9]*t0 + tmp[10]*t1 + tmp[11]*t2;
        const float* wl = wlt + cp * 192;
        #pragma unroll
        for (int o = 0; o < 48; o++) {
            float a = out[o];
            a = fmaf(wl[4*o+0], u0, a);
            a = fmaf(wl[4*o+1], u1, a);
            a = fmaf(wl[4*o+2], u2, a);
            a = fmaf(wl[4*o+3], u3, a);
            out[o] = a;
        }
    }

    // gamma scale + k-reduction (8 lanes per pixel)
    #pragma unroll
    for (int o = 0; o < 48; o++) {
        float w = gamma * out[o];
        w += __shfl_xor(w, 1, 64);
        w += __shfl_xor(w, 2, 64);
        w += __shfl_xor(w, 4, 64);
        out[o] = w;
    }

    // LDS transpose -> coalesced 64B-line stores (16 consecutive pixels per channel)
    __syncthreads();
    float* ob = &th_s[0][0];
    int pix = tid >> 3;
    if ((tid & 7) == 0) {
        #pragma unroll
        for (int o = 0; o < 48; o++) ob[pix*49 + o] = 0.0625f * out[o];  // 0.5 * (1/8)
    }
    __syncthreads();
    int nb = (blockIdx.x * 128) >> 3;      // first of the block's 16 pixels
    int px = tid & 15, cb = tid >> 4;      // cb 0..7
    #pragma unroll
    for (int j = 0; j < 6; j++) {
        int chn = cb + 8*j;
        outp[chn*NPIX + nb + px] = ob[px*49 + chn];
    }
}

// ---------------- conv 3x3 (reflect pad), adds 0.5*hL + bias into d_out ----------------
__global__ __launch_bounds__(256) void conv_kernel(const float* h, const float* wc,
                                                   const float* bias, float* outp) {
    int o  = blockIdx.x / 40;
    int yg = blockIdx.x % 40;
    int ty = threadIdx.x >> 6;
    int tx = threadIdx.x & 63;
    int y = yg * 4 + ty;
    const float* wo = wc + o * 432;
    float bo = bias[o];
    for (int xb = 0; xb < 3; xb++) {
        int x = xb * 64 + tx;
        if (x < WWID) {
            float acc = 0.f;
            for (int c = 0; c < 48; c++) {
                const float* hc = h + c * NPIX;
                #pragma unroll
                for (int dy = 0; dy < 3; dy++) {
                    int yy = y + dy - 1;
                    yy = yy < 0 ? -yy : (yy >= HH ? 2*HH - 2 - yy : yy);
                    const float* hr = hc + yy * WWID;
                    const float* w3 = wo + c*9 + dy*3;
                    #pragma unroll
                    for (int dx = 0; dx < 3; dx++) {
                        int xx = x + dx - 1;
                        xx = xx < 0 ? -xx : (xx >= WWID ? 2*WWID - 2 - xx : xx);
                        acc = fmaf(hr[xx], w3[dx], acc);
                    }
                }
            }
            int idx = o * NPIX + y * WWID + x;
            outp[idx] = outp[idx] + 0.5f * acc + bo;
        }
    }
}

extern "C" void kernel_launch(void* const* d_in, const int* in_sizes, int n_in,
                              void* d_out, int out_size, void* d_ws, size_t ws_size,
                              hipStream_t stream) {
    const float* h    = (const float*)d_in[0];
    const float* W0   = (const float*)d_in[1];
    const float* b0   = (const float*)d_in[2];
    const float* WL   = (const float*)d_in[3];
    const float* WR   = (const float*)d_in[4];
    const float* Wk   = (const float*)d_in[5];
    const float* bk   = (const float*)d_in[6];
    const float* Wc   = (const float*)d_in[7];
    const float* bias = (const float*)d_in[8];

    float* ws     = (float*)d_ws;
    float* sqp    = ws + OFF_SQP;
    int*   edge   = (int*)(ws + OFF_EDGE);
    float* s2e    = ws + OFF_S2E;
    float* w0v    = ws + OFF_W0V;
    float* vt     = ws + OFF_VT;
    float* part_d = ws + OFF_PARTD;
    u16*   part_i = (u16*)(ws + OFF_PARTI);
    float* outp   = (float*)d_out;

    prep_kernel<<<dim3(16), dim3(256), 0, stream>>>(b0, WL, WR, Wk, bk, ws);
    pix_pre<<<dim3(100), dim3(256), 0, stream>>>(h, W0, w0v, sqp);
    topk_part<<<dim3(800), dim3(128), 0, stream>>>(h, part_d, part_i);
    topk_merge<<<dim3(100), dim3(256), 0, stream>>>(part_d, part_i, sqp, edge, s2e);
    vt_pre<<<dim3(100), dim3(256), 0, stream>>>(h, ws, vt);   // overwrites part region
    ecc_kernel<<<dim3(1600), dim3(128), 0, stream>>>(ws, edge, s2e, outp);
    conv_kernel<<<dim3(1920), dim3(256), 0, stream>>>(h, Wc, bias, outp);
}

// Round 5
// 540.938 us; speedup vs baseline: 1.2565x; 1.2565x over previous
//
#include <hip/hip_runtime.h>

#define CC    48
#define HH    160
#define WWID  160
#define NPIX  25600
#define KK    8

typedef unsigned short u16;

// ws float-offset layout
#define OFF_B0    0        // 48
#define OFF_BK    48       // 12
#define OFF_WKT   60       // 576    wkt[c*12+r] = Wk[r][c]
#define OFF_WRT   636      // 9216   wrt[cp*192 + i] = WR[i][cp]
#define OFF_WLT   9852     // 9216   wlt[cp*192 + i] = WL[i][cp]
#define OFF_SQP   19068    // 25600  ||h[:,p]||^2
#define OFF_EDGE  44668    // int[204800]
#define OFF_S2E   249468   // float[204800]  ||label||^2 per edge
#define OFF_W0V   454268   // float[25600*48]  W0 @ h[:,p]
#define OFF_VT    1683068  // float[25600*192] (aliases PARTD/PARTI; written after merge)
#define OFF_PARTD 1683068  // float[25600*64]
#define OFF_PARTI 3321468  // u16[25600*64]
// high-water: 6,598,268 floats = 25.2 MB

__global__ void prep_kernel(const float* b0, const float* WL, const float* WR,
                            const float* Wk, const float* bk, float* ws) {
    float* b0f  = ws + OFF_B0;
    float* bkf  = ws + OFF_BK;
    float* wkt  = ws + OFF_WKT;
    float* wrt  = ws + OFF_WRT;
    float* wlt  = ws + OFF_WLT;
    int t = blockIdx.x * 256 + threadIdx.x;
    int stride = gridDim.x * 256;
    for (int i = t; i < 9216; i += stride) {
        int cp = i / 192, r = i % 192;
        wrt[i] = WR[r*48 + cp];
        wlt[i] = WL[r*48 + cp];
    }
    for (int i = t; i < 576; i += stride) { int c = i / 12, r = i % 12; wkt[i] = Wk[r*48 + c]; }
    for (int i = t; i < 48; i += stride) { b0f[i] = b0[i]; }
    for (int i = t; i < 12; i += stride) { bkf[i] = bk[i]; }
}

// per-pixel: sq[p] = ||h_p||^2,  W0V[p][o] = sum_c W0[o][c] h[c][p]
__global__ __launch_bounds__(256) void pix_pre(const float* h, const float* W0,
                                               float* w0v, float* sqp) {
    int p = blockIdx.x * 256 + threadIdx.x;
    float f[48];
    float sq = 0.f;
    #pragma unroll
    for (int c = 0; c < 48; c++) { f[c] = h[c*NPIX + p]; sq = fmaf(f[c], f[c], sq); }
    sqp[p] = sq;
    for (int o = 0; o < 48; o++) {
        const float* wr = W0 + o*48;
        float a0 = 0.f, a1 = 0.f, a2 = 0.f, a3 = 0.f;
        #pragma unroll
        for (int c4 = 0; c4 < 12; c4++) {
            a0 = fmaf(wr[c4*4+0], f[c4*4+0], a0);
            a1 = fmaf(wr[c4*4+1], f[c4*4+1], a1);
            a2 = fmaf(wr[c4*4+2], f[c4*4+2], a2);
            a3 = fmaf(wr[c4*4+3], f[c4*4+3], a3);
        }
        w0v[(long)p*48 + o] = (a0 + a1) + (a2 + a3);
    }
}

// per-pixel: VT[p][cp*4+q] = sum_c h[c][p] * WR[4c+q][cp]
__global__ __launch_bounds__(256) void vt_pre(const float* h, const float* ws, float* vt) {
    const float* wrt = ws + OFF_WRT;
    int p = blockIdx.x * 256 + threadIdx.x;
    float f[48];
    #pragma unroll
    for (int c = 0; c < 48; c++) f[c] = h[c*NPIX + p];
    float* vrow = vt + (long)p * 192;
    for (int cp = 0; cp < 48; cp++) {
        const float* wr = wrt + cp * 192;
        float v0 = 0.f, v1 = 0.f, v2 = 0.f, v3 = 0.f;
        #pragma unroll
        for (int c = 0; c < 48; c++) {
            float vc = f[c];
            v0 = fmaf(wr[4*c+0], vc, v0);
            v1 = fmaf(wr[4*c+1], vc, v1);
            v2 = fmaf(wr[4*c+2], vc, v2);
            v3 = fmaf(wr[4*c+3], vc, v3);
        }
        float4 o4 = make_float4(v0, v1, v2, v3);
        *(float4*)&vrow[cp*4] = o4;
    }
}

// ---- topk stage 1: per (window, 256-pixel group, 128-candidate chunk) partial top8 ----
__global__ __launch_bounds__(128) void topk_part(const float* h, float* part_d, u16* part_i) {
    __shared__ float fs[128][52];
    __shared__ float sqs[128];
    int b   = blockIdx.x;
    int ch  = b & 7;
    int pg  = (b >> 3) & 3;
    int win = b >> 5;
    int wi = win / 5, wj = win % 5;
    int tid = threadIdx.x;

    int ml = ch * 128 + tid;
    int mg = (wi*32 + (ml >> 5)) * WWID + (wj*32 + (ml & 31));
    {
        float s = 0.f;
        #pragma unroll
        for (int c = 0; c < 48; c++) {
            float v = h[c*NPIX + mg];
            fs[tid][c] = v;
            s += v * v;
        }
        sqs[tid] = s;
    }
    __syncthreads();

    int nl0 = pg * 256 + tid * 2;
    int rn = nl0 >> 5, cn0 = nl0 & 31;
    int n0 = (wi*32 + rn) * WWID + (wj*32 + cn0);
    float f0[48], f1[48];
    #pragma unroll
    for (int c = 0; c < 48; c++) { f0[c] = h[c*NPIX + n0]; f1[c] = h[c*NPIX + n0 + 1]; }

    float d80[8], d81[8]; int i80[8], i81[8];
    #pragma unroll
    for (int s = 0; s < 8; s++) { d80[s] = 3.0e38f; d81[s] = 3.0e38f; i80[s] = 0; i81[s] = 0; }
    float w0 = 3.0e38f, w1 = 3.0e38f;

    for (int j = 0; j < 128; j++) {
        int mlj = ch * 128 + j;
        int rm = mlj >> 5, cm = mlj & 31;
        float a0 = 0.f, a1 = 0.f, a2 = 0.f, a3 = 0.f;
        float b0_ = 0.f, b1_ = 0.f, b2_ = 0.f, b3_ = 0.f;
        #pragma unroll
        for (int c4 = 0; c4 < 12; c4++) {
            float4 q = *(const float4*)&fs[j][c4*4];
            a0 = fmaf(f0[c4*4+0], q.x, a0); a1 = fmaf(f0[c4*4+1], q.y, a1);
            a2 = fmaf(f0[c4*4+2], q.z, a2); a3 = fmaf(f0[c4*4+3], q.w, a3);
            b0_ = fmaf(f1[c4*4+0], q.x, b0_); b1_ = fmaf(f1[c4*4+1], q.y, b1_);
            b2_ = fmaf(f1[c4*4+2], q.z, b2_); b3_ = fmaf(f1[c4*4+3], q.w, b3_);
        }
        float sq = sqs[j];
        float d0 = sq - 2.f * ((a0 + a1) + (a2 + a3));
        float d1 = sq - 2.f * ((b0_ + b1_) + (b2_ + b3_));
        int dr = rn - rm; dr = dr < 0 ? -dr : dr;
        int dc0 = cn0 - cm; dc0 = dc0 < 0 ? -dc0 : dc0;
        int dc1 = cn0 + 1 - cm; dc1 = dc1 < 0 ? -dc1 : dc1;
        bool ok0 = !(dr <= 1 && dc0 <= 1);
        bool ok1 = !(dr <= 1 && dc1 <= 1);
        if (ok0 && d0 < w0) {
            bool done = false;
            #pragma unroll
            for (int s = 0; s < 8; s++) {
                bool hit = (!done) && (d80[s] == w0);
                if (hit) { d80[s] = d0; i80[s] = mlj; done = true; }
            }
            w0 = d80[0];
            #pragma unroll
            for (int s = 1; s < 8; s++) w0 = fmaxf(w0, d80[s]);
        }
        if (ok1 && d1 < w1) {
            bool done = false;
            #pragma unroll
            for (int s = 0; s < 8; s++) {
                bool hit = (!done) && (d81[s] == w1);
                if (hit) { d81[s] = d1; i81[s] = mlj; done = true; }
            }
            w1 = d81[0];
            #pragma unroll
            for (int s = 1; s < 8; s++) w1 = fmaxf(w1, d81[s]);
        }
    }

    long base0 = (long)n0 * 64 + ch * 8;
    long base1 = (long)(n0 + 1) * 64 + ch * 8;
    #pragma unroll
    for (int s = 0; s < 8; s++) {
        part_d[base0 + s] = d80[s];
        part_i[base0 + s] = (u16)i80[s];
        part_d[base1 + s] = d81[s];
        part_i[base1 + s] = (u16)i81[s];
    }
}

// ---- topk stage 2: merge 8x8 -> top8; emit global edge idx + exact ||label||^2 ----
__global__ __launch_bounds__(256) void topk_merge(const float* part_d, const u16* part_i,
                                                  const float* sqp, int* edge, float* s2e) {
    int n = blockIdx.x * 256 + threadIdx.x;
    const float* pd = part_d + (long)n * 64;
    const u16*   pi = part_i + (long)n * 64;
    float d8[8]; int i8[8];
    #pragma unroll
    for (int s = 0; s < 8; s++) { d8[s] = 3.0e38f; i8[s] = 0; }
    float dworst = 3.0e38f;
    for (int j = 0; j < 64; j++) {
        float d = pd[j];
        if (d < dworst) {
            int idx = (int)pi[j];
            bool done = false;
            #pragma unroll
            for (int s = 0; s < 8; s++) {
                bool hit = (!done) && (d8[s] == dworst);
                if (hit) { d8[s] = d; i8[s] = idx; done = true; }
            }
            dworst = d8[0];
            #pragma unroll
            for (int s = 1; s < 8; s++) dworst = fmaxf(dworst, d8[s]);
        }
    }
    int y = n / WWID, x = n % WWID;
    int wy = (y >> 5) << 5, wx = (x >> 5) << 5;
    float sqn = sqp[n];
    #pragma unroll
    for (int s = 0; s < 8; s++) {
        int ml = i8[s];
        edge[n*8 + s] = (wy + (ml >> 5)) * WWID + (wx + (ml & 31));
        s2e[n*8 + s] = d8[s] + sqn;     // ||m||^2 - 2<m,n> + ||n||^2
    }
}

// ---------------- ecc: one lane per edge; writes 0.5*hNL into d_out ----------------
__global__ __launch_bounds__(128) void ecc_kernel(const float* ws, const int* edge,
                                                  const float* s2e, float* outp) {
    const float* b0f = ws + OFF_B0;
    const float* bkf = ws + OFF_BK;
    const float* wkt = ws + OFF_WKT;
    const float* wlt = ws + OFF_WLT;
    const float* w0v = ws + OFF_W0V;
    const float* vt  = ws + OFF_VT;

    __shared__ float th_s[128][49];   // theta rows; reused as 16x49 out-staging at the end

    int tid = threadIdx.x;
    int gt = blockIdx.x * 128 + tid;  // edge id = n*8+k
    int n = gt >> 3;
    int m = edge[gt];

    // theta = LReLU(W0V[m] - W0V[n] + b0)
    const float* wm = w0v + (long)m * 48;
    const float* wn = w0v + (long)n * 48;
    #pragma unroll
    for (int o = 0; o < 48; o++) {
        float x = wm[o] - wn[o] + b0f[o];
        th_s[tid][o] = (x >= 0.f) ? x : 0.01f * x;
    }
    float gamma = expf(-s2e[gt] * 0.1f);

    // kappa = Wk @ theta + bk
    float kap[12];
    #pragma unroll
    for (int r = 0; r < 12; r++) kap[r] = bkf[r];
    for (int c = 0; c < 48; c++) {
        float t = th_s[tid][c];
        const float* wkc = wkt + c*12;
        #pragma unroll
        for (int r = 0; r < 12; r++) kap[r] = fmaf(wkc[r], t, kap[r]);
    }

    // sR[3q+p] = sum_cp theta[(p+cp)%48] * VT[m][cp][q]
    float sr[12];
    #pragma unroll
    for (int r = 0; r < 12; r++) sr[r] = 0.f;
    const float* vrow = vt + (long)m * 192;
    for (int cp = 0; cp < 48; cp++) {
        float4 v4 = *(const float4*)&vrow[cp*4];
        int i1 = (cp + 1 < 48) ? cp + 1 : cp - 47;
        int i2 = (cp + 2 < 48) ? cp + 2 : cp - 46;
        float t0 = th_s[tid][cp], t1 = th_s[tid][i1], t2 = th_s[tid][i2];
        sr[0] = fmaf(t0, v4.x, sr[0]); sr[1]  = fmaf(t1, v4.x, sr[1]);  sr[2]  = fmaf(t2, v4.x, sr[2]);
        sr[3] = fmaf(t0, v4.y, sr[3]); sr[4]  = fmaf(t1, v4.y, sr[4]);  sr[5]  = fmaf(t2, v4.y, sr[5]);
        sr[6] = fmaf(t0, v4.z, sr[6]); sr[7]  = fmaf(t1, v4.z, sr[7]);  sr[8]  = fmaf(t2, v4.z, sr[8]);
        sr[9] = fmaf(t0, v4.w, sr[9]); sr[10] = fmaf(t1, v4.w, sr[10]); sr[11] = fmaf(t2, v4.w, sr[11]);
    }

    float tmp[12];
    #pragma unroll
    for (int r = 0; r < 12; r++) tmp[r] = kap[r] * sr[r];

    // out[o] = sum_cp sum_q WL[4o+q][cp] * U_q[cp],  U_q[cp] = sum_p tmp[3q+p]*theta[(p+cp)%48]
    float out[48];
    #pragma unroll
    for (int o = 0; o < 48; o++) out[o] = 0.f;
    for (int cp = 0; cp < 48; cp++) {
        int i1 = (cp + 1 < 48) ? cp + 1 : cp - 47;
        int i2 = (cp + 2 < 48) ? cp + 2 : cp - 46;
        float t0 = th_s[tid][cp], t1 = th_s[tid][i1], t2 = th_s[tid][i2];
        float u0 = tmp[0]*t0 + tmp[1]*t1 + tmp[2]*t2;
        float u1 = tmp[3]*t0 + tmp[4]*t1 + tmp[5]*t2;
        float u2 = tmp[6]*t0 + tmp[7]*t1 + tmp[8]*t2;
        float u3 = tmp[9]*t0 + tmp[10]*t1 + tmp[11]*t2;
        const float* wl = wlt + cp * 192;
        #pragma unroll
        for (int o = 0; o < 48; o++) {
            float a = out[o];
            a = fmaf(wl[4*o+0], u0, a);
            a = fmaf(wl[4*o+1], u1, a);
            a = fmaf(wl[4*o+2], u2, a);
            a = fmaf(wl[4*o+3], u3, a);
            out[o] = a;
        }
    }

    // gamma scale + k-reduction (8 lanes per pixel)
    #pragma unroll
    for (int o = 0; o < 48; o++) {
        float w = gamma * out[o];
        w += __shfl_xor(w, 1, 64);
        w += __shfl_xor(w, 2, 64);
        w += __shfl_xor(w, 4, 64);
        out[o] = w;
    }

    // LDS transpose -> coalesced 64B-line stores (16 consecutive pixels per channel)
    __syncthreads();
    float* ob = &th_s[0][0];
    int pix = tid >> 3;
    if ((tid & 7) == 0) {
        #pragma unroll
        for (int o = 0; o < 48; o++) ob[pix*49 + o] = 0.0625f * out[o];  // 0.5 * (1/8)
    }
    __syncthreads();
    int nb = (blockIdx.x * 128) >> 3;      // first of the block's 16 pixels
    int px = tid & 15, cb = tid >> 4;      // cb 0..7
    #pragma unroll
    for (int j = 0; j < 6; j++) {
        int chn = cb + 8*j;
        outp[chn*NPIX + nb + px] = ob[px*49 + chn];
    }
}

// ---- conv 3x3 (reflect pad), 8 output channels per thread, adds 0.5*hL + bias ----
#define OCH 8
__global__ __launch_bounds__(320) void conv_kernel(const float* h, const float* wc,
                                                   const float* bias, float* outp) {
    int og = blockIdx.x % 6;          // output-channel group (6 x 8 = 48)
    int yp = blockIdx.x / 6;          // row-pair 0..79
    int t  = threadIdx.x;             // 0..319 = 2 rows x 160 px
    int ty = t / 160;
    int x  = t % 160;
    int y  = yp * 2 + ty;

    // 9 reflect-resolved flat indices (computed once per pixel)
    int idx9[9];
    #pragma unroll
    for (int dy = 0; dy < 3; dy++) {
        int yy = y + dy - 1;
        yy = yy < 0 ? -yy : (yy >= HH ? 2*HH - 2 - yy : yy);
        #pragma unroll
        for (int dx = 0; dx < 3; dx++) {
            int xx = x + dx - 1;
            xx = xx < 0 ? -xx : (xx >= WWID ? 2*WWID - 2 - xx : xx);
            idx9[dy*3 + dx] = yy * WWID + xx;
        }
    }

    float acc[OCH];
    #pragma unroll
    for (int oi = 0; oi < OCH; oi++) acc[oi] = 0.f;

    const float* wbase = wc + og * OCH * 432;   // [OCH][48][9], block-uniform -> s_load
    for (int c = 0; c < 48; c++) {
        float v[9];
        #pragma unroll
        for (int k = 0; k < 9; k++) v[k] = h[c*NPIX + idx9[k]];
        #pragma unroll
        for (int oi = 0; oi < OCH; oi++) {
            const float* w9 = wbase + oi*432 + c*9;
            float a = acc[oi];
            a = fmaf(v[0], w9[0], a);
            a = fmaf(v[1], w9[1], a);
            a = fmaf(v[2], w9[2], a);
            a = fmaf(v[3], w9[3], a);
            a = fmaf(v[4], w9[4], a);
            a = fmaf(v[5], w9[5], a);
            a = fmaf(v[6], w9[6], a);
            a = fmaf(v[7], w9[7], a);
            a = fmaf(v[8], w9[8], a);
            acc[oi] = a;
        }
    }

    int p = y * WWID + x;
    #pragma unroll
    for (int oi = 0; oi < OCH; oi++) {
        int o = og * OCH + oi;
        outp[o*NPIX + p] = outp[o*NPIX + p] + 0.5f * acc[oi] + bias[o];
    }
}

extern "C" void kernel_launch(void* const* d_in, const int* in_sizes, int n_in,
                              void* d_out, int out_size, void* d_ws, size_t ws_size,
                              hipStream_t stream) {
    const float* h    = (const float*)d_in[0];
    const float* W0   = (const float*)d_in[1];
    const float* b0   = (const float*)d_in[2];
    const float* WL   = (const float*)d_in[3];
    const float* WR   = (const float*)d_in[4];
    const float* Wk   = (const float*)d_in[5];
    const float* bk   = (const float*)d_in[6];
    const float* Wc   = (const float*)d_in[7];
    const float* bias = (const float*)d_in[8];

    float* ws     = (float*)d_ws;
    float* sqp    = ws + OFF_SQP;
    int*   edge   = (int*)(ws + OFF_EDGE);
    float* s2e    = ws + OFF_S2E;
    float* w0v    = ws + OFF_W0V;
    float* vt     = ws + OFF_VT;
    float* part_d = ws + OFF_PARTD;
    u16*   part_i = (u16*)(ws + OFF_PARTI);
    float* outp   = (float*)d_out;

    prep_kernel<<<dim3(16), dim3(256), 0, stream>>>(b0, WL, WR, Wk, bk, ws);
    pix_pre<<<dim3(100), dim3(256), 0, stream>>>(h, W0, w0v, sqp);
    topk_part<<<dim3(800), dim3(128), 0, stream>>>(h, part_d, part_i);
    topk_merge<<<dim3(100), dim3(256), 0, stream>>>(part_d, part_i, sqp, edge, s2e);
    vt_pre<<<dim3(100), dim3(256), 0, stream>>>(h, ws, vt);   // overwrites part region
    ecc_kernel<<<dim3(1600), dim3(128), 0, stream>>>(ws, edge, s2e, outp);
    conv_kernel<<<dim3(480), dim3(320), 0, stream>>>(h, Wc, bias, outp);
}

// Round 6
// 489.992 us; speedup vs baseline: 1.3872x; 1.1040x over previous
//
#include <hip/hip_runtime.h>

#define CC    48
#define HH    160
#define WWID  160
#define NPIX  25600
#define KK    8

typedef unsigned short u16;

__device__ __forceinline__ float bf2f(u16 u) {
    return __uint_as_float(((unsigned int)u) << 16);
}
__device__ __forceinline__ u16 f2bf(float f) {
    unsigned int x = __float_as_uint(f);
    return (u16)((x + 0x7FFFu + ((x >> 16) & 1u)) >> 16);
}

// ws float-offset layout (high-water 6,598,268 floats = 25.2 MB, same as proven)
#define OFF_B0    0        // 48
#define OFF_BK    48       // 12
#define OFF_WKT   60       // 576    wkt[c*12+r] = Wk[r][c]
#define OFF_WRT   636      // 9216   wrt[cp*192 + i] = WR[i][cp]
#define OFF_WLT   9852     // 9216   wlt[cp*192 + i] = WL[i][cp]
#define OFF_SQP   19068    // 25600
#define OFF_EDGE  44668    // int[204800]
#define OFF_S2E   249468   // float[204800]
#define OFF_W0V   454268   // float[25600*48]
#define OFF_VTB   1683068  // u16[25600*192] bf16 (aliases PART; written after merge)
#define OFF_PARTD 1683068  // float[25600*64]
#define OFF_PARTI 3321468  // u16[25600*64]
#define OFF_UBAR  4140668  // u16[25600*192] bf16 (after part region)

__global__ void prep_kernel(const float* b0, const float* WL, const float* WR,
                            const float* Wk, const float* bk, float* ws) {
    float* b0f  = ws + OFF_B0;
    float* bkf  = ws + OFF_BK;
    float* wkt  = ws + OFF_WKT;
    float* wrt  = ws + OFF_WRT;
    float* wlt  = ws + OFF_WLT;
    int t = blockIdx.x * 256 + threadIdx.x;
    int stride = gridDim.x * 256;
    for (int i = t; i < 9216; i += stride) {
        int cp = i / 192, r = i % 192;
        wrt[i] = WR[r*48 + cp];
        wlt[i] = WL[r*48 + cp];
    }
    for (int i = t; i < 576; i += stride) { int c = i / 12, r = i % 12; wkt[i] = Wk[r*48 + c]; }
    for (int i = t; i < 48; i += stride) { b0f[i] = b0[i]; }
    for (int i = t; i < 12; i += stride) { bkf[i] = bk[i]; }
}

// per-pixel: sq[p] = ||h_p||^2,  W0V[p][o] = sum_c W0[o][c] h[c][p]
__global__ __launch_bounds__(256) void pix_pre(const float* h, const float* W0,
                                               float* w0v, float* sqp) {
    int p = blockIdx.x * 256 + threadIdx.x;
    float f[48];
    float sq = 0.f;
    #pragma unroll
    for (int c = 0; c < 48; c++) { f[c] = h[c*NPIX + p]; sq = fmaf(f[c], f[c], sq); }
    sqp[p] = sq;
    for (int o = 0; o < 48; o++) {
        const float* wr = W0 + o*48;
        float a0 = 0.f, a1 = 0.f, a2 = 0.f, a3 = 0.f;
        #pragma unroll
        for (int c4 = 0; c4 < 12; c4++) {
            a0 = fmaf(wr[c4*4+0], f[c4*4+0], a0);
            a1 = fmaf(wr[c4*4+1], f[c4*4+1], a1);
            a2 = fmaf(wr[c4*4+2], f[c4*4+2], a2);
            a3 = fmaf(wr[c4*4+3], f[c4*4+3], a3);
        }
        w0v[(long)p*48 + o] = (a0 + a1) + (a2 + a3);
    }
}

// per-pixel: VT[p][cp*4+q] = sum_c h[c][p] * WR[4c+q][cp]  (stored bf16)
__global__ __launch_bounds__(256) void vt_pre(const float* h, const float* ws, u16* vtb) {
    const float* wrt = ws + OFF_WRT;
    int p = blockIdx.x * 256 + threadIdx.x;
    float f[48];
    #pragma unroll
    for (int c = 0; c < 48; c++) f[c] = h[c*NPIX + p];
    u16* vrow = vtb + (long)p * 192;
    for (int cp = 0; cp < 48; cp++) {
        const float* wr = wrt + cp * 192;
        float v0 = 0.f, v1 = 0.f, v2 = 0.f, v3 = 0.f;
        #pragma unroll
        for (int c = 0; c < 48; c++) {
            float vc = f[c];
            v0 = fmaf(wr[4*c+0], vc, v0);
            v1 = fmaf(wr[4*c+1], vc, v1);
            v2 = fmaf(wr[4*c+2], vc, v2);
            v3 = fmaf(wr[4*c+3], vc, v3);
        }
        ushort4 st;
        st.x = f2bf(v0); st.y = f2bf(v1); st.z = f2bf(v2); st.w = f2bf(v3);
        *(ushort4*)&vrow[cp*4] = st;
    }
}

// ---- topk stage 1 ----
__global__ __launch_bounds__(128) void topk_part(const float* h, float* part_d, u16* part_i) {
    __shared__ float fs[128][52];
    __shared__ float sqs[128];
    int b   = blockIdx.x;
    int ch  = b & 7;
    int pg  = (b >> 3) & 3;
    int win = b >> 5;
    int wi = win / 5, wj = win % 5;
    int tid = threadIdx.x;

    int ml = ch * 128 + tid;
    int mg = (wi*32 + (ml >> 5)) * WWID + (wj*32 + (ml & 31));
    {
        float s = 0.f;
        #pragma unroll
        for (int c = 0; c < 48; c++) {
            float v = h[c*NPIX + mg];
            fs[tid][c] = v;
            s += v * v;
        }
        sqs[tid] = s;
    }
    __syncthreads();

    int nl0 = pg * 256 + tid * 2;
    int rn = nl0 >> 5, cn0 = nl0 & 31;
    int n0 = (wi*32 + rn) * WWID + (wj*32 + cn0);
    float f0[48], f1[48];
    #pragma unroll
    for (int c = 0; c < 48; c++) { f0[c] = h[c*NPIX + n0]; f1[c] = h[c*NPIX + n0 + 1]; }

    float d80[8], d81[8]; int i80[8], i81[8];
    #pragma unroll
    for (int s = 0; s < 8; s++) { d80[s] = 3.0e38f; d81[s] = 3.0e38f; i80[s] = 0; i81[s] = 0; }
    float w0 = 3.0e38f, w1 = 3.0e38f;

    for (int j = 0; j < 128; j++) {
        int mlj = ch * 128 + j;
        int rm = mlj >> 5, cm = mlj & 31;
        float a0 = 0.f, a1 = 0.f, a2 = 0.f, a3 = 0.f;
        float b0_ = 0.f, b1_ = 0.f, b2_ = 0.f, b3_ = 0.f;
        #pragma unroll
        for (int c4 = 0; c4 < 12; c4++) {
            float4 q = *(const float4*)&fs[j][c4*4];
            a0 = fmaf(f0[c4*4+0], q.x, a0); a1 = fmaf(f0[c4*4+1], q.y, a1);
            a2 = fmaf(f0[c4*4+2], q.z, a2); a3 = fmaf(f0[c4*4+3], q.w, a3);
            b0_ = fmaf(f1[c4*4+0], q.x, b0_); b1_ = fmaf(f1[c4*4+1], q.y, b1_);
            b2_ = fmaf(f1[c4*4+2], q.z, b2_); b3_ = fmaf(f1[c4*4+3], q.w, b3_);
        }
        float sq = sqs[j];
        float d0 = sq - 2.f * ((a0 + a1) + (a2 + a3));
        float d1 = sq - 2.f * ((b0_ + b1_) + (b2_ + b3_));
        int dr = rn - rm; dr = dr < 0 ? -dr : dr;
        int dc0 = cn0 - cm; dc0 = dc0 < 0 ? -dc0 : dc0;
        int dc1 = cn0 + 1 - cm; dc1 = dc1 < 0 ? -dc1 : dc1;
        bool ok0 = !(dr <= 1 && dc0 <= 1);
        bool ok1 = !(dr <= 1 && dc1 <= 1);
        if (ok0 && d0 < w0) {
            bool done = false;
            #pragma unroll
            for (int s = 0; s < 8; s++) {
                bool hit = (!done) && (d80[s] == w0);
                if (hit) { d80[s] = d0; i80[s] = mlj; done = true; }
            }
            w0 = d80[0];
            #pragma unroll
            for (int s = 1; s < 8; s++) w0 = fmaxf(w0, d80[s]);
        }
        if (ok1 && d1 < w1) {
            bool done = false;
            #pragma unroll
            for (int s = 0; s < 8; s++) {
                bool hit = (!done) && (d81[s] == w1);
                if (hit) { d81[s] = d1; i81[s] = mlj; done = true; }
            }
            w1 = d81[0];
            #pragma unroll
            for (int s = 1; s < 8; s++) w1 = fmaxf(w1, d81[s]);
        }
    }

    long base0 = (long)n0 * 64 + ch * 8;
    long base1 = (long)(n0 + 1) * 64 + ch * 8;
    #pragma unroll
    for (int s = 0; s < 8; s++) {
        part_d[base0 + s] = d80[s];
        part_i[base0 + s] = (u16)i80[s];
        part_d[base1 + s] = d81[s];
        part_i[base1 + s] = (u16)i81[s];
    }
}

// ---- topk stage 2 ----
__global__ __launch_bounds__(256) void topk_merge(const float* part_d, const u16* part_i,
                                                  const float* sqp, int* edge, float* s2e) {
    int n = blockIdx.x * 256 + threadIdx.x;
    const float* pd = part_d + (long)n * 64;
    const u16*   pi = part_i + (long)n * 64;
    float d8[8]; int i8[8];
    #pragma unroll
    for (int s = 0; s < 8; s++) { d8[s] = 3.0e38f; i8[s] = 0; }
    float dworst = 3.0e38f;
    for (int j = 0; j < 64; j++) {
        float d = pd[j];
        if (d < dworst) {
            int idx = (int)pi[j];
            bool done = false;
            #pragma unroll
            for (int s = 0; s < 8; s++) {
                bool hit = (!done) && (d8[s] == dworst);
                if (hit) { d8[s] = d; i8[s] = idx; done = true; }
            }
            dworst = d8[0];
            #pragma unroll
            for (int s = 1; s < 8; s++) dworst = fmaxf(dworst, d8[s]);
        }
    }
    int y = n / WWID, x = n % WWID;
    int wy = (y >> 5) << 5, wx = (x >> 5) << 5;
    float sqn = sqp[n];
    #pragma unroll
    for (int s = 0; s < 8; s++) {
        int ml = i8[s];
        edge[n*8 + s] = (wy + (ml >> 5)) * WWID + (wx + (ml & 31));
        s2e[n*8 + s] = d8[s] + sqn;
    }
}

// ---- ecc: per edge up to tmp; per-pixel Ubar = sum_k gamma_k U_k (bf16 out) ----
__global__ __launch_bounds__(128) void ecc_kernel(const float* ws, const int* edge,
                                                  const float* s2e, const u16* vtb,
                                                  u16* ubar) {
    const float* b0f = ws + OFF_B0;
    const float* bkf = ws + OFF_BK;
    const float* wkt = ws + OFF_WKT;
    const float* w0v = ws + OFF_W0V;

    __shared__ float th_s[128][49];
    __shared__ float tg_s[128][13];   // tmp[12] + gamma

    int tid = threadIdx.x;
    int gt = blockIdx.x * 128 + tid;  // edge id = n*8+k
    int n = gt >> 3;
    int m = edge[gt];

    // theta = LReLU(W0V[m] - W0V[n] + b0)
    const float* wm = w0v + (long)m * 48;
    const float* wn = w0v + (long)n * 48;
    #pragma unroll
    for (int o = 0; o < 48; o++) {
        float x = wm[o] - wn[o] + b0f[o];
        th_s[tid][o] = (x >= 0.f) ? x : 0.01f * x;
    }
    float gamma = expf(-s2e[gt] * 0.1f);

    // kappa = Wk @ theta + bk
    float kap[12];
    #pragma unroll
    for (int r = 0; r < 12; r++) kap[r] = bkf[r];
    for (int c = 0; c < 48; c++) {
        float t = th_s[tid][c];
        const float* wkc = wkt + c*12;
        #pragma unroll
        for (int r = 0; r < 12; r++) kap[r] = fmaf(wkc[r], t, kap[r]);
    }

    // sR[3q+p] = sum_cp theta[(p+cp)%48] * VT[m][cp][q]   (VT bf16)
    float sr[12];
    #pragma unroll
    for (int r = 0; r < 12; r++) sr[r] = 0.f;
    const u16* vrow = vtb + (long)m * 192;
    for (int cp = 0; cp < 48; cp++) {
        uint2 vv = *(const uint2*)&vrow[cp*4];
        float vx = bf2f((u16)(vv.x & 0xffff));
        float vy = bf2f((u16)(vv.x >> 16));
        float vz = bf2f((u16)(vv.y & 0xffff));
        float vw = bf2f((u16)(vv.y >> 16));
        int i1 = (cp + 1 < 48) ? cp + 1 : cp - 47;
        int i2 = (cp + 2 < 48) ? cp + 2 : cp - 46;
        float t0 = th_s[tid][cp], t1 = th_s[tid][i1], t2 = th_s[tid][i2];
        sr[0] = fmaf(t0, vx, sr[0]); sr[1]  = fmaf(t1, vx, sr[1]);  sr[2]  = fmaf(t2, vx, sr[2]);
        sr[3] = fmaf(t0, vy, sr[3]); sr[4]  = fmaf(t1, vy, sr[4]);  sr[5]  = fmaf(t2, vy, sr[5]);
        sr[6] = fmaf(t0, vz, sr[6]); sr[7]  = fmaf(t1, vz, sr[7]);  sr[8]  = fmaf(t2, vz, sr[8]);
        sr[9] = fmaf(t0, vw, sr[9]); sr[10] = fmaf(t1, vw, sr[10]); sr[11] = fmaf(t2, vw, sr[11]);
    }

    #pragma unroll
    for (int r = 0; r < 12; r++) tg_s[tid][r] = kap[r] * sr[r];
    tg_s[tid][12] = gamma;
    __syncthreads();

    // phase B: lane (pix, sh) accumulates Ubar for cps {sh, sh+8, ..., sh+40}
    int pix = tid >> 3, sh = tid & 7;
    float acc0[6], acc1[6], acc2[6], acc3[6];
    #pragma unroll
    for (int j = 0; j < 6; j++) { acc0[j] = 0.f; acc1[j] = 0.f; acc2[j] = 0.f; acc3[j] = 0.f; }
    #pragma unroll 1
    for (int e = 0; e < 8; e++) {
        int row = pix * 8 + e;
        float tm[12];
        #pragma unroll
        for (int r = 0; r < 12; r++) tm[r] = tg_s[row][r];
        float ge = tg_s[row][12];
        #pragma unroll
        for (int j = 0; j < 6; j++) {
            int cp = sh + 8*j;
            int i1 = (cp + 1 < 48) ? cp + 1 : cp - 47;
            int i2 = (cp + 2 < 48) ? cp + 2 : cp - 46;
            float t0 = th_s[row][cp], t1 = th_s[row][i1], t2 = th_s[row][i2];
            float u0 = tm[0]*t0 + tm[1]*t1 + tm[2]*t2;
            float u1 = tm[3]*t0 + tm[4]*t1 + tm[5]*t2;
            float u2 = tm[6]*t0 + tm[7]*t1 + tm[8]*t2;
            float u3 = tm[9]*t0 + tm[10]*t1 + tm[11]*t2;
            acc0[j] = fmaf(ge, u0, acc0[j]);
            acc1[j] = fmaf(ge, u1, acc1[j]);
            acc2[j] = fmaf(ge, u2, acc2[j]);
            acc3[j] = fmaf(ge, u3, acc3[j]);
        }
    }
    u16* ub = ubar + (long)(blockIdx.x * 16 + pix) * 192;
    #pragma unroll
    for (int j = 0; j < 6; j++) {
        int cp = sh + 8*j;
        ushort4 st;
        st.x = f2bf(acc0[j]); st.y = f2bf(acc1[j]);
        st.z = f2bf(acc2[j]); st.w = f2bf(acc3[j]);
        *(ushort4*)&ub[cp*4] = st;
    }
}

// ---- wl: per pixel out[o] = sum_cp sum_q WL'[cp][4o+q] * Ubar[cp*4+q]; writes 0.5*hNL ----
__global__ __launch_bounds__(256) void wl_kernel(const float* ws, const u16* ubar, float* outp) {
    const float* wlt = ws + OFF_WLT;
    int p = blockIdx.x * 256 + threadIdx.x;
    const u16* ub = ubar + (long)p * 192;
    float out[48];
    #pragma unroll
    for (int o = 0; o < 48; o++) out[o] = 0.f;
    for (int cp = 0; cp < 48; cp++) {
        uint2 vv = *(const uint2*)&ub[cp*4];
        float ux = bf2f((u16)(vv.x & 0xffff));
        float uy = bf2f((u16)(vv.x >> 16));
        float uz = bf2f((u16)(vv.y & 0xffff));
        float uw = bf2f((u16)(vv.y >> 16));
        const float* wl = wlt + cp * 192;
        #pragma unroll
        for (int o = 0; o < 48; o++) {
            float a = out[o];
            a = fmaf(wl[4*o+0], ux, a);
            a = fmaf(wl[4*o+1], uy, a);
            a = fmaf(wl[4*o+2], uz, a);
            a = fmaf(wl[4*o+3], uw, a);
            out[o] = a;
        }
    }
    #pragma unroll
    for (int o = 0; o < 48; o++) outp[o*NPIX + p] = 0.0625f * out[o];  // 0.5 * (1/8)
}

// ---- conv 3x3 (reflect pad), 8 output channels per thread, adds 0.5*hL + bias ----
#define OCH 8
__global__ __launch_bounds__(320) void conv_kernel(const float* h, const float* wc,
                                                   const float* bias, float* outp) {
    int og = blockIdx.x % 6;
    int yp = blockIdx.x / 6;
    int t  = threadIdx.x;
    int ty = t / 160;
    int x  = t % 160;
    int y  = yp * 2 + ty;

    int idx9[9];
    #pragma unroll
    for (int dy = 0; dy < 3; dy++) {
        int yy = y + dy - 1;
        yy = yy < 0 ? -yy : (yy >= HH ? 2*HH - 2 - yy : yy);
        #pragma unroll
        for (int dx = 0; dx < 3; dx++) {
            int xx = x + dx - 1;
            xx = xx < 0 ? -xx : (xx >= WWID ? 2*WWID - 2 - xx : xx);
            idx9[dy*3 + dx] = yy * WWID + xx;
        }
    }

    float acc[OCH];
    #pragma unroll
    for (int oi = 0; oi < OCH; oi++) acc[oi] = 0.f;

    const float* wbase = wc + og * OCH * 432;
    for (int c = 0; c < 48; c++) {
        float v[9];
        #pragma unroll
        for (int k = 0; k < 9; k++) v[k] = h[c*NPIX + idx9[k]];
        #pragma unroll
        for (int oi = 0; oi < OCH; oi++) {
            const float* w9 = wbase + oi*432 + c*9;
            float a = acc[oi];
            a = fmaf(v[0], w9[0], a);
            a = fmaf(v[1], w9[1], a);
            a = fmaf(v[2], w9[2], a);
            a = fmaf(v[3], w9[3], a);
            a = fmaf(v[4], w9[4], a);
            a = fmaf(v[5], w9[5], a);
            a = fmaf(v[6], w9[6], a);
            a = fmaf(v[7], w9[7], a);
            a = fmaf(v[8], w9[8], a);
            acc[oi] = a;
        }
    }

    int p = y * WWID + x;
    #pragma unroll
    for (int oi = 0; oi < OCH; oi++) {
        int o = og * OCH + oi;
        outp[o*NPIX + p] = outp[o*NPIX + p] + 0.5f * acc[oi] + bias[o];
    }
}

extern "C" void kernel_launch(void* const* d_in, const int* in_sizes, int n_in,
                              void* d_out, int out_size, void* d_ws, size_t ws_size,
                              hipStream_t stream) {
    const float* h    = (const float*)d_in[0];
    const float* W0   = (const float*)d_in[1];
    const float* b0   = (const float*)d_in[2];
    const float* WL   = (const float*)d_in[3];
    const float* WR   = (const float*)d_in[4];
    const float* Wk   = (const float*)d_in[5];
    const float* bk   = (const float*)d_in[6];
    const float* Wc   = (const float*)d_in[7];
    const float* bias = (const float*)d_in[8];

    float* ws     = (float*)d_ws;
    float* sqp    = ws + OFF_SQP;
    int*   edge   = (int*)(ws + OFF_EDGE);
    float* s2e    = ws + OFF_S2E;
    float* w0v    = ws + OFF_W0V;
    u16*   vtb    = (u16*)(ws + OFF_VTB);
    float* part_d = ws + OFF_PARTD;
    u16*   part_i = (u16*)(ws + OFF_PARTI);
    u16*   ubar   = (u16*)(ws + OFF_UBAR);
    float* outp   = (float*)d_out;

    prep_kernel<<<dim3(16), dim3(256), 0, stream>>>(b0, WL, WR, Wk, bk, ws);
    pix_pre<<<dim3(100), dim3(256), 0, stream>>>(h, W0, w0v, sqp);
    topk_part<<<dim3(800), dim3(128), 0, stream>>>(h, part_d, part_i);
    topk_merge<<<dim3(100), dim3(256), 0, stream>>>(part_d, part_i, sqp, edge, s2e);
    vt_pre<<<dim3(100), dim3(256), 0, stream>>>(h, ws, vtb);   // overwrites part region
    ecc_kernel<<<dim3(1600), dim3(128), 0, stream>>>(ws, edge, s2e, vtb, ubar);
    wl_kernel<<<dim3(100), dim3(256), 0, stream>>>(ws, ubar, outp);
    conv_kernel<<<dim3(480), dim3(320), 0, stream>>>(h, Wc, bias, outp);
}

// Round 7
// 445.872 us; speedup vs baseline: 1.5244x; 1.0990x over previous
//
#include <hip/hip_runtime.h>

#define CC    48
#define HH    160
#define WWID  160
#define NPIX  25600
#define KK    8

typedef unsigned short u16;
typedef __attribute__((ext_vector_type(8))) short bf16x8;
typedef __attribute__((ext_vector_type(4))) float f32x4;

__device__ __forceinline__ float bf2f(u16 u) {
    return __uint_as_float(((unsigned int)u) << 16);
}
__device__ __forceinline__ u16 f2bf(float f) {
    unsigned int x = __float_as_uint(f);
    return (u16)((x + 0x7FFFu + ((x >> 16) & 1u)) >> 16);
}

// ws float-offset layout (high-water 6,598,268 floats = 25.2 MB, same as proven)
#define OFF_B0    0        // 48
#define OFF_BK    48       // 12
#define OFF_WKT   60       // 576    wkt[c*12+r] = Wk[r][c]
#define OFF_WRT   636      // 9216   wrt[cp*192 + i] = WR[i][cp]
#define OFF_WLT   9852     // 9216   wlt[cp*192 + i] = WL[i][cp]
#define OFF_SQP   19068    // 25600
#define OFF_EDGE  44668    // int[204800]
#define OFF_S2E   249468   // float[204800]
#define OFF_W0V   454268   // float[25600*48]
#define OFF_VTB   1683068  // u16[25600*192] bf16 (aliases PART; written after merge)
#define OFF_PARTD 1683068  // float[25600*64]
#define OFF_PARTI 3321468  // u16[25600*64]
#define OFF_UBAR  4140668  // u16[25600*192] bf16 (after part region)

__global__ void prep_kernel(const float* b0, const float* WL, const float* WR,
                            const float* Wk, const float* bk, float* ws) {
    float* b0f  = ws + OFF_B0;
    float* bkf  = ws + OFF_BK;
    float* wkt  = ws + OFF_WKT;
    float* wrt  = ws + OFF_WRT;
    float* wlt  = ws + OFF_WLT;
    int t = blockIdx.x * 256 + threadIdx.x;
    int stride = gridDim.x * 256;
    for (int i = t; i < 9216; i += stride) {
        int cp = i / 192, r = i % 192;
        wrt[i] = WR[r*48 + cp];
        wlt[i] = WL[r*48 + cp];
    }
    for (int i = t; i < 576; i += stride) { int c = i / 12, r = i % 12; wkt[i] = Wk[r*48 + c]; }
    for (int i = t; i < 48; i += stride) { b0f[i] = b0[i]; }
    for (int i = t; i < 12; i += stride) { bkf[i] = bk[i]; }
}

// per-pixel: sq[p] = ||h_p||^2,  W0V[p][o] = sum_c W0[o][c] h[c][p]
__global__ __launch_bounds__(256) void pix_pre(const float* h, const float* W0,
                                               float* w0v, float* sqp) {
    int p = blockIdx.x * 256 + threadIdx.x;
    float f[48];
    float sq = 0.f;
    #pragma unroll
    for (int c = 0; c < 48; c++) { f[c] = h[c*NPIX + p]; sq = fmaf(f[c], f[c], sq); }
    sqp[p] = sq;
    for (int o = 0; o < 48; o++) {
        const float* wr = W0 + o*48;
        float a0 = 0.f, a1 = 0.f, a2 = 0.f, a3 = 0.f;
        #pragma unroll
        for (int c4 = 0; c4 < 12; c4++) {
            a0 = fmaf(wr[c4*4+0], f[c4*4+0], a0);
            a1 = fmaf(wr[c4*4+1], f[c4*4+1], a1);
            a2 = fmaf(wr[c4*4+2], f[c4*4+2], a2);
            a3 = fmaf(wr[c4*4+3], f[c4*4+3], a3);
        }
        w0v[(long)p*48 + o] = (a0 + a1) + (a2 + a3);
    }
}

// per-pixel: VT[p][cp*4+q] = sum_c h[c][p] * WR[4c+q][cp]  (stored bf16)
__global__ __launch_bounds__(256) void vt_pre(const float* h, const float* ws, u16* vtb) {
    const float* wrt = ws + OFF_WRT;
    int p = blockIdx.x * 256 + threadIdx.x;
    float f[48];
    #pragma unroll
    for (int c = 0; c < 48; c++) f[c] = h[c*NPIX + p];
    u16* vrow = vtb + (long)p * 192;
    for (int cp = 0; cp < 48; cp++) {
        const float* wr = wrt + cp * 192;
        float v0 = 0.f, v1 = 0.f, v2 = 0.f, v3 = 0.f;
        #pragma unroll
        for (int c = 0; c < 48; c++) {
            float vc = f[c];
            v0 = fmaf(wr[4*c+0], vc, v0);
            v1 = fmaf(wr[4*c+1], vc, v1);
            v2 = fmaf(wr[4*c+2], vc, v2);
            v3 = fmaf(wr[4*c+3], vc, v3);
        }
        ushort4 st;
        st.x = f2bf(v0); st.y = f2bf(v1); st.z = f2bf(v2); st.w = f2bf(v3);
        *(ushort4*)&vrow[cp*4] = st;
    }
}

// ---- topk stage 1 (MFMA Gram): block = (window, 128-px group, 128-cand chunk) ----
__global__ __launch_bounds__(512, 4) void topk_mfma(const float* h, const float* sqp,
                                                    float* part_d, u16* part_i) {
    __shared__ u16 ca_hi[128*72];
    __shared__ u16 ca_lo[128*72];
    __shared__ u16 px_hi[128*72];
    __shared__ u16 px_lo[128*72];
    __shared__ float sq_s[128];

    int tid = threadIdx.x;
    int b = blockIdx.x;
    int chunk = b & 7, pg = (b >> 3) & 7, win = b >> 6;
    int wi = win / 5, wj = win % 5;
    int base = wi*32*WWID + wj*32;

    // stage candidates (hi/lo split bf16), K padded 48->64 with zeros
    #pragma unroll
    for (int j = 0; j < 12; j++) {
        int id = j*512 + tid;
        int c = id >> 7, cl = id & 127;
        int ml = chunk*128 + cl;
        float f = h[c*NPIX + base + (ml>>5)*WWID + (ml&31)];
        u16 hi = f2bf(f);
        u16 lo = f2bf(f - bf2f(hi));
        ca_hi[cl*72 + c] = hi;
        ca_lo[cl*72 + c] = lo;
    }
    #pragma unroll
    for (int j = 0; j < 12; j++) {
        int id = j*512 + tid;
        int c = id >> 7, pl = id & 127;
        int nl = pg*128 + pl;
        float f = h[c*NPIX + base + (nl>>5)*WWID + (nl&31)];
        u16 hi = f2bf(f);
        u16 lo = f2bf(f - bf2f(hi));
        px_hi[pl*72 + c] = hi;
        px_lo[pl*72 + c] = lo;
    }
    #pragma unroll
    for (int j = 0; j < 4; j++) {
        int id = j*512 + tid;
        int c = 48 + (id >> 7), l = id & 127;
        ca_hi[l*72 + c] = 0; ca_lo[l*72 + c] = 0;
        px_hi[l*72 + c] = 0; px_lo[l*72 + c] = 0;
    }
    if (tid < 128) {
        int ml = chunk*128 + tid;
        sq_s[tid] = sqp[base + (ml>>5)*WWID + (ml&31)];
    }
    __syncthreads();

    int w = tid >> 6, lane = tid & 63;
    int lm = lane & 15, lg = lane >> 4;

    // Gram tile: A = cands (M=128 via 8 frags), B = this wave's 16 pixels (N)
    f32x4 acc[8];
    #pragma unroll
    for (int t = 0; t < 8; t++) acc[t] = (f32x4){0.f, 0.f, 0.f, 0.f};

    #pragma unroll
    for (int s = 0; s < 2; s++) {
        int ko = s*32 + lg*8;
        bf16x8 bh = *(const bf16x8*)&px_hi[(w*16 + lm)*72 + ko];
        bf16x8 bl = *(const bf16x8*)&px_lo[(w*16 + lm)*72 + ko];
        #pragma unroll
        for (int t = 0; t < 8; t++) {
            bf16x8 ah = *(const bf16x8*)&ca_hi[(t*16 + lm)*72 + ko];
            bf16x8 al = *(const bf16x8*)&ca_lo[(t*16 + lm)*72 + ko];
            acc[t] = __builtin_amdgcn_mfma_f32_16x16x32_bf16(ah, bh, acc[t], 0, 0, 0);
            acc[t] = __builtin_amdgcn_mfma_f32_16x16x32_bf16(ah, bl, acc[t], 0, 0, 0);
            acc[t] = __builtin_amdgcn_mfma_f32_16x16x32_bf16(al, bh, acc[t], 0, 0, 0);
        }
    }

    // selection: lane owns pixel col=lm (of wave), cands {16t + 4*lg + r}
    int nl = pg*128 + w*16 + lm;
    int rn = nl >> 5, cn = nl & 31;
    float d8[8]; int i8[8];
    #pragma unroll
    for (int s = 0; s < 8; s++) { d8[s] = 3.0e38f; i8[s] = 0; }
    float worst = 3.0e38f;

    #pragma unroll
    for (int t = 0; t < 8; t++) {
        #pragma unroll
        for (int r = 0; r < 4; r++) {
            int cl = t*16 + lg*4 + r;
            int ml = chunk*128 + cl;
            int rm = ml >> 5, cm = ml & 31;
            int dr = rn - rm; dr = dr < 0 ? -dr : dr;
            int dc = cn - cm; dc = dc < 0 ? -dc : dc;
            float d = (dr <= 1 && dc <= 1) ? 3.0e38f : sq_s[cl] - 2.0f * acc[t][r];
            if (d < worst) {
                bool done = false;
                #pragma unroll
                for (int s = 0; s < 8; s++) {
                    bool hit = (!done) && (d8[s] == worst);
                    if (hit) { d8[s] = d; i8[s] = ml; done = true; }
                }
                worst = d8[0];
                #pragma unroll
                for (int s = 1; s < 8; s++) worst = fmaxf(worst, d8[s]);
            }
        }
    }

    // merge the 4 row-groups (lanes lm, lm+16, lm+32, lm+48) -> full chunk top8
    #pragma unroll
    for (int st = 0; st < 2; st++) {
        int mk = (st == 0) ? 16 : 32;
        float dd[8]; int ii[8];
        #pragma unroll
        for (int s = 0; s < 8; s++) {
            dd[s] = __shfl_xor(d8[s], mk, 64);
            ii[s] = __shfl_xor(i8[s], mk, 64);
        }
        #pragma unroll
        for (int s = 0; s < 8; s++) {
            float d = dd[s];
            if (d < worst) {
                int idx = ii[s];
                bool done = false;
                #pragma unroll
                for (int s2 = 0; s2 < 8; s2++) {
                    bool hit = (!done) && (d8[s2] == worst);
                    if (hit) { d8[s2] = d; i8[s2] = idx; done = true; }
                }
                worst = d8[0];
                #pragma unroll
                for (int s2 = 1; s2 < 8; s2++) worst = fmaxf(worst, d8[s2]);
            }
        }
    }

    if (lg == 0) {
        int n = base + (nl >> 5)*WWID + (nl & 31);
        long bb = (long)n*64 + chunk*8;
        #pragma unroll
        for (int s = 0; s < 8; s++) {
            part_d[bb + s] = d8[s];
            part_i[bb + s] = (u16)i8[s];
        }
    }
}

// ---- topk stage 2 ----
__global__ __launch_bounds__(256) void topk_merge(const float* part_d, const u16* part_i,
                                                  const float* sqp, int* edge, float* s2e) {
    int n = blockIdx.x * 256 + threadIdx.x;
    const float* pd = part_d + (long)n * 64;
    const u16*   pi = part_i + (long)n * 64;
    float d8[8]; int i8[8];
    #pragma unroll
    for (int s = 0; s < 8; s++) { d8[s] = 3.0e38f; i8[s] = 0; }
    float dworst = 3.0e38f;
    for (int j = 0; j < 64; j++) {
        float d = pd[j];
        if (d < dworst) {
            int idx = (int)pi[j];
            bool done = false;
            #pragma unroll
            for (int s = 0; s < 8; s++) {
                bool hit = (!done) && (d8[s] == dworst);
                if (hit) { d8[s] = d; i8[s] = idx; done = true; }
            }
            dworst = d8[0];
            #pragma unroll
            for (int s = 1; s < 8; s++) dworst = fmaxf(dworst, d8[s]);
        }
    }
    int y = n / WWID, x = n % WWID;
    int wy = (y >> 5) << 5, wx = (x >> 5) << 5;
    float sqn = sqp[n];
    #pragma unroll
    for (int s = 0; s < 8; s++) {
        int ml = i8[s];
        edge[n*8 + s] = (wy + (ml >> 5)) * WWID + (wx + (ml & 31));
        s2e[n*8 + s] = d8[s] + sqn;
    }
}

// ---- ecc: per edge up to tmp; per-pixel Ubar = sum_k gamma_k U_k (bf16 out) ----
__global__ __launch_bounds__(128) void ecc_kernel(const float* ws, const int* edge,
                                                  const float* s2e, const u16* vtb,
                                                  u16* ubar) {
    const float* b0f = ws + OFF_B0;
    const float* bkf = ws + OFF_BK;
    const float* wkt = ws + OFF_WKT;
    const float* w0v = ws + OFF_W0V;

    __shared__ float th_s[128][49];
    __shared__ float tg_s[128][13];   // tmp[12] + gamma

    int tid = threadIdx.x;
    int gt = blockIdx.x * 128 + tid;  // edge id = n*8+k
    int n = gt >> 3;
    int m = edge[gt];

    // theta = LReLU(W0V[m] - W0V[n] + b0)
    const float* wm = w0v + (long)m * 48;
    const float* wn = w0v + (long)n * 48;
    #pragma unroll
    for (int o = 0; o < 48; o++) {
        float x = wm[o] - wn[o] + b0f[o];
        th_s[tid][o] = (x >= 0.f) ? x : 0.01f * x;
    }
    float gamma = expf(-s2e[gt] * 0.1f);

    // kappa = Wk @ theta + bk
    float kap[12];
    #pragma unroll
    for (int r = 0; r < 12; r++) kap[r] = bkf[r];
    for (int c = 0; c < 48; c++) {
        float t = th_s[tid][c];
        const float* wkc = wkt + c*12;
        #pragma unroll
        for (int r = 0; r < 12; r++) kap[r] = fmaf(wkc[r], t, kap[r]);
    }

    // sR[3q+p] = sum_cp theta[(p+cp)%48] * VT[m][cp][q]   (VT bf16)
    float sr[12];
    #pragma unroll
    for (int r = 0; r < 12; r++) sr[r] = 0.f;
    const u16* vrow = vtb + (long)m * 192;
    for (int cp = 0; cp < 48; cp++) {
        uint2 vv = *(const uint2*)&vrow[cp*4];
        float vx = bf2f((u16)(vv.x & 0xffff));
        float vy = bf2f((u16)(vv.x >> 16));
        float vz = bf2f((u16)(vv.y & 0xffff));
        float vw = bf2f((u16)(vv.y >> 16));
        int i1 = (cp + 1 < 48) ? cp + 1 : cp - 47;
        int i2 = (cp + 2 < 48) ? cp + 2 : cp - 46;
        float t0 = th_s[tid][cp], t1 = th_s[tid][i1], t2 = th_s[tid][i2];
        sr[0] = fmaf(t0, vx, sr[0]); sr[1]  = fmaf(t1, vx, sr[1]);  sr[2]  = fmaf(t2, vx, sr[2]);
        sr[3] = fmaf(t0, vy, sr[3]); sr[4]  = fmaf(t1, vy, sr[4]);  sr[5]  = fmaf(t2, vy, sr[5]);
        sr[6] = fmaf(t0, vz, sr[6]); sr[7]  = fmaf(t1, vz, sr[7]);  sr[8]  = fmaf(t2, vz, sr[8]);
        sr[9] = fmaf(t0, vw, sr[9]); sr[10] = fmaf(t1, vw, sr[10]); sr[11] = fmaf(t2, vw, sr[11]);
    }

    #pragma unroll
    for (int r = 0; r < 12; r++) tg_s[tid][r] = kap[r] * sr[r];
    tg_s[tid][12] = gamma;
    __syncthreads();

    // phase B: lane (pix, sh) accumulates Ubar for cps {sh, sh+8, ..., sh+40}
    int pix = tid >> 3, sh = tid & 7;
    float acc0[6], acc1[6], acc2[6], acc3[6];
    #pragma unroll
    for (int j = 0; j < 6; j++) { acc0[j] = 0.f; acc1[j] = 0.f; acc2[j] = 0.f; acc3[j] = 0.f; }
    #pragma unroll 1
    for (int e = 0; e < 8; e++) {
        int row = pix * 8 + e;
        float tm[12];
        #pragma unroll
        for (int r = 0; r < 12; r++) tm[r] = tg_s[row][r];
        float ge = tg_s[row][12];
        #pragma unroll
        for (int j = 0; j < 6; j++) {
            int cp = sh + 8*j;
            int i1 = (cp + 1 < 48) ? cp + 1 : cp - 47;
            int i2 = (cp + 2 < 48) ? cp + 2 : cp - 46;
            float t0 = th_s[row][cp], t1 = th_s[row][i1], t2 = th_s[row][i2];
            float u0 = tm[0]*t0 + tm[1]*t1 + tm[2]*t2;
            float u1 = tm[3]*t0 + tm[4]*t1 + tm[5]*t2;
            float u2 = tm[6]*t0 + tm[7]*t1 + tm[8]*t2;
            float u3 = tm[9]*t0 + tm[10]*t1 + tm[11]*t2;
            acc0[j] = fmaf(ge, u0, acc0[j]);
            acc1[j] = fmaf(ge, u1, acc1[j]);
            acc2[j] = fmaf(ge, u2, acc2[j]);
            acc3[j] = fmaf(ge, u3, acc3[j]);
        }
    }
    u16* ub = ubar + (long)(blockIdx.x * 16 + pix) * 192;
    #pragma unroll
    for (int j = 0; j < 6; j++) {
        int cp = sh + 8*j;
        ushort4 st;
        st.x = f2bf(acc0[j]); st.y = f2bf(acc1[j]);
        st.z = f2bf(acc2[j]); st.w = f2bf(acc3[j]);
        *(ushort4*)&ub[cp*4] = st;
    }
}

// ---- wl: per pixel out[o] = sum_cp sum_q WL'[cp][4o+q] * Ubar[cp*4+q]; writes 0.5*hNL ----
__global__ __launch_bounds__(256) void wl_kernel(const float* ws, const u16* ubar, float* outp) {
    const float* wlt = ws + OFF_WLT;
    int p = blockIdx.x * 256 + threadIdx.x;
    const u16* ub = ubar + (long)p * 192;
    float out[48];
    #pragma unroll
    for (int o = 0; o < 48; o++) out[o] = 0.f;
    for (int cp = 0; cp < 48; cp++) {
        uint2 vv = *(const uint2*)&ub[cp*4];
        float ux = bf2f((u16)(vv.x & 0xffff));
        float uy = bf2f((u16)(vv.x >> 16));
        float uz = bf2f((u16)(vv.y & 0xffff));
        float uw = bf2f((u16)(vv.y >> 16));
        const float* wl = wlt + cp * 192;
        #pragma unroll
        for (int o = 0; o < 48; o++) {
            float a = out[o];
            a = fmaf(wl[4*o+0], ux, a);
            a = fmaf(wl[4*o+1], uy, a);
            a = fmaf(wl[4*o+2], uz, a);
            a = fmaf(wl[4*o+3], uw, a);
            out[o] = a;
        }
    }
    #pragma unroll
    for (int o = 0; o < 48; o++) outp[o*NPIX + p] = 0.0625f * out[o];  // 0.5 * (1/8)
}

// ---- conv 3x3 (reflect pad), 8 output channels per thread, adds 0.5*hL + bias ----
#define OCH 8
__global__ __launch_bounds__(320) void conv_kernel(const float* h, const float* wc,
                                                   const float* bias, float* outp) {
    int og = blockIdx.x % 6;
    int yp = blockIdx.x / 6;
    int t  = threadIdx.x;
    int ty = t / 160;
    int x  = t % 160;
    int y  = yp * 2 + ty;

    int idx9[9];
    #pragma unroll
    for (int dy = 0; dy < 3; dy++) {
        int yy = y + dy - 1;
        yy = yy < 0 ? -yy : (yy >= HH ? 2*HH - 2 - yy : yy);
        #pragma unroll
        for (int dx = 0; dx < 3; dx++) {
            int xx = x + dx - 1;
            xx = xx < 0 ? -xx : (xx >= WWID ? 2*WWID - 2 - xx : xx);
            idx9[dy*3 + dx] = yy * WWID + xx;
        }
    }

    float acc[OCH];
    #pragma unroll
    for (int oi = 0; oi < OCH; oi++) acc[oi] = 0.f;

    const float* wbase = wc + og * OCH * 432;
    for (int c = 0; c < 48; c++) {
        float v[9];
        #pragma unroll
        for (int k = 0; k < 9; k++) v[k] = h[c*NPIX + idx9[k]];
        #pragma unroll
        for (int oi = 0; oi < OCH; oi++) {
            const float* w9 = wbase + oi*432 + c*9;
            float a = acc[oi];
            a = fmaf(v[0], w9[0], a);
            a = fmaf(v[1], w9[1], a);
            a = fmaf(v[2], w9[2], a);
            a = fmaf(v[3], w9[3], a);
            a = fmaf(v[4], w9[4], a);
            a = fmaf(v[5], w9[5], a);
            a = fmaf(v[6], w9[6], a);
            a = fmaf(v[7], w9[7], a);
            a = fmaf(v[8], w9[8], a);
            acc[oi] = a;
        }
    }

    int p = y * WWID + x;
    #pragma unroll
    for (int oi = 0; oi < OCH; oi++) {
        int o = og * OCH + oi;
        outp[o*NPIX + p] = outp[o*NPIX + p] + 0.5f * acc[oi] + bias[o];
    }
}

extern "C" void kernel_launch(void* const* d_in, const int* in_sizes, int n_in,
                              void* d_out, int out_size, void* d_ws, size_t ws_size,
                              hipStream_t stream) {
    const float* h    = (const float*)d_in[0];
    const float* W0   = (const float*)d_in[1];
    const float* b0   = (const float*)d_in[2];
    const float* WL   = (const float*)d_in[3];
    const float* WR   = (const float*)d_in[4];
    const float* Wk   = (const float*)d_in[5];
    const float* bk   = (const float*)d_in[6];
    const float* Wc   = (const float*)d_in[7];
    const float* bias = (const float*)d_in[8];

    float* ws     = (float*)d_ws;
    float* sqp    = ws + OFF_SQP;
    int*   edge   = (int*)(ws + OFF_EDGE);
    float* s2e    = ws + OFF_S2E;
    float* w0v    = ws + OFF_W0V;
    u16*   vtb    = (u16*)(ws + OFF_VTB);
    float* part_d = ws + OFF_PARTD;
    u16*   part_i = (u16*)(ws + OFF_PARTI);
    u16*   ubar   = (u16*)(ws + OFF_UBAR);
    float* outp   = (float*)d_out;

    prep_kernel<<<dim3(16), dim3(256), 0, stream>>>(b0, WL, WR, Wk, bk, ws);
    pix_pre<<<dim3(100), dim3(256), 0, stream>>>(h, W0, w0v, sqp);
    topk_mfma<<<dim3(1600), dim3(512), 0, stream>>>(h, sqp, part_d, part_i);
    topk_merge<<<dim3(100), dim3(256), 0, stream>>>(part_d, part_i, sqp, edge, s2e);
    vt_pre<<<dim3(100), dim3(256), 0, stream>>>(h, ws, vtb);   // overwrites part region
    ecc_kernel<<<dim3(1600), dim3(128), 0, stream>>>(ws, edge, s2e, vtb, ubar);
    wl_kernel<<<dim3(100), dim3(256), 0, stream>>>(ws, ubar, outp);
    conv_kernel<<<dim3(480), dim3(320), 0, stream>>>(h, Wc, bias, outp);
}

// Round 8
// 444.963 us; speedup vs baseline: 1.5275x; 1.0020x over previous
//
#include <hip/hip_runtime.h>

#define CC    48
#define HH    160
#define WWID  160
#define NPIX  25600
#define KK    8

typedef unsigned short u16;
typedef __attribute__((ext_vector_type(8))) short bf16x8;
typedef __attribute__((ext_vector_type(4))) float f32x4;

__device__ __forceinline__ float bf2f(u16 u) {
    return __uint_as_float(((unsigned int)u) << 16);
}
__device__ __forceinline__ u16 f2bf(float f) {
    unsigned int x = __float_as_uint(f);
    return (u16)((x + 0x7FFFu + ((x >> 16) & 1u)) >> 16);
}

// ws float-offset layout (high-water 6,598,268 floats = 25.2 MB, same as proven)
#define OFF_B0    0        // 48
#define OFF_BK    48       // 12
#define OFF_WKT   60       // 576    wkt[c*12+r] = Wk[r][c]
#define OFF_WRT   636      // 9216   wrt[cp*192 + i] = WR[i][cp]
#define OFF_WLT   9852     // 9216   wlt[cp*192 + i] = WL[i][cp]
#define OFF_SQP   19068    // 25600
#define OFF_EDGE  44668    // int[204800]
#define OFF_S2E   249468   // float[204800]
#define OFF_W0V   454268   // float[25600*48]
#define OFF_VTB   1683068  // u16[25600*192] bf16 (aliases PART; written after merge)
#define OFF_PARTD 1683068  // float[25600*64]
#define OFF_PARTI 3321468  // u16[25600*64]
#define OFF_UBAR  4140668  // u16[25600*192] bf16 (after part region)

__global__ void prep_kernel(const float* b0, const float* WL, const float* WR,
                            const float* Wk, const float* bk, float* ws) {
    float* b0f  = ws + OFF_B0;
    float* bkf  = ws + OFF_BK;
    float* wkt  = ws + OFF_WKT;
    float* wrt  = ws + OFF_WRT;
    float* wlt  = ws + OFF_WLT;
    int t = blockIdx.x * 256 + threadIdx.x;
    int stride = gridDim.x * 256;
    for (int i = t; i < 9216; i += stride) {
        int cp = i / 192, r = i % 192;
        wrt[i] = WR[r*48 + cp];
        wlt[i] = WL[r*48 + cp];
    }
    for (int i = t; i < 576; i += stride) { int c = i / 12, r = i % 12; wkt[i] = Wk[r*48 + c]; }
    for (int i = t; i < 48; i += stride) { b0f[i] = b0[i]; }
    for (int i = t; i < 12; i += stride) { bkf[i] = bk[i]; }
}

// per-pixel: sq[p] = ||h_p||^2,  W0V[p][o] = sum_c W0[o][c] h[c][p]
__global__ __launch_bounds__(256) void pix_pre(const float* h, const float* W0,
                                               float* w0v, float* sqp) {
    int p = blockIdx.x * 256 + threadIdx.x;
    float f[48];
    float sq = 0.f;
    #pragma unroll
    for (int c = 0; c < 48; c++) { f[c] = h[c*NPIX + p]; sq = fmaf(f[c], f[c], sq); }
    sqp[p] = sq;
    for (int o = 0; o < 48; o++) {
        const float* wr = W0 + o*48;
        float a0 = 0.f, a1 = 0.f, a2 = 0.f, a3 = 0.f;
        #pragma unroll
        for (int c4 = 0; c4 < 12; c4++) {
            a0 = fmaf(wr[c4*4+0], f[c4*4+0], a0);
            a1 = fmaf(wr[c4*4+1], f[c4*4+1], a1);
            a2 = fmaf(wr[c4*4+2], f[c4*4+2], a2);
            a3 = fmaf(wr[c4*4+3], f[c4*4+3], a3);
        }
        w0v[(long)p*48 + o] = (a0 + a1) + (a2 + a3);
    }
}

// per-pixel: VT[p][cp*4+q] = sum_c h[c][p] * WR[4c+q][cp]  (stored bf16)
__global__ __launch_bounds__(256) void vt_pre(const float* h, const float* ws, u16* vtb) {
    const float* wrt = ws + OFF_WRT;
    int p = blockIdx.x * 256 + threadIdx.x;
    float f[48];
    #pragma unroll
    for (int c = 0; c < 48; c++) f[c] = h[c*NPIX + p];
    u16* vrow = vtb + (long)p * 192;
    for (int cp = 0; cp < 48; cp++) {
        const float* wr = wrt + cp * 192;
        float v0 = 0.f, v1 = 0.f, v2 = 0.f, v3 = 0.f;
        #pragma unroll
        for (int c = 0; c < 48; c++) {
            float vc = f[c];
            v0 = fmaf(wr[4*c+0], vc, v0);
            v1 = fmaf(wr[4*c+1], vc, v1);
            v2 = fmaf(wr[4*c+2], vc, v2);
            v3 = fmaf(wr[4*c+3], vc, v3);
        }
        ushort4 st;
        st.x = f2bf(v0); st.y = f2bf(v1); st.z = f2bf(v2); st.w = f2bf(v3);
        *(ushort4*)&vrow[cp*4] = st;
    }
}

// ---- topk stage 1 (MFMA Gram, XOR-swizzled LDS): block = (window, 128-px, 128-cand) ----
// LDS layout: [128 rows][64 u16], 16B blocks; physical blk = logical blk ^ (row&7).
__global__ __launch_bounds__(512, 4) void topk_mfma(const float* h, const float* sqp,
                                                    float* part_d, u16* part_i) {
    __shared__ u16 ca_hi[128*64];
    __shared__ u16 ca_lo[128*64];
    __shared__ u16 px_hi[128*64];
    __shared__ u16 px_lo[128*64];
    __shared__ float sq_s[128];

    int tid = threadIdx.x;
    int b = blockIdx.x;
    int chunk = b & 7, pg = (b >> 3) & 7, win = b >> 6;
    int wi = win / 5, wj = win % 5;
    int base = wi*32*WWID + wj*32;

    // staging: task = (blk, row); lanes span consecutive rows -> coalesced global,
    // spread ds_write_b128 (one per task, swizzled)
    #pragma unroll
    for (int r = 0; r < 2; r++) {
        int task = r*512 + tid;
        int blk = task >> 7, row = task & 127;
        int swz = (blk ^ (row & 7)) * 8;
        // candidates
        {
            int ml = chunk*128 + row;
            int gp = base + (ml>>5)*WWID + (ml&31);
            u16 hi8[8], lo8[8];
            #pragma unroll
            for (int k = 0; k < 8; k++) {
                int c = blk*8 + k;
                float f = (blk < 6) ? h[c*NPIX + gp] : 0.f;
                u16 hi = f2bf(f);
                hi8[k] = hi;
                lo8[k] = f2bf(f - bf2f(hi));
            }
            *(bf16x8*)&ca_hi[row*64 + swz] = *(const bf16x8*)hi8;
            *(bf16x8*)&ca_lo[row*64 + swz] = *(const bf16x8*)lo8;
        }
        // pixels
        {
            int nl = pg*128 + row;
            int gp = base + (nl>>5)*WWID + (nl&31);
            u16 hi8[8], lo8[8];
            #pragma unroll
            for (int k = 0; k < 8; k++) {
                int c = blk*8 + k;
                float f = (blk < 6) ? h[c*NPIX + gp] : 0.f;
                u16 hi = f2bf(f);
                hi8[k] = hi;
                lo8[k] = f2bf(f - bf2f(hi));
            }
            *(bf16x8*)&px_hi[row*64 + swz] = *(const bf16x8*)hi8;
            *(bf16x8*)&px_lo[row*64 + swz] = *(const bf16x8*)lo8;
        }
    }
    if (tid < 128) {
        int ml = chunk*128 + tid;
        sq_s[tid] = sqp[base + (ml>>5)*WWID + (ml&31)];
    }
    __syncthreads();

    int w = tid >> 6, lane = tid & 63;
    int lm = lane & 15, lg = lane >> 4;

    f32x4 acc[8];
    #pragma unroll
    for (int t = 0; t < 8; t++) acc[t] = (f32x4){0.f, 0.f, 0.f, 0.f};

    #pragma unroll
    for (int s = 0; s < 2; s++) {
        int lblk = 4*s + lg;
        int prow = w*16 + lm;
        int poff = prow*64 + (lblk ^ (lm & 7))*8;
        bf16x8 bh = *(const bf16x8*)&px_hi[poff];
        bf16x8 bl = *(const bf16x8*)&px_lo[poff];
        #pragma unroll
        for (int t = 0; t < 8; t++) {
            int aoff = (t*16 + lm)*64 + (lblk ^ (lm & 7))*8;
            bf16x8 ah = *(const bf16x8*)&ca_hi[aoff];
            bf16x8 al = *(const bf16x8*)&ca_lo[aoff];
            acc[t] = __builtin_amdgcn_mfma_f32_16x16x32_bf16(ah, bh, acc[t], 0, 0, 0);
            acc[t] = __builtin_amdgcn_mfma_f32_16x16x32_bf16(ah, bl, acc[t], 0, 0, 0);
            acc[t] = __builtin_amdgcn_mfma_f32_16x16x32_bf16(al, bh, acc[t], 0, 0, 0);
        }
    }

    // selection: lane owns pixel col=lm (of wave), cands {16t + 4*lg + r}
    int nl = pg*128 + w*16 + lm;
    int rn = nl >> 5, cn = nl & 31;
    float d8[8]; int i8[8];
    #pragma unroll
    for (int s = 0; s < 8; s++) { d8[s] = 3.0e38f; i8[s] = 0; }
    float worst = 3.0e38f;

    #pragma unroll
    for (int t = 0; t < 8; t++) {
        #pragma unroll
        for (int r = 0; r < 4; r++) {
            int cl = t*16 + lg*4 + r;
            int ml = chunk*128 + cl;
            int rm = ml >> 5, cm = ml & 31;
            int dr = rn - rm; dr = dr < 0 ? -dr : dr;
            int dc = cn - cm; dc = dc < 0 ? -dc : dc;
            float d = (dr <= 1 && dc <= 1) ? 3.0e38f : sq_s[cl] - 2.0f * acc[t][r];
            if (d < worst) {
                bool done = false;
                #pragma unroll
                for (int s = 0; s < 8; s++) {
                    bool hit = (!done) && (d8[s] == worst);
                    if (hit) { d8[s] = d; i8[s] = ml; done = true; }
                }
                worst = d8[0];
                #pragma unroll
                for (int s = 1; s < 8; s++) worst = fmaxf(worst, d8[s]);
            }
        }
    }

    // merge the 4 row-groups (lanes lm, lm+16, lm+32, lm+48) -> full chunk top8
    #pragma unroll
    for (int st = 0; st < 2; st++) {
        int mk = (st == 0) ? 16 : 32;
        float dd[8]; int ii[8];
        #pragma unroll
        for (int s = 0; s < 8; s++) {
            dd[s] = __shfl_xor(d8[s], mk, 64);
            ii[s] = __shfl_xor(i8[s], mk, 64);
        }
        #pragma unroll
        for (int s = 0; s < 8; s++) {
            float d = dd[s];
            if (d < worst) {
                int idx = ii[s];
                bool done = false;
                #pragma unroll
                for (int s2 = 0; s2 < 8; s2++) {
                    bool hit = (!done) && (d8[s2] == worst);
                    if (hit) { d8[s2] = d; i8[s2] = idx; done = true; }
                }
                worst = d8[0];
                #pragma unroll
                for (int s2 = 1; s2 < 8; s2++) worst = fmaxf(worst, d8[s2]);
            }
        }
    }

    if (lg == 0) {
        int n = base + (nl >> 5)*WWID + (nl & 31);
        long bb = (long)n*64 + chunk*8;
        #pragma unroll
        for (int s = 0; s < 8; s++) {
            part_d[bb + s] = d8[s];
            part_i[bb + s] = (u16)i8[s];
        }
    }
}

// ---- topk stage 2 ----
__global__ __launch_bounds__(256) void topk_merge(const float* part_d, const u16* part_i,
                                                  const float* sqp, int* edge, float* s2e) {
    int n = blockIdx.x * 256 + threadIdx.x;
    const float* pd = part_d + (long)n * 64;
    const u16*   pi = part_i + (long)n * 64;
    float d8[8]; int i8[8];
    #pragma unroll
    for (int s = 0; s < 8; s++) { d8[s] = 3.0e38f; i8[s] = 0; }
    float dworst = 3.0e38f;
    for (int j = 0; j < 64; j++) {
        float d = pd[j];
        if (d < dworst) {
            int idx = (int)pi[j];
            bool done = false;
            #pragma unroll
            for (int s = 0; s < 8; s++) {
                bool hit = (!done) && (d8[s] == dworst);
                if (hit) { d8[s] = d; i8[s] = idx; done = true; }
            }
            dworst = d8[0];
            #pragma unroll
            for (int s = 1; s < 8; s++) dworst = fmaxf(dworst, d8[s]);
        }
    }
    int y = n / WWID, x = n % WWID;
    int wy = (y >> 5) << 5, wx = (x >> 5) << 5;
    float sqn = sqp[n];
    #pragma unroll
    for (int s = 0; s < 8; s++) {
        int ml = i8[s];
        edge[n*8 + s] = (wy + (ml >> 5)) * WWID + (wx + (ml & 31));
        s2e[n*8 + s] = d8[s] + sqn;
    }
}

// ---- ecc: per edge up to tmp; per-pixel Ubar = sum_k gamma_k U_k (bf16 out) ----
__global__ __launch_bounds__(128) void ecc_kernel(const float* ws, const int* edge,
                                                  const float* s2e, const u16* vtb,
                                                  u16* ubar) {
    const float* b0f = ws + OFF_B0;
    const float* bkf = ws + OFF_BK;
    const float* wkt = ws + OFF_WKT;
    const float* w0v = ws + OFF_W0V;

    __shared__ float th_s[128][49];
    __shared__ float tg_s[128][13];   // tmp[12] + gamma

    int tid = threadIdx.x;
    int gt = blockIdx.x * 128 + tid;  // edge id = n*8+k
    int n = gt >> 3;
    int m = edge[gt];

    // theta = LReLU(W0V[m] - W0V[n] + b0)
    const float* wm = w0v + (long)m * 48;
    const float* wn = w0v + (long)n * 48;
    #pragma unroll
    for (int o = 0; o < 48; o++) {
        float x = wm[o] - wn[o] + b0f[o];
        th_s[tid][o] = (x >= 0.f) ? x : 0.01f * x;
    }
    float gamma = expf(-s2e[gt] * 0.1f);

    // kappa = Wk @ theta + bk
    float kap[12];
    #pragma unroll
    for (int r = 0; r < 12; r++) kap[r] = bkf[r];
    for (int c = 0; c < 48; c++) {
        float t = th_s[tid][c];
        const float* wkc = wkt + c*12;
        #pragma unroll
        for (int r = 0; r < 12; r++) kap[r] = fmaf(wkc[r], t, kap[r]);
    }

    // sR[3q+p] = sum_cp theta[(p+cp)%48] * VT[m][cp][q]   (VT bf16)
    float sr[12];
    #pragma unroll
    for (int r = 0; r < 12; r++) sr[r] = 0.f;
    const u16* vrow = vtb + (long)m * 192;
    for (int cp = 0; cp < 48; cp++) {
        uint2 vv = *(const uint2*)&vrow[cp*4];
        float vx = bf2f((u16)(vv.x & 0xffff));
        float vy = bf2f((u16)(vv.x >> 16));
        float vz = bf2f((u16)(vv.y & 0xffff));
        float vw = bf2f((u16)(vv.y >> 16));
        int i1 = (cp + 1 < 48) ? cp + 1 : cp - 47;
        int i2 = (cp + 2 < 48) ? cp + 2 : cp - 46;
        float t0 = th_s[tid][cp], t1 = th_s[tid][i1], t2 = th_s[tid][i2];
        sr[0] = fmaf(t0, vx, sr[0]); sr[1]  = fmaf(t1, vx, sr[1]);  sr[2]  = fmaf(t2, vx, sr[2]);
        sr[3] = fmaf(t0, vy, sr[3]); sr[4]  = fmaf(t1, vy, sr[4]);  sr[5]  = fmaf(t2, vy, sr[5]);
        sr[6] = fmaf(t0, vz, sr[6]); sr[7]  = fmaf(t1, vz, sr[7]);  sr[8]  = fmaf(t2, vz, sr[8]);
        sr[9] = fmaf(t0, vw, sr[9]); sr[10] = fmaf(t1, vw, sr[10]); sr[11] = fmaf(t2, vw, sr[11]);
    }

    #pragma unroll
    for (int r = 0; r < 12; r++) tg_s[tid][r] = kap[r] * sr[r];
    tg_s[tid][12] = gamma;
    __syncthreads();

    // phase B: lane (pix, sh) accumulates Ubar for cps {sh, sh+8, ..., sh+40}
    int pix = tid >> 3, sh = tid & 7;
    float acc0[6], acc1[6], acc2[6], acc3[6];
    #pragma unroll
    for (int j = 0; j < 6; j++) { acc0[j] = 0.f; acc1[j] = 0.f; acc2[j] = 0.f; acc3[j] = 0.f; }
    #pragma unroll 1
    for (int e = 0; e < 8; e++) {
        int row = pix * 8 + e;
        float tm[12];
        #pragma unroll
        for (int r = 0; r < 12; r++) tm[r] = tg_s[row][r];
        float ge = tg_s[row][12];
        #pragma unroll
        for (int j = 0; j < 6; j++) {
            int cp = sh + 8*j;
            int i1 = (cp + 1 < 48) ? cp + 1 : cp - 47;
            int i2 = (cp + 2 < 48) ? cp + 2 : cp - 46;
            float t0 = th_s[row][cp], t1 = th_s[row][i1], t2 = th_s[row][i2];
            float u0 = tm[0]*t0 + tm[1]*t1 + tm[2]*t2;
            float u1 = tm[3]*t0 + tm[4]*t1 + tm[5]*t2;
            float u2 = tm[6]*t0 + tm[7]*t1 + tm[8]*t2;
            float u3 = tm[9]*t0 + tm[10]*t1 + tm[11]*t2;
            acc0[j] = fmaf(ge, u0, acc0[j]);
            acc1[j] = fmaf(ge, u1, acc1[j]);
            acc2[j] = fmaf(ge, u2, acc2[j]);
            acc3[j] = fmaf(ge, u3, acc3[j]);
        }
    }
    u16* ub = ubar + (long)(blockIdx.x * 16 + pix) * 192;
    #pragma unroll
    for (int j = 0; j < 6; j++) {
        int cp = sh + 8*j;
        ushort4 st;
        st.x = f2bf(acc0[j]); st.y = f2bf(acc1[j]);
        st.z = f2bf(acc2[j]); st.w = f2bf(acc3[j]);
        *(ushort4*)&ub[cp*4] = st;
    }
}

// ---- wl: per pixel out[o] = sum_cp sum_q WL'[cp][4o+q] * Ubar[cp*4+q]; writes 0.5*hNL ----
__global__ __launch_bounds__(256) void wl_kernel(const float* ws, const u16* ubar, float* outp) {
    const float* wlt = ws + OFF_WLT;
    int p = blockIdx.x * 256 + threadIdx.x;
    const u16* ub = ubar + (long)p * 192;
    float out[48];
    #pragma unroll
    for (int o = 0; o < 48; o++) out[o] = 0.f;
    for (int cp = 0; cp < 48; cp++) {
        uint2 vv = *(const uint2*)&ub[cp*4];
        float ux = bf2f((u16)(vv.x & 0xffff));
        float uy = bf2f((u16)(vv.x >> 16));
        float uz = bf2f((u16)(vv.y & 0xffff));
        float uw = bf2f((u16)(vv.y >> 16));
        const float* wl = wlt + cp * 192;
        #pragma unroll
        for (int o = 0; o < 48; o++) {
            float a = out[o];
            a = fmaf(wl[4*o+0], ux, a);
            a = fmaf(wl[4*o+1], uy, a);
            a = fmaf(wl[4*o+2], uz, a);
            a = fmaf(wl[4*o+3], uw, a);
            out[o] = a;
        }
    }
    #pragma unroll
    for (int o = 0; o < 48; o++) outp[o*NPIX + p] = 0.0625f * out[o];  // 0.5 * (1/8)
}

// ---- conv 3x3 (reflect pad), 8 output channels per thread, adds 0.5*hL + bias ----
#define OCH 8
__global__ __launch_bounds__(320) void conv_kernel(const float* h, const float* wc,
                                                   const float* bias, float* outp) {
    int og = blockIdx.x % 6;
    int yp = blockIdx.x / 6;
    int t  = threadIdx.x;
    int ty = t / 160;
    int x  = t % 160;
    int y  = yp * 2 + ty;

    int idx9[9];
    #pragma unroll
    for (int dy = 0; dy < 3; dy++) {
        int yy = y + dy - 1;
        yy = yy < 0 ? -yy : (yy >= HH ? 2*HH - 2 - yy : yy);
        #pragma unroll
        for (int dx = 0; dx < 3; dx++) {
            int xx = x + dx - 1;
            xx = xx < 0 ? -xx : (xx >= WWID ? 2*WWID - 2 - xx : xx);
            idx9[dy*3 + dx] = yy * WWID + xx;
        }
    }

    float acc[OCH];
    #pragma unroll
    for (int oi = 0; oi < OCH; oi++) acc[oi] = 0.f;

    const float* wbase = wc + og * OCH * 432;
    for (int c = 0; c < 48; c++) {
        float v[9];
        #pragma unroll
        for (int k = 0; k < 9; k++) v[k] = h[c*NPIX + idx9[k]];
        #pragma unroll
        for (int oi = 0; oi < OCH; oi++) {
            const float* w9 = wbase + oi*432 + c*9;
            float a = acc[oi];
            a = fmaf(v[0], w9[0], a);
            a = fmaf(v[1], w9[1], a);
            a = fmaf(v[2], w9[2], a);
            a = fmaf(v[3], w9[3], a);
            a = fmaf(v[4], w9[4], a);
            a = fmaf(v[5], w9[5], a);
            a = fmaf(v[6], w9[6], a);
            a = fmaf(v[7], w9[7], a);
            a = fmaf(v[8], w9[8], a);
            acc[oi] = a;
        }
    }

    int p = y * WWID + x;
    #pragma unroll
    for (int oi = 0; oi < OCH; oi++) {
        int o = og * OCH + oi;
        outp[o*NPIX + p] = outp[o*NPIX + p] + 0.5f * acc[oi] + bias[o];
    }
}

extern "C" void kernel_launch(void* const* d_in, const int* in_sizes, int n_in,
                              void* d_out, int out_size, void* d_ws, size_t ws_size,
                              hipStream_t stream) {
    const float* h    = (const float*)d_in[0];
    const float* W0   = (const float*)d_in[1];
    const float* b0   = (const float*)d_in[2];
    const float* WL   = (const float*)d_in[3];
    const float* WR   = (const float*)d_in[4];
    const float* Wk   = (const float*)d_in[5];
    const float* bk   = (const float*)d_in[6];
    const float* Wc   = (const float*)d_in[7];
    const float* bias = (const float*)d_in[8];

    float* ws     = (float*)d_ws;
    float* sqp    = ws + OFF_SQP;
    int*   edge   = (int*)(ws + OFF_EDGE);
    float* s2e    = ws + OFF_S2E;
    float* w0v    = ws + OFF_W0V;
    u16*   vtb    = (u16*)(ws + OFF_VTB);
    float* part_d = ws + OFF_PARTD;
    u16*   part_i = (u16*)(ws + OFF_PARTI);
    u16*   ubar   = (u16*)(ws + OFF_UBAR);
    float* outp   = (float*)d_out;

    prep_kernel<<<dim3(16), dim3(256), 0, stream>>>(b0, WL, WR, Wk, bk, ws);
    pix_pre<<<dim3(100), dim3(256), 0, stream>>>(h, W0, w0v, sqp);
    topk_mfma<<<dim3(1600), dim3(512), 0, stream>>>(h, sqp, part_d, part_i);
    topk_merge<<<dim3(100), dim3(256), 0, stream>>>(part_d, part_i, sqp, edge, s2e);
    vt_pre<<<dim3(100), dim3(256), 0, stream>>>(h, ws, vtb);   // overwrites part region
    ecc_kernel<<<dim3(1600), dim3(128), 0, stream>>>(ws, edge, s2e, vtb, ubar);
    wl_kernel<<<dim3(100), dim3(256), 0, stream>>>(ws, ubar, outp);
    conv_kernel<<<dim3(480), dim3(320), 0, stream>>>(h, Wc, bias, outp);
}

// Round 9
// 357.133 us; speedup vs baseline: 1.9032x; 1.2459x over previous
//
#include <hip/hip_runtime.h>

#define CC    48
#define HH    160
#define WWID  160
#define NPIX  25600
#define KK    8

typedef unsigned short u16;
typedef __attribute__((ext_vector_type(8))) short bf16x8;
typedef __attribute__((ext_vector_type(4))) float f32x4;

__device__ __forceinline__ float bf2f(u16 u) {
    return __uint_as_float(((unsigned int)u) << 16);
}
__device__ __forceinline__ u16 f2bf(float f) {
    unsigned int x = __float_as_uint(f);
    return (u16)((x + 0x7FFFu + ((x >> 16) & 1u)) >> 16);
}

// ws float-offset layout (high-water 6,598,268 floats = 25.2 MB, same as proven)
#define OFF_B0    0        // 48
#define OFF_BK    48       // 12
#define OFF_WKT   60       // 576    wkt[c*12+r] = Wk[r][c]
#define OFF_WRT   636      // 9216   wrt[cp*192 + i] = WR[i][cp]
#define OFF_WLT   9852     // 9216   wlt[cp*192 + i] = WL[i][cp]
#define OFF_SQP   19068    // 25600
#define OFF_EDGE  44668    // int[204800]
#define OFF_S2E   249468   // float[204800]
#define OFF_W0V   454268   // float[25600*48]
#define OFF_VTB   1683068  // u16[25600*192] bf16 (aliases PART; written after merge)
#define OFF_PARTD 1683068  // float[25600*64]
#define OFF_PARTI 3321468  // u16[25600*64]
#define OFF_UBAR  4140668  // u16[25600*192] bf16 (written by ecc)
// h_hi_t/h_lo_t (u16[25600*64] each) alias the UBAR region: live pix_pre..topk_mfma,
// dead before ecc writes ubar. 1,638,400 floats < ubar's 2,457,600 floats.

__global__ void prep_kernel(const float* b0, const float* WL, const float* WR,
                            const float* Wk, const float* bk, float* ws) {
    float* b0f  = ws + OFF_B0;
    float* bkf  = ws + OFF_BK;
    float* wkt  = ws + OFF_WKT;
    float* wrt  = ws + OFF_WRT;
    float* wlt  = ws + OFF_WLT;
    int t = blockIdx.x * 256 + threadIdx.x;
    int stride = gridDim.x * 256;
    for (int i = t; i < 9216; i += stride) {
        int cp = i / 192, r = i % 192;
        wrt[i] = WR[r*48 + cp];
        wlt[i] = WL[r*48 + cp];
    }
    for (int i = t; i < 576; i += stride) { int c = i / 12, r = i % 12; wkt[i] = Wk[r*48 + c]; }
    for (int i = t; i < 48; i += stride) { b0f[i] = b0[i]; }
    for (int i = t; i < 12; i += stride) { bkf[i] = bk[i]; }
}

// per-pixel: sq, W0V (o-half per thread-half), bf16 hi/lo split transposed [p][64]
__global__ __launch_bounds__(256) void pix_pre(const float* h, const float* W0,
                                               float* w0v, float* sqp,
                                               u16* hht, u16* hlt) {
    int tid = threadIdx.x;
    int p = blockIdx.x * 128 + (tid & 127);
    int half = tid >> 7;
    float f[48];
    float sq = 0.f;
    #pragma unroll
    for (int c = 0; c < 48; c++) { f[c] = h[c*NPIX + p]; sq = fmaf(f[c], f[c], sq); }
    if (half == 0) sqp[p] = sq;

    // bf16 hi/lo split for this half's 24 channels
    {
        u16 hi24[24], lo24[24];
        #pragma unroll
        for (int k = 0; k < 24; k++) {
            float v = f[half*24 + k];
            u16 hi = f2bf(v);
            hi24[k] = hi;
            lo24[k] = f2bf(v - bf2f(hi));
        }
        uint4* dh = (uint4*)&hht[(long)p*64 + half*24];
        uint4* dl = (uint4*)&hlt[(long)p*64 + half*24];
        const uint4* sh4 = (const uint4*)hi24;
        const uint4* sl4 = (const uint4*)lo24;
        dh[0] = sh4[0]; dh[1] = sh4[1]; dh[2] = sh4[2];
        dl[0] = sl4[0]; dl[1] = sl4[1]; dl[2] = sl4[2];
        if (half) {
            uint4 z = make_uint4(0, 0, 0, 0);
            uint4* zh = (uint4*)&hht[(long)p*64 + 48];
            uint4* zl = (uint4*)&hlt[(long)p*64 + 48];
            zh[0] = z; zh[1] = z;
            zl[0] = z; zl[1] = z;
        }
    }

    for (int o = half*24; o < half*24 + 24; o++) {
        const float* wr = W0 + o*48;
        float a0 = 0.f, a1 = 0.f, a2 = 0.f, a3 = 0.f;
        #pragma unroll
        for (int c4 = 0; c4 < 12; c4++) {
            a0 = fmaf(wr[c4*4+0], f[c4*4+0], a0);
            a1 = fmaf(wr[c4*4+1], f[c4*4+1], a1);
            a2 = fmaf(wr[c4*4+2], f[c4*4+2], a2);
            a3 = fmaf(wr[c4*4+3], f[c4*4+3], a3);
        }
        w0v[(long)p*48 + o] = (a0 + a1) + (a2 + a3);
    }
}

// per-pixel: VT[p][cp*4+q] (cp-half per thread-half), stored bf16
__global__ __launch_bounds__(256) void vt_pre(const float* h, const float* ws, u16* vtb) {
    const float* wrt = ws + OFF_WRT;
    int tid = threadIdx.x;
    int p = blockIdx.x * 128 + (tid & 127);
    int cpb = (tid >> 7) * 24;
    float f[48];
    #pragma unroll
    for (int c = 0; c < 48; c++) f[c] = h[c*NPIX + p];
    u16* vrow = vtb + (long)p * 192;
    for (int cp = cpb; cp < cpb + 24; cp++) {
        const float* wr = wrt + cp * 192;
        float v0 = 0.f, v1 = 0.f, v2 = 0.f, v3 = 0.f;
        #pragma unroll
        for (int c = 0; c < 48; c++) {
            float vc = f[c];
            v0 = fmaf(wr[4*c+0], vc, v0);
            v1 = fmaf(wr[4*c+1], vc, v1);
            v2 = fmaf(wr[4*c+2], vc, v2);
            v3 = fmaf(wr[4*c+3], vc, v3);
        }
        ushort4 st;
        st.x = f2bf(v0); st.y = f2bf(v1); st.z = f2bf(v2); st.w = f2bf(v3);
        *(ushort4*)&vrow[cp*4] = st;
    }
}

// ---- topk stage 1 (MFMA Gram, pre-split bf16, cand-only LDS) ----
__global__ __launch_bounds__(512, 8) void topk_mfma(const u16* hht, const u16* hlt,
                                                    const float* sqp,
                                                    float* part_d, u16* part_i) {
    __shared__ u16 ca_hi[128*64];
    __shared__ u16 ca_lo[128*64];
    __shared__ float sq_s[128];

    int tid = threadIdx.x;
    int b = blockIdx.x;
    int chunk = b & 7, pg = (b >> 3) & 7, win = b >> 6;
    int wi = win / 5, wj = win % 5;
    int base = wi*32*WWID + wj*32;

    // stage candidates: task = (blk, row); one 16B u16 load + one swizzled ds_write each
    #pragma unroll
    for (int r = 0; r < 2; r++) {
        int task = r*512 + tid;
        int blk = task >> 7, row = task & 127;
        int swz = (blk ^ (row & 7)) * 8;
        int ml = chunk*128 + row;
        long gp = base + (ml>>5)*WWID + (ml&31);
        *(uint4*)&ca_hi[row*64 + swz] = *(const uint4*)&hht[gp*64 + blk*8];
        *(uint4*)&ca_lo[row*64 + swz] = *(const uint4*)&hlt[gp*64 + blk*8];
    }
    if (tid < 128) {
        int ml = chunk*128 + tid;
        sq_s[tid] = sqp[base + (ml>>5)*WWID + (ml&31)];
    }
    __syncthreads();

    int w = tid >> 6, lane = tid & 63;
    int lm = lane & 15, lg = lane >> 4;

    int nl = pg*128 + w*16 + lm;
    long gpx = base + (nl>>5)*WWID + (nl&31);

    f32x4 acc[8];
    #pragma unroll
    for (int t = 0; t < 8; t++) acc[t] = (f32x4){0.f, 0.f, 0.f, 0.f};

    #pragma unroll
    for (int s = 0; s < 2; s++) {
        int lblk = 4*s + lg;
        int ko = lblk * 8;
        bf16x8 bh = *(const bf16x8*)&hht[gpx*64 + ko];   // B-frag direct from global
        bf16x8 bl = *(const bf16x8*)&hlt[gpx*64 + ko];
        #pragma unroll
        for (int t = 0; t < 8; t++) {
            int aoff = (t*16 + lm)*64 + (lblk ^ (lm & 7))*8;
            bf16x8 ah = *(const bf16x8*)&ca_hi[aoff];
            bf16x8 al = *(const bf16x8*)&ca_lo[aoff];
            acc[t] = __builtin_amdgcn_mfma_f32_16x16x32_bf16(ah, bh, acc[t], 0, 0, 0);
            acc[t] = __builtin_amdgcn_mfma_f32_16x16x32_bf16(ah, bl, acc[t], 0, 0, 0);
            acc[t] = __builtin_amdgcn_mfma_f32_16x16x32_bf16(al, bh, acc[t], 0, 0, 0);
        }
    }

    // selection: lane owns pixel col=lm (of wave), cands {16t + 4*lg + r}
    int rn = nl >> 5, cn = nl & 31;
    float d8[8]; int i8[8];
    #pragma unroll
    for (int s = 0; s < 8; s++) { d8[s] = 3.0e38f; i8[s] = 0; }
    float worst = 3.0e38f;

    #pragma unroll
    for (int t = 0; t < 8; t++) {
        #pragma unroll
        for (int r = 0; r < 4; r++) {
            int cl = t*16 + lg*4 + r;
            int ml = chunk*128 + cl;
            int rm = ml >> 5, cm = ml & 31;
            int dr = rn - rm; dr = dr < 0 ? -dr : dr;
            int dc = cn - cm; dc = dc < 0 ? -dc : dc;
            float d = (dr <= 1 && dc <= 1) ? 3.0e38f : sq_s[cl] - 2.0f * acc[t][r];
            if (d < worst) {
                bool done = false;
                #pragma unroll
                for (int s = 0; s < 8; s++) {
                    bool hit = (!done) && (d8[s] == worst);
                    if (hit) { d8[s] = d; i8[s] = ml; done = true; }
                }
                worst = d8[0];
                #pragma unroll
                for (int s = 1; s < 8; s++) worst = fmaxf(worst, d8[s]);
            }
        }
    }

    // merge the 4 row-groups (lanes lm, lm+16, lm+32, lm+48) -> full chunk top8
    #pragma unroll
    for (int st = 0; st < 2; st++) {
        int mk = (st == 0) ? 16 : 32;
        float dd[8]; int ii[8];
        #pragma unroll
        for (int s = 0; s < 8; s++) {
            dd[s] = __shfl_xor(d8[s], mk, 64);
            ii[s] = __shfl_xor(i8[s], mk, 64);
        }
        #pragma unroll
        for (int s = 0; s < 8; s++) {
            float d = dd[s];
            if (d < worst) {
                int idx = ii[s];
                bool done = false;
                #pragma unroll
                for (int s2 = 0; s2 < 8; s2++) {
                    bool hit = (!done) && (d8[s2] == worst);
                    if (hit) { d8[s2] = d; i8[s2] = idx; done = true; }
                }
                worst = d8[0];
                #pragma unroll
                for (int s2 = 1; s2 < 8; s2++) worst = fmaxf(worst, d8[s2]);
            }
        }
    }

    if (lg == 0) {
        long bb = gpx*64 + chunk*8;
        #pragma unroll
        for (int s = 0; s < 8; s++) {
            part_d[bb + s] = d8[s];
            part_i[bb + s] = (u16)i8[s];
        }
    }
}

// ---- topk stage 2 ----
__global__ __launch_bounds__(256) void topk_merge(const float* part_d, const u16* part_i,
                                                  const float* sqp, int* edge, float* s2e) {
    int n = blockIdx.x * 256 + threadIdx.x;
    const float* pd = part_d + (long)n * 64;
    const u16*   pi = part_i + (long)n * 64;
    float d8[8]; int i8[8];
    #pragma unroll
    for (int s = 0; s < 8; s++) { d8[s] = 3.0e38f; i8[s] = 0; }
    float dworst = 3.0e38f;
    for (int j = 0; j < 64; j++) {
        float d = pd[j];
        if (d < dworst) {
            int idx = (int)pi[j];
            bool done = false;
            #pragma unroll
            for (int s = 0; s < 8; s++) {
                bool hit = (!done) && (d8[s] == dworst);
                if (hit) { d8[s] = d; i8[s] = idx; done = true; }
            }
            dworst = d8[0];
            #pragma unroll
            for (int s = 1; s < 8; s++) dworst = fmaxf(dworst, d8[s]);
        }
    }
    int y = n / WWID, x = n % WWID;
    int wy = (y >> 5) << 5, wx = (x >> 5) << 5;
    float sqn = sqp[n];
    #pragma unroll
    for (int s = 0; s < 8; s++) {
        int ml = i8[s];
        edge[n*8 + s] = (wy + (ml >> 5)) * WWID + (wx + (ml & 31));
        s2e[n*8 + s] = d8[s] + sqn;
    }
}

// ---- ecc: per edge up to tmp; per-pixel Ubar = sum_k gamma_k U_k (bf16 out) ----
__global__ __launch_bounds__(128) void ecc_kernel(const float* ws, const int* edge,
                                                  const float* s2e, const u16* vtb,
                                                  u16* ubar) {
    const float* b0f = ws + OFF_B0;
    const float* bkf = ws + OFF_BK;
    const float* wkt = ws + OFF_WKT;
    const float* w0v = ws + OFF_W0V;

    __shared__ float th_s[128][49];
    __shared__ float tg_s[128][13];   // tmp[12] + gamma

    int tid = threadIdx.x;
    int gt = blockIdx.x * 128 + tid;  // edge id = n*8+k
    int n = gt >> 3;
    int m = edge[gt];

    // theta = LReLU(W0V[m] - W0V[n] + b0)
    const float* wm = w0v + (long)m * 48;
    const float* wn = w0v + (long)n * 48;
    #pragma unroll
    for (int o = 0; o < 48; o++) {
        float x = wm[o] - wn[o] + b0f[o];
        th_s[tid][o] = (x >= 0.f) ? x : 0.01f * x;
    }
    float gamma = expf(-s2e[gt] * 0.1f);

    // kappa = Wk @ theta + bk
    float kap[12];
    #pragma unroll
    for (int r = 0; r < 12; r++) kap[r] = bkf[r];
    for (int c = 0; c < 48; c++) {
        float t = th_s[tid][c];
        const float* wkc = wkt + c*12;
        #pragma unroll
        for (int r = 0; r < 12; r++) kap[r] = fmaf(wkc[r], t, kap[r]);
    }

    // sR[3q+p] = sum_cp theta[(p+cp)%48] * VT[m][cp][q]   (VT bf16)
    float sr[12];
    #pragma unroll
    for (int r = 0; r < 12; r++) sr[r] = 0.f;
    const u16* vrow = vtb + (long)m * 192;
    for (int cp = 0; cp < 48; cp++) {
        uint2 vv = *(const uint2*)&vrow[cp*4];
        float vx = bf2f((u16)(vv.x & 0xffff));
        float vy = bf2f((u16)(vv.x >> 16));
        float vz = bf2f((u16)(vv.y & 0xffff));
        float vw = bf2f((u16)(vv.y >> 16));
        int i1 = (cp + 1 < 48) ? cp + 1 : cp - 47;
        int i2 = (cp + 2 < 48) ? cp + 2 : cp - 46;
        float t0 = th_s[tid][cp], t1 = th_s[tid][i1], t2 = th_s[tid][i2];
        sr[0] = fmaf(t0, vx, sr[0]); sr[1]  = fmaf(t1, vx, sr[1]);  sr[2]  = fmaf(t2, vx, sr[2]);
        sr[3] = fmaf(t0, vy, sr[3]); sr[4]  = fmaf(t1, vy, sr[4]);  sr[5]  = fmaf(t2, vy, sr[5]);
        sr[6] = fmaf(t0, vz, sr[6]); sr[7]  = fmaf(t1, vz, sr[7]);  sr[8]  = fmaf(t2, vz, sr[8]);
        sr[9] = fmaf(t0, vw, sr[9]); sr[10] = fmaf(t1, vw, sr[10]); sr[11] = fmaf(t2, vw, sr[11]);
    }

    #pragma unroll
    for (int r = 0; r < 12; r++) tg_s[tid][r] = kap[r] * sr[r];
    tg_s[tid][12] = gamma;
    __syncthreads();

    // phase B: lane (pix, sh) accumulates Ubar for cps {sh, sh+8, ..., sh+40}
    int pix = tid >> 3, sh = tid & 7;
    float acc0[6], acc1[6], acc2[6], acc3[6];
    #pragma unroll
    for (int j = 0; j < 6; j++) { acc0[j] = 0.f; acc1[j] = 0.f; acc2[j] = 0.f; acc3[j] = 0.f; }
    #pragma unroll 1
    for (int e = 0; e < 8; e++) {
        int row = pix * 8 + e;
        float tm[12];
        #pragma unroll
        for (int r = 0; r < 12; r++) tm[r] = tg_s[row][r];
        float ge = tg_s[row][12];
        #pragma unroll
        for (int j = 0; j < 6; j++) {
            int cp = sh + 8*j;
            int i1 = (cp + 1 < 48) ? cp + 1 : cp - 47;
            int i2 = (cp + 2 < 48) ? cp + 2 : cp - 46;
            float t0 = th_s[row][cp], t1 = th_s[row][i1], t2 = th_s[row][i2];
            float u0 = tm[0]*t0 + tm[1]*t1 + tm[2]*t2;
            float u1 = tm[3]*t0 + tm[4]*t1 + tm[5]*t2;
            float u2 = tm[6]*t0 + tm[7]*t1 + tm[8]*t2;
            float u3 = tm[9]*t0 + tm[10]*t1 + tm[11]*t2;
            acc0[j] = fmaf(ge, u0, acc0[j]);
            acc1[j] = fmaf(ge, u1, acc1[j]);
            acc2[j] = fmaf(ge, u2, acc2[j]);
            acc3[j] = fmaf(ge, u3, acc3[j]);
        }
    }
    u16* ub = ubar + (long)(blockIdx.x * 16 + pix) * 192;
    #pragma unroll
    for (int j = 0; j < 6; j++) {
        int cp = sh + 8*j;
        ushort4 st;
        st.x = f2bf(acc0[j]); st.y = f2bf(acc1[j]);
        st.z = f2bf(acc2[j]); st.w = f2bf(acc3[j]);
        *(ushort4*)&ub[cp*4] = st;
    }
}

// ---- wl: per pixel out[o] (o-half per thread-half); writes 0.5*hNL ----
__global__ __launch_bounds__(256) void wl_kernel(const float* ws, const u16* ubar, float* outp) {
    const float* wlt = ws + OFF_WLT;
    int tid = threadIdx.x;
    int p = blockIdx.x * 128 + (tid & 127);
    int ob = (tid >> 7) * 24;
    const u16* ub = ubar + (long)p * 192;
    float out[24];
    #pragma unroll
    for (int o = 0; o < 24; o++) out[o] = 0.f;
    for (int cp = 0; cp < 48; cp++) {
        uint2 vv = *(const uint2*)&ub[cp*4];
        float ux = bf2f((u16)(vv.x & 0xffff));
        float uy = bf2f((u16)(vv.x >> 16));
        float uz = bf2f((u16)(vv.y & 0xffff));
        float uw = bf2f((u16)(vv.y >> 16));
        const float* wl = wlt + cp * 192 + ob * 4;
        #pragma unroll
        for (int o = 0; o < 24; o++) {
            float a = out[o];
            a = fmaf(wl[4*o+0], ux, a);
            a = fmaf(wl[4*o+1], uy, a);
            a = fmaf(wl[4*o+2], uz, a);
            a = fmaf(wl[4*o+3], uw, a);
            out[o] = a;
        }
    }
    #pragma unroll
    for (int o = 0; o < 24; o++) outp[(ob + o)*NPIX + p] = 0.0625f * out[o];  // 0.5 * (1/8)
}

// ---- conv 3x3 (reflect pad), 8 output channels per thread, adds 0.5*hL + bias ----
#define OCH 8
__global__ __launch_bounds__(320) void conv_kernel(const float* h, const float* wc,
                                                   const float* bias, float* outp) {
    int og = blockIdx.x % 6;
    int yp = blockIdx.x / 6;
    int t  = threadIdx.x;
    int ty = t / 160;
    int x  = t % 160;
    int y  = yp * 2 + ty;

    int idx9[9];
    #pragma unroll
    for (int dy = 0; dy < 3; dy++) {
        int yy = y + dy - 1;
        yy = yy < 0 ? -yy : (yy >= HH ? 2*HH - 2 - yy : yy);
        #pragma unroll
        for (int dx = 0; dx < 3; dx++) {
            int xx = x + dx - 1;
            xx = xx < 0 ? -xx : (xx >= WWID ? 2*WWID - 2 - xx : xx);
            idx9[dy*3 + dx] = yy * WWID + xx;
        }
    }

    float acc[OCH];
    #pragma unroll
    for (int oi = 0; oi < OCH; oi++) acc[oi] = 0.f;

    const float* wbase = wc + og * OCH * 432;
    for (int c = 0; c < 48; c++) {
        float v[9];
        #pragma unroll
        for (int k = 0; k < 9; k++) v[k] = h[c*NPIX + idx9[k]];
        #pragma unroll
        for (int oi = 0; oi < OCH; oi++) {
            const float* w9 = wbase + oi*432 + c*9;
            float a = acc[oi];
            a = fmaf(v[0], w9[0], a);
            a = fmaf(v[1], w9[1], a);
            a = fmaf(v[2], w9[2], a);
            a = fmaf(v[3], w9[3], a);
            a = fmaf(v[4], w9[4], a);
            a = fmaf(v[5], w9[5], a);
            a = fmaf(v[6], w9[6], a);
            a = fmaf(v[7], w9[7], a);
            a = fmaf(v[8], w9[8], a);
            acc[oi] = a;
        }
    }

    int p = y * WWID + x;
    #pragma unroll
    for (int oi = 0; oi < OCH; oi++) {
        int o = og * OCH + oi;
        outp[o*NPIX + p] = outp[o*NPIX + p] + 0.5f * acc[oi] + bias[o];
    }
}

extern "C" void kernel_launch(void* const* d_in, const int* in_sizes, int n_in,
                              void* d_out, int out_size, void* d_ws, size_t ws_size,
                              hipStream_t stream) {
    const float* h    = (const float*)d_in[0];
    const float* W0   = (const float*)d_in[1];
    const float* b0   = (const float*)d_in[2];
    const float* WL   = (const float*)d_in[3];
    const float* WR   = (const float*)d_in[4];
    const float* Wk   = (const float*)d_in[5];
    const float* bk   = (const float*)d_in[6];
    const float* Wc   = (const float*)d_in[7];
    const float* bias = (const float*)d_in[8];

    float* ws     = (float*)d_ws;
    float* sqp    = ws + OFF_SQP;
    int*   edge   = (int*)(ws + OFF_EDGE);
    float* s2e    = ws + OFF_S2E;
    float* w0v    = ws + OFF_W0V;
    u16*   vtb    = (u16*)(ws + OFF_VTB);
    float* part_d = ws + OFF_PARTD;
    u16*   part_i = (u16*)(ws + OFF_PARTI);
    u16*   ubar   = (u16*)(ws + OFF_UBAR);
    u16*   hht    = (u16*)(ws + OFF_UBAR);            // aliases ubar (dead before ecc)
    u16*   hlt    = hht + 25600*64;
    float* outp   = (float*)d_out;

    prep_kernel<<<dim3(16), dim3(256), 0, stream>>>(b0, WL, WR, Wk, bk, ws);
    pix_pre<<<dim3(200), dim3(256), 0, stream>>>(h, W0, w0v, sqp, hht, hlt);
    topk_mfma<<<dim3(1600), dim3(512), 0, stream>>>(hht, hlt, sqp, part_d, part_i);
    topk_merge<<<dim3(100), dim3(256), 0, stream>>>(part_d, part_i, sqp, edge, s2e);
    vt_pre<<<dim3(200), dim3(256), 0, stream>>>(h, ws, vtb);   // overwrites part region
    ecc_kernel<<<dim3(1600), dim3(128), 0, stream>>>(ws, edge, s2e, vtb, ubar);
    wl_kernel<<<dim3(200), dim3(256), 0, stream>>>(ws, ubar, outp);
    conv_kernel<<<dim3(480), dim3(320), 0, stream>>>(h, Wc, bias, outp);
}

// Round 10
// 278.727 us; speedup vs baseline: 2.4386x; 1.2813x over previous
//
#include <hip/hip_runtime.h>

#define CC    48
#define HH    160
#define WWID  160
#define NPIX  25600
#define KK    8

typedef unsigned short u16;
typedef unsigned int u32;
typedef __attribute__((ext_vector_type(8))) short bf16x8;
typedef __attribute__((ext_vector_type(4))) float f32x4;

__device__ __forceinline__ float bf2f(u16 u) {
    return __uint_as_float(((unsigned int)u) << 16);
}
__device__ __forceinline__ u16 f2bf(float f) {
    unsigned int x = __float_as_uint(f);
    return (u16)((x + 0x7FFFu + ((x >> 16) & 1u)) >> 16);
}

// ws float-offset layout (high-water 25.2 MB, proven)
#define OFF_B0    0        // 48
#define OFF_BK    48       // 12
#define OFF_WKT   60       // 576    wkt[c*12+r] = Wk[r][c]
#define OFF_WRT   636      // 9216   wrt[cp*192 + i] = WR[i][cp]
#define OFF_WLT   9852     // 9216   wlt[cp*192 + i] = WL[i][cp]
#define OFF_SQP   19068    // 25600
#define OFF_EDGE  44668    // int[204800]
#define OFF_S2E   249468   // float[204800]
#define OFF_W0V   454268   // float[25600*48]
#define OFF_VTB   1683068  // u16[25600*192] bf16 (aliases PART; written after merge)
#define OFF_PARTK 1683068  // u32[25600*64] packed keys, chunk-major [c][n][8]
#define OFF_UBAR  4140668  // u16[25600*192] bf16 (written by ecc)
// hht/hlt (u16[25600*64] each) alias UBAR region: live pix_pre..topk_mfma.

__global__ void prep_kernel(const float* b0, const float* WL, const float* WR,
                            const float* Wk, const float* bk, float* ws) {
    float* b0f  = ws + OFF_B0;
    float* bkf  = ws + OFF_BK;
    float* wkt  = ws + OFF_WKT;
    float* wrt  = ws + OFF_WRT;
    float* wlt  = ws + OFF_WLT;
    int t = blockIdx.x * 256 + threadIdx.x;
    int stride = gridDim.x * 256;
    for (int i = t; i < 9216; i += stride) {
        int cp = i / 192, r = i % 192;
        wrt[i] = WR[r*48 + cp];
        wlt[i] = WL[r*48 + cp];
    }
    for (int i = t; i < 576; i += stride) { int c = i / 12, r = i % 12; wkt[i] = Wk[r*48 + c]; }
    for (int i = t; i < 48; i += stride) { b0f[i] = b0[i]; }
    for (int i = t; i < 12; i += stride) { bkf[i] = bk[i]; }
}

// per-pixel: sq, W0V (o-half per thread-half), bf16 hi/lo split transposed [p][64]
__global__ __launch_bounds__(256) void pix_pre(const float* h, const float* W0,
                                               float* w0v, float* sqp,
                                               u16* hht, u16* hlt) {
    int tid = threadIdx.x;
    int p = blockIdx.x * 128 + (tid & 127);
    int half = tid >> 7;
    float f[48];
    float sq = 0.f;
    #pragma unroll
    for (int c = 0; c < 48; c++) { f[c] = h[c*NPIX + p]; sq = fmaf(f[c], f[c], sq); }
    if (half == 0) sqp[p] = sq;

    {
        u16 hi24[24], lo24[24];
        #pragma unroll
        for (int k = 0; k < 24; k++) {
            float v = f[half*24 + k];
            u16 hi = f2bf(v);
            hi24[k] = hi;
            lo24[k] = f2bf(v - bf2f(hi));
        }
        uint4* dh = (uint4*)&hht[(long)p*64 + half*24];
        uint4* dl = (uint4*)&hlt[(long)p*64 + half*24];
        const uint4* sh4 = (const uint4*)hi24;
        const uint4* sl4 = (const uint4*)lo24;
        dh[0] = sh4[0]; dh[1] = sh4[1]; dh[2] = sh4[2];
        dl[0] = sl4[0]; dl[1] = sl4[1]; dl[2] = sl4[2];
        if (half) {
            uint4 z = make_uint4(0, 0, 0, 0);
            uint4* zh = (uint4*)&hht[(long)p*64 + 48];
            uint4* zl = (uint4*)&hlt[(long)p*64 + 48];
            zh[0] = z; zh[1] = z;
            zl[0] = z; zl[1] = z;
        }
    }

    for (int o = half*24; o < half*24 + 24; o++) {
        const float* wr = W0 + o*48;
        float a0 = 0.f, a1 = 0.f, a2 = 0.f, a3 = 0.f;
        #pragma unroll
        for (int c4 = 0; c4 < 12; c4++) {
            a0 = fmaf(wr[c4*4+0], f[c4*4+0], a0);
            a1 = fmaf(wr[c4*4+1], f[c4*4+1], a1);
            a2 = fmaf(wr[c4*4+2], f[c4*4+2], a2);
            a3 = fmaf(wr[c4*4+3], f[c4*4+3], a3);
        }
        w0v[(long)p*48 + o] = (a0 + a1) + (a2 + a3);
    }
}

// per-pixel: VT[p][cp*4+q] (cp-half per thread-half), stored bf16
__global__ __launch_bounds__(256) void vt_pre(const float* h, const float* ws, u16* vtb) {
    const float* wrt = ws + OFF_WRT;
    int tid = threadIdx.x;
    int p = blockIdx.x * 128 + (tid & 127);
    int cpb = (tid >> 7) * 24;
    float f[48];
    #pragma unroll
    for (int c = 0; c < 48; c++) f[c] = h[c*NPIX + p];
    u16* vrow = vtb + (long)p * 192;
    for (int cp = cpb; cp < cpb + 24; cp++) {
        const float* wr = wrt + cp * 192;
        float v0 = 0.f, v1 = 0.f, v2 = 0.f, v3 = 0.f;
        #pragma unroll
        for (int c = 0; c < 48; c++) {
            float vc = f[c];
            v0 = fmaf(wr[4*c+0], vc, v0);
            v1 = fmaf(wr[4*c+1], vc, v1);
            v2 = fmaf(wr[4*c+2], vc, v2);
            v3 = fmaf(wr[4*c+3], vc, v3);
        }
        ushort4 st;
        st.x = f2bf(v0); st.y = f2bf(v1); st.z = f2bf(v2); st.w = f2bf(v3);
        *(ushort4*)&vrow[cp*4] = st;
    }
}

// ---- topk stage 1 (MFMA Gram, packed-key bubble selection) ----
__global__ __launch_bounds__(512, 8) void topk_mfma(const u16* hht, const u16* hlt,
                                                    const float* sqp, u32* partk) {
    __shared__ u16 ca_hi[128*64];
    __shared__ u16 ca_lo[128*64];
    __shared__ float sq_s[128];

    int tid = threadIdx.x;
    int b = blockIdx.x;
    int chunk = b & 7, pg = (b >> 3) & 7, win = b >> 6;
    int wi = win / 5, wj = win % 5;
    int base = wi*32*WWID + wj*32;

    #pragma unroll
    for (int r = 0; r < 2; r++) {
        int task = r*512 + tid;
        int blk = task >> 7, row = task & 127;
        int swz = (blk ^ (row & 7)) * 8;
        int ml = chunk*128 + row;
        long gp = base + (ml>>5)*WWID + (ml&31);
        *(uint4*)&ca_hi[row*64 + swz] = *(const uint4*)&hht[gp*64 + blk*8];
        *(uint4*)&ca_lo[row*64 + swz] = *(const uint4*)&hlt[gp*64 + blk*8];
    }
    if (tid < 128) {
        int ml = chunk*128 + tid;
        sq_s[tid] = sqp[base + (ml>>5)*WWID + (ml&31)];
    }
    __syncthreads();

    int w = tid >> 6, lane = tid & 63;
    int lm = lane & 15, lg = lane >> 4;

    int nl = pg*128 + w*16 + lm;
    long gpx = base + (nl>>5)*WWID + (nl&31);

    f32x4 acc[8];
    #pragma unroll
    for (int t = 0; t < 8; t++) acc[t] = (f32x4){0.f, 0.f, 0.f, 0.f};

    #pragma unroll
    for (int s = 0; s < 2; s++) {
        int lblk = 4*s + lg;
        int ko = lblk * 8;
        bf16x8 bh = *(const bf16x8*)&hht[gpx*64 + ko];
        bf16x8 bl = *(const bf16x8*)&hlt[gpx*64 + ko];
        #pragma unroll
        for (int t = 0; t < 8; t++) {
            int aoff = (t*16 + lm)*64 + (lblk ^ (lm & 7))*8;
            bf16x8 ah = *(const bf16x8*)&ca_hi[aoff];
            bf16x8 al = *(const bf16x8*)&ca_lo[aoff];
            acc[t] = __builtin_amdgcn_mfma_f32_16x16x32_bf16(ah, bh, acc[t], 0, 0, 0);
            acc[t] = __builtin_amdgcn_mfma_f32_16x16x32_bf16(ah, bl, acc[t], 0, 0, 0);
            acc[t] = __builtin_amdgcn_mfma_f32_16x16x32_bf16(al, bh, acc[t], 0, 0, 0);
        }
    }

    // local-mask tables (lane-constant)
    int rn = nl >> 5, cn = nl & 31;
    int rowok[8], colok[8];
    #pragma unroll
    for (int t = 0; t < 8; t++) {
        int rm = chunk*4 + (t >> 1);
        int dr = rn - rm; dr = dr < 0 ? -dr : dr;
        rowok[t] = (dr <= 1);
    }
    #pragma unroll
    for (int j = 0; j < 8; j++) {
        int cm = (j >> 2)*16 + lg*4 + (j & 3);
        int dc = cn - cm; dc = dc < 0 ? -dc : dc;
        colok[j] = (dc <= 1);
    }

    // branchless top-8 via sorted min/max bubble ladder on packed keys
    u32 k8[8];
    #pragma unroll
    for (int s = 0; s < 8; s++) k8[s] = 0xFFFFFFFFu;

    #pragma unroll
    for (int t = 0; t < 8; t++) {
        #pragma unroll
        for (int r = 0; r < 4; r++) {
            int cl = t*16 + lg*4 + r;
            int ml = chunk*128 + cl;
            float d = fmaf(-2.0f, acc[t][r], sq_s[cl]);
            u32 u = __float_as_uint(d);
            u32 key = u ^ (0x80000000u | (u32)((int)u >> 31));   // order-preserving fold
            key = (key & 0xFFFFFC00u) | (u32)ml;                  // 10-bit idx in low bits
            bool bad = rowok[t] && colok[(t & 1)*4 + r];
            key = bad ? 0xFFFFFFFFu : key;
            #pragma unroll
            for (int s = 0; s < 8; s++) {
                u32 lo = min(k8[s], key);
                u32 hi = max(k8[s], key);
                k8[s] = lo; key = hi;
            }
        }
    }

    // lane merge: k8 sorted ascending; bitonic merge of partner lists (lg 0<-16<-32<-48)
    #pragma unroll
    for (int st = 0; st < 2; st++) {
        int mk = (st == 0) ? 16 : 32;
        u32 o[8];
        #pragma unroll
        for (int s = 0; s < 8; s++) o[s] = (u32)__shfl_xor((int)k8[s], mk, 64);
        u32 c0 = min(k8[0], o[7]);
        u32 c1 = min(k8[1], o[6]);
        u32 c2 = min(k8[2], o[5]);
        u32 c3 = min(k8[3], o[4]);
        u32 c4 = min(k8[4], o[3]);
        u32 c5 = min(k8[5], o[2]);
        u32 c6 = min(k8[6], o[1]);
        u32 c7 = min(k8[7], o[0]);
        // bitonic cleanup (sort 8, bitonic input)
        u32 a, bb;
        a = min(c0,c4); bb = max(c0,c4); c0 = a; c4 = bb;
        a = min(c1,c5); bb = max(c1,c5); c1 = a; c5 = bb;
        a = min(c2,c6); bb = max(c2,c6); c2 = a; c6 = bb;
        a = min(c3,c7); bb = max(c3,c7); c3 = a; c7 = bb;
        a = min(c0,c2); bb = max(c0,c2); c0 = a; c2 = bb;
        a = min(c1,c3); bb = max(c1,c3); c1 = a; c3 = bb;
        a = min(c4,c6); bb = max(c4,c6); c4 = a; c6 = bb;
        a = min(c5,c7); bb = max(c5,c7); c5 = a; c7 = bb;
        a = min(c0,c1); bb = max(c0,c1); c0 = a; c1 = bb;
        a = min(c2,c3); bb = max(c2,c3); c2 = a; c3 = bb;
        a = min(c4,c5); bb = max(c4,c5); c4 = a; c5 = bb;
        a = min(c6,c7); bb = max(c6,c7); c6 = a; c7 = bb;
        k8[0]=c0; k8[1]=c1; k8[2]=c2; k8[3]=c3; k8[4]=c4; k8[5]=c5; k8[6]=c6; k8[7]=c7;
    }

    if (lg == 0) {
        int n = base + (nl >> 5)*WWID + (nl & 31);
        u32* pk = partk + (long)chunk*NPIX*8 + (long)n*8;   // chunk-major: contiguous per 16 lanes
        #pragma unroll
        for (int s = 0; s < 8; s++) pk[s] = k8[s];
    }
}

// ---- topk stage 2: merge 8 chunk-lists of 8 keys -> top8; decode idx + d ----
__global__ __launch_bounds__(256) void topk_merge(const u32* partk, const float* sqp,
                                                  int* edge, float* s2e) {
    int n = blockIdx.x * 256 + threadIdx.x;
    u32 k8[8];
    #pragma unroll
    for (int s = 0; s < 8; s++) k8[s] = 0xFFFFFFFFu;
    for (int c = 0; c < 8; c++) {
        const u32* pk = partk + (long)c*NPIX*8 + (long)n*8;
        #pragma unroll
        for (int j = 0; j < 8; j++) {
            u32 key = pk[j];
            #pragma unroll
            for (int s = 0; s < 8; s++) {
                u32 lo = min(k8[s], key);
                u32 hi = max(k8[s], key);
                k8[s] = lo; key = hi;
            }
        }
    }
    int y = n / WWID, x = n % WWID;
    int wy = (y >> 5) << 5, wx = (x >> 5) << 5;
    float sqn = sqp[n];
    #pragma unroll
    for (int s = 0; s < 8; s++) {
        u32 key = k8[s];
        int ml = (int)(key & 1023u);
        u32 uf = key & 0xFFFFFC00u;
        u32 u = (uf & 0x80000000u) ? (uf ^ 0x80000000u) : ~uf;
        float d = __uint_as_float(u);
        edge[n*8 + s] = (wy + (ml >> 5)) * WWID + (wx + (ml & 31));
        s2e[n*8 + s] = d + sqn;
    }
}

// ---- ecc: per edge up to tmp; per-pixel Ubar = sum_k gamma_k U_k (bf16 out) ----
__global__ __launch_bounds__(128) void ecc_kernel(const float* ws, const int* edge,
                                                  const float* s2e, const u16* vtb,
                                                  u16* ubar) {
    const float* b0f = ws + OFF_B0;
    const float* bkf = ws + OFF_BK;
    const float* wkt = ws + OFF_WKT;
    const float* w0v = ws + OFF_W0V;

    __shared__ float th_s[128][49];
    __shared__ float tg_s[128][13];   // tmp[12] + gamma

    int tid = threadIdx.x;
    int gt = blockIdx.x * 128 + tid;  // edge id = n*8+k
    int n = gt >> 3;
    int m = edge[gt];

    const float* wm = w0v + (long)m * 48;
    const float* wn = w0v + (long)n * 48;
    #pragma unroll
    for (int o = 0; o < 48; o++) {
        float x = wm[o] - wn[o] + b0f[o];
        th_s[tid][o] = (x >= 0.f) ? x : 0.01f * x;
    }
    float gamma = expf(-s2e[gt] * 0.1f);

    float kap[12];
    #pragma unroll
    for (int r = 0; r < 12; r++) kap[r] = bkf[r];
    for (int c = 0; c < 48; c++) {
        float t = th_s[tid][c];
        const float* wkc = wkt + c*12;
        #pragma unroll
        for (int r = 0; r < 12; r++) kap[r] = fmaf(wkc[r], t, kap[r]);
    }

    float sr[12];
    #pragma unroll
    for (int r = 0; r < 12; r++) sr[r] = 0.f;
    const u16* vrow = vtb + (long)m * 192;
    for (int cp = 0; cp < 48; cp++) {
        uint2 vv = *(const uint2*)&vrow[cp*4];
        float vx = bf2f((u16)(vv.x & 0xffff));
        float vy = bf2f((u16)(vv.x >> 16));
        float vz = bf2f((u16)(vv.y & 0xffff));
        float vw = bf2f((u16)(vv.y >> 16));
        int i1 = (cp + 1 < 48) ? cp + 1 : cp - 47;
        int i2 = (cp + 2 < 48) ? cp + 2 : cp - 46;
        float t0 = th_s[tid][cp], t1 = th_s[tid][i1], t2 = th_s[tid][i2];
        sr[0] = fmaf(t0, vx, sr[0]); sr[1]  = fmaf(t1, vx, sr[1]);  sr[2]  = fmaf(t2, vx, sr[2]);
        sr[3] = fmaf(t0, vy, sr[3]); sr[4]  = fmaf(t1, vy, sr[4]);  sr[5]  = fmaf(t2, vy, sr[5]);
        sr[6] = fmaf(t0, vz, sr[6]); sr[7]  = fmaf(t1, vz, sr[7]);  sr[8]  = fmaf(t2, vz, sr[8]);
        sr[9] = fmaf(t0, vw, sr[9]); sr[10] = fmaf(t1, vw, sr[10]); sr[11] = fmaf(t2, vw, sr[11]);
    }

    #pragma unroll
    for (int r = 0; r < 12; r++) tg_s[tid][r] = kap[r] * sr[r];
    tg_s[tid][12] = gamma;
    __syncthreads();

    int pix = tid >> 3, sh = tid & 7;
    float acc0[6], acc1[6], acc2[6], acc3[6];
    #pragma unroll
    for (int j = 0; j < 6; j++) { acc0[j] = 0.f; acc1[j] = 0.f; acc2[j] = 0.f; acc3[j] = 0.f; }
    #pragma unroll 1
    for (int e = 0; e < 8; e++) {
        int row = pix * 8 + e;
        float tm[12];
        #pragma unroll
        for (int r = 0; r < 12; r++) tm[r] = tg_s[row][r];
        float ge = tg_s[row][12];
        #pragma unroll
        for (int j = 0; j < 6; j++) {
            int cp = sh + 8*j;
            int i1 = (cp + 1 < 48) ? cp + 1 : cp - 47;
            int i2 = (cp + 2 < 48) ? cp + 2 : cp - 46;
            float t0 = th_s[row][cp], t1 = th_s[row][i1], t2 = th_s[row][i2];
            float u0 = tm[0]*t0 + tm[1]*t1 + tm[2]*t2;
            float u1 = tm[3]*t0 + tm[4]*t1 + tm[5]*t2;
            float u2 = tm[6]*t0 + tm[7]*t1 + tm[8]*t2;
            float u3 = tm[9]*t0 + tm[10]*t1 + tm[11]*t2;
            acc0[j] = fmaf(ge, u0, acc0[j]);
            acc1[j] = fmaf(ge, u1, acc1[j]);
            acc2[j] = fmaf(ge, u2, acc2[j]);
            acc3[j] = fmaf(ge, u3, acc3[j]);
        }
    }
    u16* ub = ubar + (long)(blockIdx.x * 16 + pix) * 192;
    #pragma unroll
    for (int j = 0; j < 6; j++) {
        int cp = sh + 8*j;
        ushort4 st;
        st.x = f2bf(acc0[j]); st.y = f2bf(acc1[j]);
        st.z = f2bf(acc2[j]); st.w = f2bf(acc3[j]);
        *(ushort4*)&ub[cp*4] = st;
    }
}

// ---- wl: per pixel out[o] (o-half per thread-half); writes 0.5*hNL ----
__global__ __launch_bounds__(256) void wl_kernel(const float* ws, const u16* ubar, float* outp) {
    const float* wlt = ws + OFF_WLT;
    int tid = threadIdx.x;
    int p = blockIdx.x * 128 + (tid & 127);
    int ob = (tid >> 7) * 24;
    const u16* ub = ubar + (long)p * 192;
    float out[24];
    #pragma unroll
    for (int o = 0; o < 24; o++) out[o] = 0.f;
    for (int cp = 0; cp < 48; cp++) {
        uint2 vv = *(const uint2*)&ub[cp*4];
        float ux = bf2f((u16)(vv.x & 0xffff));
        float uy = bf2f((u16)(vv.x >> 16));
        float uz = bf2f((u16)(vv.y & 0xffff));
        float uw = bf2f((u16)(vv.y >> 16));
        const float* wl = wlt + cp * 192 + ob * 4;
        #pragma unroll
        for (int o = 0; o < 24; o++) {
            float a = out[o];
            a = fmaf(wl[4*o+0], ux, a);
            a = fmaf(wl[4*o+1], uy, a);
            a = fmaf(wl[4*o+2], uz, a);
            a = fmaf(wl[4*o+3], uw, a);
            out[o] = a;
        }
    }
    #pragma unroll
    for (int o = 0; o < 24; o++) outp[(ob + o)*NPIX + p] = 0.0625f * out[o];  // 0.5 * (1/8)
}

// ---- conv 3x3 (reflect pad), 8 output channels per thread, adds 0.5*hL + bias ----
#define OCH 8
__global__ __launch_bounds__(320) void conv_kernel(const float* h, const float* wc,
                                                   const float* bias, float* outp) {
    int og = blockIdx.x % 6;
    int yp = blockIdx.x / 6;
    int t  = threadIdx.x;
    int ty = t / 160;
    int x  = t % 160;
    int y  = yp * 2 + ty;

    int idx9[9];
    #pragma unroll
    for (int dy = 0; dy < 3; dy++) {
        int yy = y + dy - 1;
        yy = yy < 0 ? -yy : (yy >= HH ? 2*HH - 2 - yy : yy);
        #pragma unroll
        for (int dx = 0; dx < 3; dx++) {
            int xx = x + dx - 1;
            xx = xx < 0 ? -xx : (xx >= WWID ? 2*WWID - 2 - xx : xx);
            idx9[dy*3 + dx] = yy * WWID + xx;
        }
    }

    float acc[OCH];
    #pragma unroll
    for (int oi = 0; oi < OCH; oi++) acc[oi] = 0.f;

    const float* wbase = wc + og * OCH * 432;
    for (int c = 0; c < 48; c++) {
        float v[9];
        #pragma unroll
        for (int k = 0; k < 9; k++) v[k] = h[c*NPIX + idx9[k]];
        #pragma unroll
        for (int oi = 0; oi < OCH; oi++) {
            const float* w9 = wbase + oi*432 + c*9;
            float a = acc[oi];
            a = fmaf(v[0], w9[0], a);
            a = fmaf(v[1], w9[1], a);
            a = fmaf(v[2], w9[2], a);
            a = fmaf(v[3], w9[3], a);
            a = fmaf(v[4], w9[4], a);
            a = fmaf(v[5], w9[5], a);
            a = fmaf(v[6], w9[6], a);
            a = fmaf(v[7], w9[7], a);
            a = fmaf(v[8], w9[8], a);
            acc[oi] = a;
        }
    }

    int p = y * WWID + x;
    #pragma unroll
    for (int oi = 0; oi < OCH; oi++) {
        int o = og * OCH + oi;
        outp[o*NPIX + p] = outp[o*NPIX + p] + 0.5f * acc[oi] + bias[o];
    }
}

extern "C" void kernel_launch(void* const* d_in, const int* in_sizes, int n_in,
                              void* d_out, int out_size, void* d_ws, size_t ws_size,
                              hipStream_t stream) {
    const float* h    = (const float*)d_in[0];
    const float* W0   = (const float*)d_in[1];
    const float* b0   = (const float*)d_in[2];
    const float* WL   = (const float*)d_in[3];
    const float* WR   = (const float*)d_in[4];
    const float* Wk   = (const float*)d_in[5];
    const float* bk   = (const float*)d_in[6];
    const float* Wc   = (const float*)d_in[7];
    const float* bias = (const float*)d_in[8];

    float* ws     = (float*)d_ws;
    float* sqp    = ws + OFF_SQP;
    int*   edge   = (int*)(ws + OFF_EDGE);
    float* s2e    = ws + OFF_S2E;
    float* w0v    = ws + OFF_W0V;
    u16*   vtb    = (u16*)(ws + OFF_VTB);
    u32*   partk  = (u32*)(ws + OFF_PARTK);
    u16*   ubar   = (u16*)(ws + OFF_UBAR);
    u16*   hht    = (u16*)(ws + OFF_UBAR);            // aliases ubar (dead before ecc)
    u16*   hlt    = hht + 25600*64;
    float* outp   = (float*)d_out;

    prep_kernel<<<dim3(16), dim3(256), 0, stream>>>(b0, WL, WR, Wk, bk, ws);
    pix_pre<<<dim3(200), dim3(256), 0, stream>>>(h, W0, w0v, sqp, hht, hlt);
    topk_mfma<<<dim3(1600), dim3(512), 0, stream>>>(hht, hlt, sqp, partk);
    topk_merge<<<dim3(100), dim3(256), 0, stream>>>(partk, sqp, edge, s2e);
    vt_pre<<<dim3(200), dim3(256), 0, stream>>>(h, ws, vtb);   // overwrites part region
    ecc_kernel<<<dim3(1600), dim3(128), 0, stream>>>(ws, edge, s2e, vtb, ubar);
    wl_kernel<<<dim3(200), dim3(256), 0, stream>>>(ws, ubar, outp);
    conv_kernel<<<dim3(480), dim3(320), 0, stream>>>(h, Wc, bias, outp);
}

// Round 11
// 254.728 us; speedup vs baseline: 2.6684x; 1.0942x over previous
//
#include <hip/hip_runtime.h>

#define CC    48
#define HH    160
#define WWID  160
#define NPIX  25600
#define KK    8

typedef unsigned short u16;
typedef unsigned int u32;
typedef __attribute__((ext_vector_type(8))) short bf16x8;
typedef __attribute__((ext_vector_type(4))) float f32x4;

__device__ __forceinline__ float bf2f(u16 u) {
    return __uint_as_float(((unsigned int)u) << 16);
}
__device__ __forceinline__ u16 f2bf(float f) {
    unsigned int x = __float_as_uint(f);
    return (u16)((x + 0x7FFFu + ((x >> 16) & 1u)) >> 16);
}

// ws float-offset layout (high-water 25.2 MB, proven)
#define OFF_B0    0        // 48
#define OFF_BK    48       // 12
#define OFF_WKT   60       // 576    wkt[c*12+r] = Wk[r][c]
#define OFF_WRT   636      // 9216   wrt[cp*192 + i] = WR[i][cp]
#define OFF_WLT   9852     // 9216   wlt[cp*192 + i] = WL[i][cp]
#define OFF_SQP   19068    // 25600
#define OFF_EDGE  44668    // int[204800]
#define OFF_S2E   249468   // float[204800]
#define OFF_W0V   454268   // float[25600*48]
#define OFF_VTB   1683068  // u16[25600*192] bf16 (aliases PARTK; written after merge)
#define OFF_PARTK 1683068  // u32[25600*64] packed keys, chunk-major [c][n][8]
#define OFF_UBAR  4140668  // u16[25600*192] bf16 (written by ecc)
// hht/hlt (u16[25600*64] each) alias UBAR region: live pix_pre..topk_mfma.

__global__ void prep_kernel(const float* b0, const float* WL, const float* WR,
                            const float* Wk, const float* bk, float* ws) {
    float* b0f  = ws + OFF_B0;
    float* bkf  = ws + OFF_BK;
    float* wkt  = ws + OFF_WKT;
    float* wrt  = ws + OFF_WRT;
    float* wlt  = ws + OFF_WLT;
    int t = blockIdx.x * 256 + threadIdx.x;
    int stride = gridDim.x * 256;
    for (int i = t; i < 9216; i += stride) {
        int cp = i / 192, r = i % 192;
        wrt[i] = WR[r*48 + cp];
        wlt[i] = WL[r*48 + cp];
    }
    for (int i = t; i < 576; i += stride) { int c = i / 12, r = i % 12; wkt[i] = Wk[r*48 + c]; }
    for (int i = t; i < 48; i += stride) { b0f[i] = b0[i]; }
    for (int i = t; i < 12; i += stride) { bkf[i] = bk[i]; }
}

// per-pixel: sq, W0V (o-half per thread-half), bf16 hi/lo split transposed [p][64]
__global__ __launch_bounds__(256) void pix_pre(const float* h, const float* W0,
                                               float* w0v, float* sqp,
                                               u16* hht, u16* hlt) {
    int tid = threadIdx.x;
    int p = blockIdx.x * 128 + (tid & 127);
    int half = tid >> 7;
    float f[48];
    float sq = 0.f;
    #pragma unroll
    for (int c = 0; c < 48; c++) { f[c] = h[c*NPIX + p]; sq = fmaf(f[c], f[c], sq); }
    if (half == 0) sqp[p] = sq;

    {
        u16 hi24[24], lo24[24];
        #pragma unroll
        for (int k = 0; k < 24; k++) {
            float v = f[half*24 + k];
            u16 hi = f2bf(v);
            hi24[k] = hi;
            lo24[k] = f2bf(v - bf2f(hi));
        }
        uint4* dh = (uint4*)&hht[(long)p*64 + half*24];
        uint4* dl = (uint4*)&hlt[(long)p*64 + half*24];
        const uint4* sh4 = (const uint4*)hi24;
        const uint4* sl4 = (const uint4*)lo24;
        dh[0] = sh4[0]; dh[1] = sh4[1]; dh[2] = sh4[2];
        dl[0] = sl4[0]; dl[1] = sl4[1]; dl[2] = sl4[2];
        if (half) {
            uint4 z = make_uint4(0, 0, 0, 0);
            uint4* zh = (uint4*)&hht[(long)p*64 + 48];
            uint4* zl = (uint4*)&hlt[(long)p*64 + 48];
            zh[0] = z; zh[1] = z;
            zl[0] = z; zl[1] = z;
        }
    }

    for (int o = half*24; o < half*24 + 24; o++) {
        const float* wr = W0 + o*48;
        float a0 = 0.f, a1 = 0.f, a2 = 0.f, a3 = 0.f;
        #pragma unroll
        for (int c4 = 0; c4 < 12; c4++) {
            a0 = fmaf(wr[c4*4+0], f[c4*4+0], a0);
            a1 = fmaf(wr[c4*4+1], f[c4*4+1], a1);
            a2 = fmaf(wr[c4*4+2], f[c4*4+2], a2);
            a3 = fmaf(wr[c4*4+3], f[c4*4+3], a3);
        }
        w0v[(long)p*48 + o] = (a0 + a1) + (a2 + a3);
    }
}

// per-pixel: VT[p][cp*4+q] (cp-half per thread-half), stored bf16
__global__ __launch_bounds__(256) void vt_pre(const float* h, const float* ws, u16* vtb) {
    const float* wrt = ws + OFF_WRT;
    int tid = threadIdx.x;
    int p = blockIdx.x * 128 + (tid & 127);
    int cpb = (tid >> 7) * 24;
    float f[48];
    #pragma unroll
    for (int c = 0; c < 48; c++) f[c] = h[c*NPIX + p];
    u16* vrow = vtb + (long)p * 192;
    for (int cp = cpb; cp < cpb + 24; cp++) {
        const float* wr = wrt + cp * 192;
        float v0 = 0.f, v1 = 0.f, v2 = 0.f, v3 = 0.f;
        #pragma unroll
        for (int c = 0; c < 48; c++) {
            float vc = f[c];
            v0 = fmaf(wr[4*c+0], vc, v0);
            v1 = fmaf(wr[4*c+1], vc, v1);
            v2 = fmaf(wr[4*c+2], vc, v2);
            v3 = fmaf(wr[4*c+3], vc, v3);
        }
        ushort4 st;
        st.x = f2bf(v0); st.y = f2bf(v1); st.z = f2bf(v2); st.w = f2bf(v3);
        *(ushort4*)&vrow[cp*4] = st;
    }
}

// ---- topk stage 1 (MFMA Gram, packed-key bubble selection, XCD-swizzled) ----
__global__ __launch_bounds__(512, 8) void topk_mfma(const u16* hht, const u16* hlt,
                                                    const float* sqp, u32* partk) {
    __shared__ u16 ca_hi[128*64];
    __shared__ u16 ca_lo[128*64];
    __shared__ float sq_s[128];

    int tid = threadIdx.x;
    int b = (blockIdx.x & 7) * 200 + (blockIdx.x >> 3);   // bijective XCD swizzle (1600=8x200)
    int chunk = b & 7, pg = (b >> 3) & 7, win = b >> 6;
    int wi = win / 5, wj = win % 5;
    int base = wi*32*WWID + wj*32;

    #pragma unroll
    for (int r = 0; r < 2; r++) {
        int task = r*512 + tid;
        int blk = task >> 7, row = task & 127;
        int swz = (blk ^ (row & 7)) * 8;
        int ml = chunk*128 + row;
        long gp = base + (ml>>5)*WWID + (ml&31);
        *(uint4*)&ca_hi[row*64 + swz] = *(const uint4*)&hht[gp*64 + blk*8];
        *(uint4*)&ca_lo[row*64 + swz] = *(const uint4*)&hlt[gp*64 + blk*8];
    }
    if (tid < 128) {
        int ml = chunk*128 + tid;
        sq_s[tid] = sqp[base + (ml>>5)*WWID + (ml&31)];
    }
    __syncthreads();

    int w = tid >> 6, lane = tid & 63;
    int lm = lane & 15, lg = lane >> 4;

    int nl = pg*128 + w*16 + lm;
    long gpx = base + (nl>>5)*WWID + (nl&31);

    f32x4 acc[8];
    #pragma unroll
    for (int t = 0; t < 8; t++) acc[t] = (f32x4){0.f, 0.f, 0.f, 0.f};

    #pragma unroll
    for (int s = 0; s < 2; s++) {
        int lblk = 4*s + lg;
        int ko = lblk * 8;
        bf16x8 bh = *(const bf16x8*)&hht[gpx*64 + ko];
        bf16x8 bl = *(const bf16x8*)&hlt[gpx*64 + ko];
        #pragma unroll
        for (int t = 0; t < 8; t++) {
            int aoff = (t*16 + lm)*64 + (lblk ^ (lm & 7))*8;
            bf16x8 ah = *(const bf16x8*)&ca_hi[aoff];
            bf16x8 al = *(const bf16x8*)&ca_lo[aoff];
            acc[t] = __builtin_amdgcn_mfma_f32_16x16x32_bf16(ah, bh, acc[t], 0, 0, 0);
            acc[t] = __builtin_amdgcn_mfma_f32_16x16x32_bf16(ah, bl, acc[t], 0, 0, 0);
            acc[t] = __builtin_amdgcn_mfma_f32_16x16x32_bf16(al, bh, acc[t], 0, 0, 0);
        }
    }

    int rn = nl >> 5, cn = nl & 31;
    int rowok[8], colok[8];
    #pragma unroll
    for (int t = 0; t < 8; t++) {
        int rm = chunk*4 + (t >> 1);
        int dr = rn - rm; dr = dr < 0 ? -dr : dr;
        rowok[t] = (dr <= 1);
    }
    #pragma unroll
    for (int j = 0; j < 8; j++) {
        int cm = (j >> 2)*16 + lg*4 + (j & 3);
        int dc = cn - cm; dc = dc < 0 ? -dc : dc;
        colok[j] = (dc <= 1);
    }

    u32 k8[8];
    #pragma unroll
    for (int s = 0; s < 8; s++) k8[s] = 0xFFFFFFFFu;

    #pragma unroll
    for (int t = 0; t < 8; t++) {
        #pragma unroll
        for (int r = 0; r < 4; r++) {
            int cl = t*16 + lg*4 + r;
            int ml = chunk*128 + cl;
            float d = fmaf(-2.0f, acc[t][r], sq_s[cl]);
            u32 u = __float_as_uint(d);
            u32 key = u ^ (0x80000000u | (u32)((int)u >> 31));
            key = (key & 0xFFFFFC00u) | (u32)ml;
            bool bad = rowok[t] && colok[(t & 1)*4 + r];
            key = bad ? 0xFFFFFFFFu : key;
            #pragma unroll
            for (int s = 0; s < 8; s++) {
                u32 lo = min(k8[s], key);
                u32 hi = max(k8[s], key);
                k8[s] = lo; key = hi;
            }
        }
    }

    #pragma unroll
    for (int st = 0; st < 2; st++) {
        int mk = (st == 0) ? 16 : 32;
        u32 o[8];
        #pragma unroll
        for (int s = 0; s < 8; s++) o[s] = (u32)__shfl_xor((int)k8[s], mk, 64);
        u32 c0 = min(k8[0], o[7]);
        u32 c1 = min(k8[1], o[6]);
        u32 c2 = min(k8[2], o[5]);
        u32 c3 = min(k8[3], o[4]);
        u32 c4 = min(k8[4], o[3]);
        u32 c5 = min(k8[5], o[2]);
        u32 c6 = min(k8[6], o[1]);
        u32 c7 = min(k8[7], o[0]);
        u32 a, bb;
        a = min(c0,c4); bb = max(c0,c4); c0 = a; c4 = bb;
        a = min(c1,c5); bb = max(c1,c5); c1 = a; c5 = bb;
        a = min(c2,c6); bb = max(c2,c6); c2 = a; c6 = bb;
        a = min(c3,c7); bb = max(c3,c7); c3 = a; c7 = bb;
        a = min(c0,c2); bb = max(c0,c2); c0 = a; c2 = bb;
        a = min(c1,c3); bb = max(c1,c3); c1 = a; c3 = bb;
        a = min(c4,c6); bb = max(c4,c6); c4 = a; c6 = bb;
        a = min(c5,c7); bb = max(c5,c7); c5 = a; c7 = bb;
        a = min(c0,c1); bb = max(c0,c1); c0 = a; c1 = bb;
        a = min(c2,c3); bb = max(c2,c3); c2 = a; c3 = bb;
        a = min(c4,c5); bb = max(c4,c5); c4 = a; c5 = bb;
        a = min(c6,c7); bb = max(c6,c7); c6 = a; c7 = bb;
        k8[0]=c0; k8[1]=c1; k8[2]=c2; k8[3]=c3; k8[4]=c4; k8[5]=c5; k8[6]=c6; k8[7]=c7;
    }

    if (lg == 0) {
        int n = base + (nl >> 5)*WWID + (nl & 31);
        u32* pk = partk + (long)chunk*NPIX*8 + (long)n*8;
        #pragma unroll
        for (int s = 0; s < 8; s++) pk[s] = k8[s];
    }
}

// ---- topk stage 2: merge 8 chunk-lists of 8 keys -> top8; decode idx + d ----
__global__ __launch_bounds__(256) void topk_merge(const u32* partk, const float* sqp,
                                                  int* edge, float* s2e) {
    int n = blockIdx.x * 256 + threadIdx.x;
    u32 k8[8];
    #pragma unroll
    for (int s = 0; s < 8; s++) k8[s] = 0xFFFFFFFFu;
    for (int c = 0; c < 8; c++) {
        const u32* pk = partk + (long)c*NPIX*8 + (long)n*8;
        #pragma unroll
        for (int j = 0; j < 8; j++) {
            u32 key = pk[j];
            #pragma unroll
            for (int s = 0; s < 8; s++) {
                u32 lo = min(k8[s], key);
                u32 hi = max(k8[s], key);
                k8[s] = lo; key = hi;
            }
        }
    }
    int y = n / WWID, x = n % WWID;
    int wy = (y >> 5) << 5, wx = (x >> 5) << 5;
    float sqn = sqp[n];
    #pragma unroll
    for (int s = 0; s < 8; s++) {
        u32 key = k8[s];
        int ml = (int)(key & 1023u);
        u32 uf = key & 0xFFFFFC00u;
        u32 u = (uf & 0x80000000u) ? (uf ^ 0x80000000u) : ~uf;
        float d = __uint_as_float(u);
        edge[n*8 + s] = (wy + (ml >> 5)) * WWID + (wx + (ml & 31));
        s2e[n*8 + s] = d + sqn;
    }
}

// ---- ecc: register-theta, bf16 theta LDS (phase B only), shfl tmp/gamma, XCD swizzle ----
__global__ __launch_bounds__(128, 4) void ecc_kernel(const float* ws, const int* edge,
                                                     const float* s2e, const u16* vtb,
                                                     u16* ubar) {
    const float* b0f = ws + OFF_B0;
    const float* bkf = ws + OFF_BK;
    const float* wkt = ws + OFF_WKT;
    const float* w0v = ws + OFF_W0V;

    __shared__ u16 th_s[128][50];   // theta bf16, row stride 100 B

    int tid = threadIdx.x;
    int sb = (blockIdx.x & 7) * 200 + (blockIdx.x >> 3);   // bijective XCD swizzle
    int gt = sb * 128 + tid;        // edge id = n*8+k
    int n = gt >> 3;
    int m = edge[gt];

    // theta = LReLU(W0V[m] - W0V[n] + b0) -> registers (all uses statically indexed)
    float th[48];
    {
        const float4* wm4 = (const float4*)(w0v + (long)m * 48);
        const float4* wn4 = (const float4*)(w0v + (long)n * 48);
        #pragma unroll
        for (int i = 0; i < 12; i++) {
            float4 a = wm4[i];
            float4 b = wn4[i];
            float x0 = a.x - b.x + b0f[4*i+0];
            float x1 = a.y - b.y + b0f[4*i+1];
            float x2 = a.z - b.z + b0f[4*i+2];
            float x3 = a.w - b.w + b0f[4*i+3];
            th[4*i+0] = (x0 >= 0.f) ? x0 : 0.01f * x0;
            th[4*i+1] = (x1 >= 0.f) ? x1 : 0.01f * x1;
            th[4*i+2] = (x2 >= 0.f) ? x2 : 0.01f * x2;
            th[4*i+3] = (x3 >= 0.f) ? x3 : 0.01f * x3;
        }
    }
    float gamma = expf(-s2e[gt] * 0.1f);

    // stage theta to LDS as bf16 (for phase B cross-lane reads)
    #pragma unroll
    for (int i = 0; i < 24; i++) {
        ushort2 pr;
        pr.x = f2bf(th[2*i]);
        pr.y = f2bf(th[2*i+1]);
        *(ushort2*)&th_s[tid][2*i] = pr;
    }

    // kappa = Wk @ theta + bk (register theta)
    float kap[12];
    #pragma unroll
    for (int r = 0; r < 12; r++) kap[r] = bkf[r];
    #pragma unroll
    for (int c = 0; c < 48; c++) {
        float t = th[c];
        const float* wkc = wkt + c*12;
        #pragma unroll
        for (int r = 0; r < 12; r++) kap[r] = fmaf(wkc[r], t, kap[r]);
    }

    // sR[3q+p] = sum_cp theta[(p+cp)%48] * VT[m][cp][q]  (register theta, uint4 VT loads)
    float sr[12];
    #pragma unroll
    for (int r = 0; r < 12; r++) sr[r] = 0.f;
    const u16* vrow = vtb + (long)m * 192;
    #pragma unroll
    for (int j = 0; j < 24; j++) {
        uint4 vv = *(const uint4*)&vrow[j*8];
        #pragma unroll
        for (int half = 0; half < 2; half++) {
            int cp = 2*j + half;
            u32 w0_ = half ? vv.z : vv.x;
            u32 w1_ = half ? vv.w : vv.y;
            float vx = bf2f((u16)(w0_ & 0xffff));
            float vy = bf2f((u16)(w0_ >> 16));
            float vz = bf2f((u16)(w1_ & 0xffff));
            float vw = bf2f((u16)(w1_ >> 16));
            int i1 = (cp + 1 < 48) ? cp + 1 : cp - 47;
            int i2 = (cp + 2 < 48) ? cp + 2 : cp - 46;
            float t0 = th[cp], t1 = th[i1], t2 = th[i2];
            sr[0] = fmaf(t0, vx, sr[0]); sr[1]  = fmaf(t1, vx, sr[1]);  sr[2]  = fmaf(t2, vx, sr[2]);
            sr[3] = fmaf(t0, vy, sr[3]); sr[4]  = fmaf(t1, vy, sr[4]);  sr[5]  = fmaf(t2, vy, sr[5]);
            sr[6] = fmaf(t0, vz, sr[6]); sr[7]  = fmaf(t1, vz, sr[7]);  sr[8]  = fmaf(t2, vz, sr[8]);
            sr[9] = fmaf(t0, vw, sr[9]); sr[10] = fmaf(t1, vw, sr[10]); sr[11] = fmaf(t2, vw, sr[11]);
        }
    }

    float tmp[12];
    #pragma unroll
    for (int r = 0; r < 12; r++) tmp[r] = kap[r] * sr[r];

    __syncthreads();

    // phase B: lane (pix, sh) accumulates Ubar over the pixel's 8 edges
    // all sharing is intra-wave: rows pix*8+e are lanes (tid&56)+e of this wave
    int pix = tid >> 3, sh = tid & 7;
    float acc0[6], acc1[6], acc2[6], acc3[6];
    #pragma unroll
    for (int j = 0; j < 6; j++) { acc0[j] = 0.f; acc1[j] = 0.f; acc2[j] = 0.f; acc3[j] = 0.f; }
    #pragma unroll 1
    for (int e = 0; e < 8; e++) {
        int srcl = (tid & 56) + e;          // lane within wave
        int row  = (tid & 120) + e;         // block-wide LDS row
        float tm[12];
        #pragma unroll
        for (int r = 0; r < 12; r++) tm[r] = __shfl(tmp[r], srcl, 64);
        float ge = __shfl(gamma, srcl, 64);
        #pragma unroll
        for (int j = 0; j < 6; j++) {
            int cp = sh + 8*j;
            int i1 = (cp + 1 < 48) ? cp + 1 : cp - 47;
            int i2 = (cp + 2 < 48) ? cp + 2 : cp - 46;
            float t0 = bf2f(th_s[row][cp]);
            float t1 = bf2f(th_s[row][i1]);
            float t2 = bf2f(th_s[row][i2]);
            float u0 = tm[0]*t0 + tm[1]*t1 + tm[2]*t2;
            float u1 = tm[3]*t0 + tm[4]*t1 + tm[5]*t2;
            float u2 = tm[6]*t0 + tm[7]*t1 + tm[8]*t2;
            float u3 = tm[9]*t0 + tm[10]*t1 + tm[11]*t2;
            acc0[j] = fmaf(ge, u0, acc0[j]);
            acc1[j] = fmaf(ge, u1, acc1[j]);
            acc2[j] = fmaf(ge, u2, acc2[j]);
            acc3[j] = fmaf(ge, u3, acc3[j]);
        }
    }
    u16* ub = ubar + (long)(sb * 16 + pix) * 192;
    #pragma unroll
    for (int j = 0; j < 6; j++) {
        int cp = sh + 8*j;
        ushort4 st;
        st.x = f2bf(acc0[j]); st.y = f2bf(acc1[j]);
        st.z = f2bf(acc2[j]); st.w = f2bf(acc3[j]);
        *(ushort4*)&ub[cp*4] = st;
    }
}

// ---- wl: per pixel out[o] (o-half per thread-half); writes 0.5*hNL ----
__global__ __launch_bounds__(256) void wl_kernel(const float* ws, const u16* ubar, float* outp) {
    const float* wlt = ws + OFF_WLT;
    int tid = threadIdx.x;
    int p = blockIdx.x * 128 + (tid & 127);
    int ob = (tid >> 7) * 24;
    const u16* ub = ubar + (long)p * 192;
    float out[24];
    #pragma unroll
    for (int o = 0; o < 24; o++) out[o] = 0.f;
    for (int cp = 0; cp < 48; cp++) {
        uint2 vv = *(const uint2*)&ub[cp*4];
        float ux = bf2f((u16)(vv.x & 0xffff));
        float uy = bf2f((u16)(vv.x >> 16));
        float uz = bf2f((u16)(vv.y & 0xffff));
        float uw = bf2f((u16)(vv.y >> 16));
        const float* wl = wlt + cp * 192 + ob * 4;
        #pragma unroll
        for (int o = 0; o < 24; o++) {
            float a = out[o];
            a = fmaf(wl[4*o+0], ux, a);
            a = fmaf(wl[4*o+1], uy, a);
            a = fmaf(wl[4*o+2], uz, a);
            a = fmaf(wl[4*o+3], uw, a);
            out[o] = a;
        }
    }
    #pragma unroll
    for (int o = 0; o < 24; o++) outp[(ob + o)*NPIX + p] = 0.0625f * out[o];  // 0.5 * (1/8)
}

// ---- conv 3x3 (reflect pad), 8 output channels per thread, adds 0.5*hL + bias ----
#define OCH 8
__global__ __launch_bounds__(320) void conv_kernel(const float* h, const float* wc,
                                                   const float* bias, float* outp) {
    int og = blockIdx.x % 6;
    int yp = blockIdx.x / 6;
    int t  = threadIdx.x;
    int ty = t / 160;
    int x  = t % 160;
    int y  = yp * 2 + ty;

    int idx9[9];
    #pragma unroll
    for (int dy = 0; dy < 3; dy++) {
        int yy = y + dy - 1;
        yy = yy < 0 ? -yy : (yy >= HH ? 2*HH - 2 - yy : yy);
        #pragma unroll
        for (int dx = 0; dx < 3; dx++) {
            int xx = x + dx - 1;
            xx = xx < 0 ? -xx : (xx >= WWID ? 2*WWID - 2 - xx : xx);
            idx9[dy*3 + dx] = yy * WWID + xx;
        }
    }

    float acc[OCH];
    #pragma unroll
    for (int oi = 0; oi < OCH; oi++) acc[oi] = 0.f;

    const float* wbase = wc + og * OCH * 432;
    for (int c = 0; c < 48; c++) {
        float v[9];
        #pragma unroll
        for (int k = 0; k < 9; k++) v[k] = h[c*NPIX + idx9[k]];
        #pragma unroll
        for (int oi = 0; oi < OCH; oi++) {
            const float* w9 = wbase + oi*432 + c*9;
            float a = acc[oi];
            a = fmaf(v[0], w9[0], a);
            a = fmaf(v[1], w9[1], a);
            a = fmaf(v[2], w9[2], a);
            a = fmaf(v[3], w9[3], a);
            a = fmaf(v[4], w9[4], a);
            a = fmaf(v[5], w9[5], a);
            a = fmaf(v[6], w9[6], a);
            a = fmaf(v[7], w9[7], a);
            a = fmaf(v[8], w9[8], a);
            acc[oi] = a;
        }
    }

    int p = y * WWID + x;
    #pragma unroll
    for (int oi = 0; oi < OCH; oi++) {
        int o = og * OCH + oi;
        outp[o*NPIX + p] = outp[o*NPIX + p] + 0.5f * acc[oi] + bias[o];
    }
}

extern "C" void kernel_launch(void* const* d_in, const int* in_sizes, int n_in,
                              void* d_out, int out_size, void* d_ws, size_t ws_size,
                              hipStream_t stream) {
    const float* h    = (const float*)d_in[0];
    const float* W0   = (const float*)d_in[1];
    const float* b0   = (const float*)d_in[2];
    const float* WL   = (const float*)d_in[3];
    const float* WR   = (const float*)d_in[4];
    const float* Wk   = (const float*)d_in[5];
    const float* bk   = (const float*)d_in[6];
    const float* Wc   = (const float*)d_in[7];
    const float* bias = (const float*)d_in[8];

    float* ws     = (float*)d_ws;
    float* sqp    = ws + OFF_SQP;
    int*   edge   = (int*)(ws + OFF_EDGE);
    float* s2e    = ws + OFF_S2E;
    float* w0v    = ws + OFF_W0V;
    u16*   vtb    = (u16*)(ws + OFF_VTB);
    u32*   partk  = (u32*)(ws + OFF_PARTK);
    u16*   ubar   = (u16*)(ws + OFF_UBAR);
    u16*   hht    = (u16*)(ws + OFF_UBAR);            // aliases ubar (dead before ecc)
    u16*   hlt    = hht + 25600*64;
    float* outp   = (float*)d_out;

    prep_kernel<<<dim3(16), dim3(256), 0, stream>>>(b0, WL, WR, Wk, bk, ws);
    pix_pre<<<dim3(200), dim3(256), 0, stream>>>(h, W0, w0v, sqp, hht, hlt);
    topk_mfma<<<dim3(1600), dim3(512), 0, stream>>>(hht, hlt, sqp, partk);
    topk_merge<<<dim3(100), dim3(256), 0, stream>>>(partk, sqp, edge, s2e);
    vt_pre<<<dim3(200), dim3(256), 0, stream>>>(h, ws, vtb);   // overwrites part region
    ecc_kernel<<<dim3(1600), dim3(128), 0, stream>>>(ws, edge, s2e, vtb, ubar);
    wl_kernel<<<dim3(200), dim3(256), 0, stream>>>(ws, ubar, outp);
    conv_kernel<<<dim3(480), dim3(320), 0, stream>>>(h, Wc, bias, outp);
}

// Round 12
// 230.785 us; speedup vs baseline: 2.9452x; 1.1037x over previous
//
#include <hip/hip_runtime.h>

#define CC    48
#define HH    160
#define WWID  160
#define NPIX  25600
#define KK    8

typedef unsigned short u16;
typedef unsigned int u32;
typedef __attribute__((ext_vector_type(8))) short bf16x8;
typedef __attribute__((ext_vector_type(4))) float f32x4;

__device__ __forceinline__ float bf2f(u16 u) {
    return __uint_as_float(((unsigned int)u) << 16);
}
__device__ __forceinline__ u16 f2bf(float f) {
    unsigned int x = __float_as_uint(f);
    return (u16)((x + 0x7FFFu + ((x >> 16) & 1u)) >> 16);
}

// ws float-offset layout (high-water 25.2 MB, proven)
#define OFF_B0    0        // 48
#define OFF_BK    48       // 12
#define OFF_WKT   60       // 576    wkt[c*12+r] = Wk[r][c]
#define OFF_WRT   636      // 9216   wrt[cp*192 + i] = WR[i][cp]
#define OFF_WLT   9852     // 9216   wlt[cp*192 + i] = WL[i][cp]
#define OFF_SQP   19068    // 25600
#define OFF_EDGE  44668    // int[204800]
#define OFF_S2E   249468   // float[204800]
#define OFF_W0V   454268   // float[25600*48]
#define OFF_VTB   1683068  // u16[25600*192] bf16 (aliases PARTK; written after merge)
#define OFF_PARTK 1683068  // u32[25600*64] packed keys, chunk-major [c][n][8]
#define OFF_UBAR  4140668  // u16[25600*192] bf16 (written by ecc)
// hht/hlt (u16[25600*64] each) alias UBAR region: live pix_pre..topk_mfma.

__global__ void prep_kernel(const float* b0, const float* WL, const float* WR,
                            const float* Wk, const float* bk, float* ws) {
    float* b0f  = ws + OFF_B0;
    float* bkf  = ws + OFF_BK;
    float* wkt  = ws + OFF_WKT;
    float* wrt  = ws + OFF_WRT;
    float* wlt  = ws + OFF_WLT;
    int t = blockIdx.x * 256 + threadIdx.x;
    int stride = gridDim.x * 256;
    for (int i = t; i < 9216; i += stride) {
        int cp = i / 192, r = i % 192;
        wrt[i] = WR[r*48 + cp];
        wlt[i] = WL[r*48 + cp];
    }
    for (int i = t; i < 576; i += stride) { int c = i / 12, r = i % 12; wkt[i] = Wk[r*48 + c]; }
    for (int i = t; i < 48; i += stride) { b0f[i] = b0[i]; }
    for (int i = t; i < 12; i += stride) { bkf[i] = bk[i]; }
}

// per-pixel: sq (q0), bf16 hi/lo split (q0/q1, 24 ch each), W0V rows q*12..q*12+11
__global__ __launch_bounds__(256) void pix_pre(const float* h, const float* W0,
                                               float* w0v, float* sqp,
                                               u16* hht, u16* hlt) {
    int tid = threadIdx.x;
    int p = blockIdx.x * 64 + (tid & 63);
    int q = tid >> 6;    // 0..3, wave-uniform
    float f[48];
    #pragma unroll
    for (int c = 0; c < 48; c++) f[c] = h[c*NPIX + p];

    if (q == 0) {
        float sq = 0.f;
        #pragma unroll
        for (int c = 0; c < 48; c++) sq = fmaf(f[c], f[c], sq);
        sqp[p] = sq;
    }
    if (q < 2) {
        u16 hi24[24], lo24[24];
        #pragma unroll
        for (int k = 0; k < 24; k++) {
            float v = f[q*24 + k];
            u16 hi = f2bf(v);
            hi24[k] = hi;
            lo24[k] = f2bf(v - bf2f(hi));
        }
        uint4* dh = (uint4*)&hht[(long)p*64 + q*24];
        uint4* dl = (uint4*)&hlt[(long)p*64 + q*24];
        const uint4* sh4 = (const uint4*)hi24;
        const uint4* sl4 = (const uint4*)lo24;
        dh[0] = sh4[0]; dh[1] = sh4[1]; dh[2] = sh4[2];
        dl[0] = sl4[0]; dl[1] = sl4[1]; dl[2] = sl4[2];
        if (q == 1) {
            uint4 z = make_uint4(0, 0, 0, 0);
            uint4* zh = (uint4*)&hht[(long)p*64 + 48];
            uint4* zl = (uint4*)&hlt[(long)p*64 + 48];
            zh[0] = z; zh[1] = z;
            zl[0] = z; zl[1] = z;
        }
    }

    for (int o = q*12; o < q*12 + 12; o++) {
        const float* wr = W0 + o*48;
        float a0 = 0.f, a1 = 0.f, a2 = 0.f, a3 = 0.f;
        #pragma unroll
        for (int c4 = 0; c4 < 12; c4++) {
            a0 = fmaf(wr[c4*4+0], f[c4*4+0], a0);
            a1 = fmaf(wr[c4*4+1], f[c4*4+1], a1);
            a2 = fmaf(wr[c4*4+2], f[c4*4+2], a2);
            a3 = fmaf(wr[c4*4+3], f[c4*4+3], a3);
        }
        w0v[(long)p*48 + o] = (a0 + a1) + (a2 + a3);
    }
}

// per-pixel: VT[p][cp*4+q] (cp-quarter of 12 per wave), stored bf16
__global__ __launch_bounds__(256) void vt_pre(const float* h, const float* ws, u16* vtb) {
    const float* wrt = ws + OFF_WRT;
    int tid = threadIdx.x;
    int p = blockIdx.x * 64 + (tid & 63);
    int cpb = (tid >> 6) * 12;   // wave-uniform
    float f[48];
    #pragma unroll
    for (int c = 0; c < 48; c++) f[c] = h[c*NPIX + p];
    u16* vrow = vtb + (long)p * 192;
    for (int cp = cpb; cp < cpb + 12; cp++) {
        const float* wr = wrt + cp * 192;
        float v0 = 0.f, v1 = 0.f, v2 = 0.f, v3 = 0.f;
        #pragma unroll
        for (int c = 0; c < 48; c++) {
            float vc = f[c];
            v0 = fmaf(wr[4*c+0], vc, v0);
            v1 = fmaf(wr[4*c+1], vc, v1);
            v2 = fmaf(wr[4*c+2], vc, v2);
            v3 = fmaf(wr[4*c+3], vc, v3);
        }
        ushort4 st;
        st.x = f2bf(v0); st.y = f2bf(v1); st.z = f2bf(v2); st.w = f2bf(v3);
        *(ushort4*)&vrow[cp*4] = st;
    }
}

// ---- topk stage 1 (MFMA Gram, packed-key bubble selection, XCD-swizzled) ----
__global__ __launch_bounds__(512, 8) void topk_mfma(const u16* hht, const u16* hlt,
                                                    const float* sqp, u32* partk) {
    __shared__ u16 ca_hi[128*64];
    __shared__ u16 ca_lo[128*64];
    __shared__ float sq_s[128];

    int tid = threadIdx.x;
    int b = (blockIdx.x & 7) * 200 + (blockIdx.x >> 3);   // bijective XCD swizzle (1600=8x200)
    int chunk = b & 7, pg = (b >> 3) & 7, win = b >> 6;
    int wi = win / 5, wj = win % 5;
    int base = wi*32*WWID + wj*32;

    #pragma unroll
    for (int r = 0; r < 2; r++) {
        int task = r*512 + tid;
        int blk = task >> 7, row = task & 127;
        int swz = (blk ^ (row & 7)) * 8;
        int ml = chunk*128 + row;
        long gp = base + (ml>>5)*WWID + (ml&31);
        *(uint4*)&ca_hi[row*64 + swz] = *(const uint4*)&hht[gp*64 + blk*8];
        *(uint4*)&ca_lo[row*64 + swz] = *(const uint4*)&hlt[gp*64 + blk*8];
    }
    if (tid < 128) {
        int ml = chunk*128 + tid;
        sq_s[tid] = sqp[base + (ml>>5)*WWID + (ml&31)];
    }
    __syncthreads();

    int w = tid >> 6, lane = tid & 63;
    int lm = lane & 15, lg = lane >> 4;

    int nl = pg*128 + w*16 + lm;
    long gpx = base + (nl>>5)*WWID + (nl&31);

    f32x4 acc[8];
    #pragma unroll
    for (int t = 0; t < 8; t++) acc[t] = (f32x4){0.f, 0.f, 0.f, 0.f};

    #pragma unroll
    for (int s = 0; s < 2; s++) {
        int lblk = 4*s + lg;
        int ko = lblk * 8;
        bf16x8 bh = *(const bf16x8*)&hht[gpx*64 + ko];
        bf16x8 bl = *(const bf16x8*)&hlt[gpx*64 + ko];
        #pragma unroll
        for (int t = 0; t < 8; t++) {
            int aoff = (t*16 + lm)*64 + (lblk ^ (lm & 7))*8;
            bf16x8 ah = *(const bf16x8*)&ca_hi[aoff];
            bf16x8 al = *(const bf16x8*)&ca_lo[aoff];
            acc[t] = __builtin_amdgcn_mfma_f32_16x16x32_bf16(ah, bh, acc[t], 0, 0, 0);
            acc[t] = __builtin_amdgcn_mfma_f32_16x16x32_bf16(ah, bl, acc[t], 0, 0, 0);
            acc[t] = __builtin_amdgcn_mfma_f32_16x16x32_bf16(al, bh, acc[t], 0, 0, 0);
        }
    }

    int rn = nl >> 5, cn = nl & 31;
    int rowok[8], colok[8];
    #pragma unroll
    for (int t = 0; t < 8; t++) {
        int rm = chunk*4 + (t >> 1);
        int dr = rn - rm; dr = dr < 0 ? -dr : dr;
        rowok[t] = (dr <= 1);
    }
    #pragma unroll
    for (int j = 0; j < 8; j++) {
        int cm = (j >> 2)*16 + lg*4 + (j & 3);
        int dc = cn - cm; dc = dc < 0 ? -dc : dc;
        colok[j] = (dc <= 1);
    }

    u32 k8[8];
    #pragma unroll
    for (int s = 0; s < 8; s++) k8[s] = 0xFFFFFFFFu;

    #pragma unroll
    for (int t = 0; t < 8; t++) {
        #pragma unroll
        for (int r = 0; r < 4; r++) {
            int cl = t*16 + lg*4 + r;
            int ml = chunk*128 + cl;
            float d = fmaf(-2.0f, acc[t][r], sq_s[cl]);
            u32 u = __float_as_uint(d);
            u32 key = u ^ (0x80000000u | (u32)((int)u >> 31));
            key = (key & 0xFFFFFC00u) | (u32)ml;
            bool bad = rowok[t] && colok[(t & 1)*4 + r];
            key = bad ? 0xFFFFFFFFu : key;
            #pragma unroll
            for (int s = 0; s < 8; s++) {
                u32 lo = min(k8[s], key);
                u32 hi = max(k8[s], key);
                k8[s] = lo; key = hi;
            }
        }
    }

    #pragma unroll
    for (int st = 0; st < 2; st++) {
        int mk = (st == 0) ? 16 : 32;
        u32 o[8];
        #pragma unroll
        for (int s = 0; s < 8; s++) o[s] = (u32)__shfl_xor((int)k8[s], mk, 64);
        u32 c0 = min(k8[0], o[7]);
        u32 c1 = min(k8[1], o[6]);
        u32 c2 = min(k8[2], o[5]);
        u32 c3 = min(k8[3], o[4]);
        u32 c4 = min(k8[4], o[3]);
        u32 c5 = min(k8[5], o[2]);
        u32 c6 = min(k8[6], o[1]);
        u32 c7 = min(k8[7], o[0]);
        u32 a, bb;
        a = min(c0,c4); bb = max(c0,c4); c0 = a; c4 = bb;
        a = min(c1,c5); bb = max(c1,c5); c1 = a; c5 = bb;
        a = min(c2,c6); bb = max(c2,c6); c2 = a; c6 = bb;
        a = min(c3,c7); bb = max(c3,c7); c3 = a; c7 = bb;
        a = min(c0,c2); bb = max(c0,c2); c0 = a; c2 = bb;
        a = min(c1,c3); bb = max(c1,c3); c1 = a; c3 = bb;
        a = min(c4,c6); bb = max(c4,c6); c4 = a; c6 = bb;
        a = min(c5,c7); bb = max(c5,c7); c5 = a; c7 = bb;
        a = min(c0,c1); bb = max(c0,c1); c0 = a; c1 = bb;
        a = min(c2,c3); bb = max(c2,c3); c2 = a; c3 = bb;
        a = min(c4,c5); bb = max(c4,c5); c4 = a; c5 = bb;
        a = min(c6,c7); bb = max(c6,c7); c6 = a; c7 = bb;
        k8[0]=c0; k8[1]=c1; k8[2]=c2; k8[3]=c3; k8[4]=c4; k8[5]=c5; k8[6]=c6; k8[7]=c7;
    }

    if (lg == 0) {
        int n = base + (nl >> 5)*WWID + (nl & 31);
        u32* pk = partk + (long)chunk*NPIX*8 + (long)n*8;
        #pragma unroll
        for (int s = 0; s < 8; s++) pk[s] = k8[s];
    }
}

// ---- topk stage 2: merge 8 chunk-lists of 8 keys -> top8; decode idx + d ----
__global__ __launch_bounds__(256) void topk_merge(const u32* partk, const float* sqp,
                                                  int* edge, float* s2e) {
    int n = blockIdx.x * 256 + threadIdx.x;
    u32 k8[8];
    #pragma unroll
    for (int s = 0; s < 8; s++) k8[s] = 0xFFFFFFFFu;
    for (int c = 0; c < 8; c++) {
        const u32* pk = partk + (long)c*NPIX*8 + (long)n*8;
        #pragma unroll
        for (int j = 0; j < 8; j++) {
            u32 key = pk[j];
            #pragma unroll
            for (int s = 0; s < 8; s++) {
                u32 lo = min(k8[s], key);
                u32 hi = max(k8[s], key);
                k8[s] = lo; key = hi;
            }
        }
    }
    int y = n / WWID, x = n % WWID;
    int wy = (y >> 5) << 5, wx = (x >> 5) << 5;
    float sqn = sqp[n];
    #pragma unroll
    for (int s = 0; s < 8; s++) {
        u32 key = k8[s];
        int ml = (int)(key & 1023u);
        u32 uf = key & 0xFFFFFC00u;
        u32 u = (uf & 0x80000000u) ? (uf ^ 0x80000000u) : ~uf;
        float d = __uint_as_float(u);
        edge[n*8 + s] = (wy + (ml >> 5)) * WWID + (wx + (ml & 31));
        s2e[n*8 + s] = d + sqn;
    }
}

// ---- ecc: register-theta, bf16 theta LDS (phase B only), shfl tmp/gamma, XCD swizzle ----
__global__ __launch_bounds__(128, 4) void ecc_kernel(const float* ws, const int* edge,
                                                     const float* s2e, const u16* vtb,
                                                     u16* ubar) {
    const float* b0f = ws + OFF_B0;
    const float* bkf = ws + OFF_BK;
    const float* wkt = ws + OFF_WKT;
    const float* w0v = ws + OFF_W0V;

    __shared__ u16 th_s[128][50];   // theta bf16, row stride 100 B

    int tid = threadIdx.x;
    int sb = (blockIdx.x & 7) * 200 + (blockIdx.x >> 3);   // bijective XCD swizzle
    int gt = sb * 128 + tid;        // edge id = n*8+k
    int n = gt >> 3;
    int m = edge[gt];

    float th[48];
    {
        const float4* wm4 = (const float4*)(w0v + (long)m * 48);
        const float4* wn4 = (const float4*)(w0v + (long)n * 48);
        #pragma unroll
        for (int i = 0; i < 12; i++) {
            float4 a = wm4[i];
            float4 b = wn4[i];
            float x0 = a.x - b.x + b0f[4*i+0];
            float x1 = a.y - b.y + b0f[4*i+1];
            float x2 = a.z - b.z + b0f[4*i+2];
            float x3 = a.w - b.w + b0f[4*i+3];
            th[4*i+0] = (x0 >= 0.f) ? x0 : 0.01f * x0;
            th[4*i+1] = (x1 >= 0.f) ? x1 : 0.01f * x1;
            th[4*i+2] = (x2 >= 0.f) ? x2 : 0.01f * x2;
            th[4*i+3] = (x3 >= 0.f) ? x3 : 0.01f * x3;
        }
    }
    float gamma = expf(-s2e[gt] * 0.1f);

    #pragma unroll
    for (int i = 0; i < 24; i++) {
        ushort2 pr;
        pr.x = f2bf(th[2*i]);
        pr.y = f2bf(th[2*i+1]);
        *(ushort2*)&th_s[tid][2*i] = pr;
    }

    float kap[12];
    #pragma unroll
    for (int r = 0; r < 12; r++) kap[r] = bkf[r];
    #pragma unroll
    for (int c = 0; c < 48; c++) {
        float t = th[c];
        const float* wkc = wkt + c*12;
        #pragma unroll
        for (int r = 0; r < 12; r++) kap[r] = fmaf(wkc[r], t, kap[r]);
    }

    float sr[12];
    #pragma unroll
    for (int r = 0; r < 12; r++) sr[r] = 0.f;
    const u16* vrow = vtb + (long)m * 192;
    #pragma unroll
    for (int j = 0; j < 24; j++) {
        uint4 vv = *(const uint4*)&vrow[j*8];
        #pragma unroll
        for (int half = 0; half < 2; half++) {
            int cp = 2*j + half;
            u32 w0_ = half ? vv.z : vv.x;
            u32 w1_ = half ? vv.w : vv.y;
            float vx = bf2f((u16)(w0_ & 0xffff));
            float vy = bf2f((u16)(w0_ >> 16));
            float vz = bf2f((u16)(w1_ & 0xffff));
            float vw = bf2f((u16)(w1_ >> 16));
            int i1 = (cp + 1 < 48) ? cp + 1 : cp - 47;
            int i2 = (cp + 2 < 48) ? cp + 2 : cp - 46;
            float t0 = th[cp], t1 = th[i1], t2 = th[i2];
            sr[0] = fmaf(t0, vx, sr[0]); sr[1]  = fmaf(t1, vx, sr[1]);  sr[2]  = fmaf(t2, vx, sr[2]);
            sr[3] = fmaf(t0, vy, sr[3]); sr[4]  = fmaf(t1, vy, sr[4]);  sr[5]  = fmaf(t2, vy, sr[5]);
            sr[6] = fmaf(t0, vz, sr[6]); sr[7]  = fmaf(t1, vz, sr[7]);  sr[8]  = fmaf(t2, vz, sr[8]);
            sr[9] = fmaf(t0, vw, sr[9]); sr[10] = fmaf(t1, vw, sr[10]); sr[11] = fmaf(t2, vw, sr[11]);
        }
    }

    float tmp[12];
    #pragma unroll
    for (int r = 0; r < 12; r++) tmp[r] = kap[r] * sr[r];

    __syncthreads();

    int pix = tid >> 3, sh = tid & 7;
    float acc0[6], acc1[6], acc2[6], acc3[6];
    #pragma unroll
    for (int j = 0; j < 6; j++) { acc0[j] = 0.f; acc1[j] = 0.f; acc2[j] = 0.f; acc3[j] = 0.f; }
    #pragma unroll 1
    for (int e = 0; e < 8; e++) {
        int srcl = (tid & 56) + e;
        int row  = (tid & 120) + e;
        float tm[12];
        #pragma unroll
        for (int r = 0; r < 12; r++) tm[r] = __shfl(tmp[r], srcl, 64);
        float ge = __shfl(gamma, srcl, 64);
        #pragma unroll
        for (int j = 0; j < 6; j++) {
            int cp = sh + 8*j;
            int i1 = (cp + 1 < 48) ? cp + 1 : cp - 47;
            int i2 = (cp + 2 < 48) ? cp + 2 : cp - 46;
            float t0 = bf2f(th_s[row][cp]);
            float t1 = bf2f(th_s[row][i1]);
            float t2 = bf2f(th_s[row][i2]);
            float u0 = tm[0]*t0 + tm[1]*t1 + tm[2]*t2;
            float u1 = tm[3]*t0 + tm[4]*t1 + tm[5]*t2;
            float u2 = tm[6]*t0 + tm[7]*t1 + tm[8]*t2;
            float u3 = tm[9]*t0 + tm[10]*t1 + tm[11]*t2;
            acc0[j] = fmaf(ge, u0, acc0[j]);
            acc1[j] = fmaf(ge, u1, acc1[j]);
            acc2[j] = fmaf(ge, u2, acc2[j]);
            acc3[j] = fmaf(ge, u3, acc3[j]);
        }
    }
    u16* ub = ubar + (long)(sb * 16 + pix) * 192;
    #pragma unroll
    for (int j = 0; j < 6; j++) {
        int cp = sh + 8*j;
        ushort4 st;
        st.x = f2bf(acc0[j]); st.y = f2bf(acc1[j]);
        st.z = f2bf(acc2[j]); st.w = f2bf(acc3[j]);
        *(ushort4*)&ub[cp*4] = st;
    }
}

// ---- wl: 64 pixels x 4 wave-uniform 12-output groups per block; writes 0.5*hNL ----
__global__ __launch_bounds__(256) void wl_kernel(const float* ws, const u16* ubar, float* outp) {
    const float* wlt = ws + OFF_WLT;
    int tid = threadIdx.x;
    int p = blockIdx.x * 64 + (tid & 63);
    int ob = (tid >> 6) * 12;          // wave-uniform -> scalar WL loads
    const u16* ub = ubar + (long)p * 192;
    float out[12];
    #pragma unroll
    for (int o = 0; o < 12; o++) out[o] = 0.f;
    for (int j = 0; j < 24; j++) {     // 2 cp per uint4
        uint4 vv = *(const uint4*)&ub[j*8];
        #pragma unroll
        for (int half = 0; half < 2; half++) {
            int cp = 2*j + half;
            u32 a_ = half ? vv.z : vv.x;
            u32 b_ = half ? vv.w : vv.y;
            float ux = bf2f((u16)(a_ & 0xffff));
            float uy = bf2f((u16)(a_ >> 16));
            float uz = bf2f((u16)(b_ & 0xffff));
            float uw = bf2f((u16)(b_ >> 16));
            const float* wl = wlt + cp * 192 + ob * 4;
            #pragma unroll
            for (int o = 0; o < 12; o++) {
                float a = out[o];
                a = fmaf(wl[4*o+0], ux, a);
                a = fmaf(wl[4*o+1], uy, a);
                a = fmaf(wl[4*o+2], uz, a);
                a = fmaf(wl[4*o+3], uw, a);
                out[o] = a;
            }
        }
    }
    #pragma unroll
    for (int o = 0; o < 12; o++) outp[(ob + o)*NPIX + p] = 0.0625f * out[o];  // 0.5 * (1/8)
}

// ---- conv 3x3 (reflect pad), 8 output channels per thread, adds 0.5*hL + bias ----
#define OCH 8
__global__ __launch_bounds__(320) void conv_kernel(const float* h, const float* wc,
                                                   const float* bias, float* outp) {
    int og = blockIdx.x % 6;
    int yp = blockIdx.x / 6;
    int t  = threadIdx.x;
    int ty = t / 160;
    int x  = t % 160;
    int y  = yp * 2 + ty;

    int idx9[9];
    #pragma unroll
    for (int dy = 0; dy < 3; dy++) {
        int yy = y + dy - 1;
        yy = yy < 0 ? -yy : (yy >= HH ? 2*HH - 2 - yy : yy);
        #pragma unroll
        for (int dx = 0; dx < 3; dx++) {
            int xx = x + dx - 1;
            xx = xx < 0 ? -xx : (xx >= WWID ? 2*WWID - 2 - xx : xx);
            idx9[dy*3 + dx] = yy * WWID + xx;
        }
    }

    float acc[OCH];
    #pragma unroll
    for (int oi = 0; oi < OCH; oi++) acc[oi] = 0.f;

    const float* wbase = wc + og * OCH * 432;
    for (int c = 0; c < 48; c++) {
        float v[9];
        #pragma unroll
        for (int k = 0; k < 9; k++) v[k] = h[c*NPIX + idx9[k]];
        #pragma unroll
        for (int oi = 0; oi < OCH; oi++) {
            const float* w9 = wbase + oi*432 + c*9;
            float a = acc[oi];
            a = fmaf(v[0], w9[0], a);
            a = fmaf(v[1], w9[1], a);
            a = fmaf(v[2], w9[2], a);
            a = fmaf(v[3], w9[3], a);
            a = fmaf(v[4], w9[4], a);
            a = fmaf(v[5], w9[5], a);
            a = fmaf(v[6], w9[6], a);
            a = fmaf(v[7], w9[7], a);
            a = fmaf(v[8], w9[8], a);
            acc[oi] = a;
        }
    }

    int p = y * WWID + x;
    #pragma unroll
    for (int oi = 0; oi < OCH; oi++) {
        int o = og * OCH + oi;
        outp[o*NPIX + p] = outp[o*NPIX + p] + 0.5f * acc[oi] + bias[o];
    }
}

extern "C" void kernel_launch(void* const* d_in, const int* in_sizes, int n_in,
                              void* d_out, int out_size, void* d_ws, size_t ws_size,
                              hipStream_t stream) {
    const float* h    = (const float*)d_in[0];
    const float* W0   = (const float*)d_in[1];
    const float* b0   = (const float*)d_in[2];
    const float* WL   = (const float*)d_in[3];
    const float* WR   = (const float*)d_in[4];
    const float* Wk   = (const float*)d_in[5];
    const float* bk   = (const float*)d_in[6];
    const float* Wc   = (const float*)d_in[7];
    const float* bias = (const float*)d_in[8];

    float* ws     = (float*)d_ws;
    float* sqp    = ws + OFF_SQP;
    int*   edge   = (int*)(ws + OFF_EDGE);
    float* s2e    = ws + OFF_S2E;
    float* w0v    = ws + OFF_W0V;
    u16*   vtb    = (u16*)(ws + OFF_VTB);
    u32*   partk  = (u32*)(ws + OFF_PARTK);
    u16*   ubar   = (u16*)(ws + OFF_UBAR);
    u16*   hht    = (u16*)(ws + OFF_UBAR);            // aliases ubar (dead before ecc)
    u16*   hlt    = hht + 25600*64;
    float* outp   = (float*)d_out;

    prep_kernel<<<dim3(16), dim3(256), 0, stream>>>(b0, WL, WR, Wk, bk, ws);
    pix_pre<<<dim3(400), dim3(256), 0, stream>>>(h, W0, w0v, sqp, hht, hlt);
    topk_mfma<<<dim3(1600), dim3(512), 0, stream>>>(hht, hlt, sqp, partk);
    topk_merge<<<dim3(100), dim3(256), 0, stream>>>(partk, sqp, edge, s2e);
    vt_pre<<<dim3(400), dim3(256), 0, stream>>>(h, ws, vtb);   // overwrites part region
    ecc_kernel<<<dim3(1600), dim3(128), 0, stream>>>(ws, edge, s2e, vtb, ubar);
    wl_kernel<<<dim3(400), dim3(256), 0, stream>>>(ws, ubar, outp);
    conv_kernel<<<dim3(480), dim3(320), 0, stream>>>(h, Wc, bias, outp);
}

// Round 13
// 222.546 us; speedup vs baseline: 3.0542x; 1.0370x over previous
//
#include <hip/hip_runtime.h>

#define CC    48
#define HH    160
#define WWID  160
#define NPIX  25600
#define KK    8

typedef unsigned short u16;
typedef unsigned int u32;
typedef __attribute__((ext_vector_type(8))) short bf16x8;
typedef __attribute__((ext_vector_type(4))) float f32x4;

__device__ __forceinline__ float bf2f(u16 u) {
    return __uint_as_float(((unsigned int)u) << 16);
}
__device__ __forceinline__ u16 f2bf(float f) {
    unsigned int x = __float_as_uint(f);
    return (u16)((x + 0x7FFFu + ((x >> 16) & 1u)) >> 16);
}

// ws float-offset layout (high-water 25.2 MB, proven)
#define OFF_B0    0        // 48
#define OFF_BK    48       // 12
#define OFF_WKT   60       // 576    wkt[c*12+r] = Wk[r][c]
#define OFF_WRT   636      // 9216   wrt[cp*192 + i] = WR[i][cp]
#define OFF_WLT   9852     // 9216   wlt[cp*192 + i] = WL[i][cp]
#define OFF_SQP   19068    // 25600
#define OFF_EDGE  44668    // int[204800]
#define OFF_S2E   249468   // float[204800]
#define OFF_W0V   454268   // float[25600*48]
#define OFF_VTB   1683068  // u16[25600*192] bf16 (aliases PARTK; written after merge)
#define OFF_PARTK 1683068  // u32[8][8][NPIX] packed keys
#define OFF_UBAR  4140668  // u16[25600*192] bf16 (written by ecc)
// hht/hlt (u16[25600*64] each) alias UBAR region: live pix_pre..topk_mfma.

__global__ void prep_kernel(const float* b0, const float* WL, const float* WR,
                            const float* Wk, const float* bk, float* ws) {
    float* b0f  = ws + OFF_B0;
    float* bkf  = ws + OFF_BK;
    float* wkt  = ws + OFF_WKT;
    float* wrt  = ws + OFF_WRT;
    float* wlt  = ws + OFF_WLT;
    int t = blockIdx.x * 256 + threadIdx.x;
    int stride = gridDim.x * 256;
    for (int i = t; i < 9216; i += stride) {
        int cp = i / 192, r = i % 192;
        wrt[i] = WR[r*48 + cp];
        wlt[i] = WL[r*48 + cp];
    }
    for (int i = t; i < 576; i += stride) { int c = i / 12, r = i % 12; wkt[i] = Wk[r*48 + c]; }
    for (int i = t; i < 48; i += stride) { b0f[i] = b0[i]; }
    for (int i = t; i < 12; i += stride) { bkf[i] = bk[i]; }
}

// per-pixel: sq (q0), bf16 hi/lo split (q0/q1, 24 ch each), W0V rows q*12..q*12+11
__global__ __launch_bounds__(256) void pix_pre(const float* h, const float* W0,
                                               float* w0v, float* sqp,
                                               u16* hht, u16* hlt) {
    int tid = threadIdx.x;
    int p = blockIdx.x * 64 + (tid & 63);
    int q = tid >> 6;    // 0..3, wave-uniform
    float f[48];
    #pragma unroll
    for (int c = 0; c < 48; c++) f[c] = h[c*NPIX + p];

    if (q == 0) {
        float sq = 0.f;
        #pragma unroll
        for (int c = 0; c < 48; c++) sq = fmaf(f[c], f[c], sq);
        sqp[p] = sq;
    }
    if (q < 2) {
        u16 hi24[24], lo24[24];
        #pragma unroll
        for (int k = 0; k < 24; k++) {
            float v = f[q*24 + k];
            u16 hi = f2bf(v);
            hi24[k] = hi;
            lo24[k] = f2bf(v - bf2f(hi));
        }
        uint4* dh = (uint4*)&hht[(long)p*64 + q*24];
        uint4* dl = (uint4*)&hlt[(long)p*64 + q*24];
        const uint4* sh4 = (const uint4*)hi24;
        const uint4* sl4 = (const uint4*)lo24;
        dh[0] = sh4[0]; dh[1] = sh4[1]; dh[2] = sh4[2];
        dl[0] = sl4[0]; dl[1] = sl4[1]; dl[2] = sl4[2];
        if (q == 1) {
            uint4 z = make_uint4(0, 0, 0, 0);
            uint4* zh = (uint4*)&hht[(long)p*64 + 48];
            uint4* zl = (uint4*)&hlt[(long)p*64 + 48];
            zh[0] = z; zh[1] = z;
            zl[0] = z; zl[1] = z;
        }
    }

    for (int o = q*12; o < q*12 + 12; o++) {
        const float* wr = W0 + o*48;
        float a0 = 0.f, a1 = 0.f, a2 = 0.f, a3 = 0.f;
        #pragma unroll
        for (int c4 = 0; c4 < 12; c4++) {
            a0 = fmaf(wr[c4*4+0], f[c4*4+0], a0);
            a1 = fmaf(wr[c4*4+1], f[c4*4+1], a1);
            a2 = fmaf(wr[c4*4+2], f[c4*4+2], a2);
            a3 = fmaf(wr[c4*4+3], f[c4*4+3], a3);
        }
        w0v[(long)p*48 + o] = (a0 + a1) + (a2 + a3);
    }
}

// per-pixel: VT[p][cp*4+q] (cp-quarter of 12 per wave), stored bf16
__global__ __launch_bounds__(256) void vt_pre(const float* h, const float* ws, u16* vtb) {
    const float* wrt = ws + OFF_WRT;
    int tid = threadIdx.x;
    int p = blockIdx.x * 64 + (tid & 63);
    int cpb = (tid >> 6) * 12;   // wave-uniform
    float f[48];
    #pragma unroll
    for (int c = 0; c < 48; c++) f[c] = h[c*NPIX + p];
    u16* vrow = vtb + (long)p * 192;
    for (int cp = cpb; cp < cpb + 12; cp++) {
        const float* wr = wrt + cp * 192;
        float v0 = 0.f, v1 = 0.f, v2 = 0.f, v3 = 0.f;
        #pragma unroll
        for (int c = 0; c < 48; c++) {
            float vc = f[c];
            v0 = fmaf(wr[4*c+0], vc, v0);
            v1 = fmaf(wr[4*c+1], vc, v1);
            v2 = fmaf(wr[4*c+2], vc, v2);
            v3 = fmaf(wr[4*c+3], vc, v3);
        }
        ushort4 st;
        st.x = f2bf(v0); st.y = f2bf(v1); st.z = f2bf(v2); st.w = f2bf(v3);
        *(ushort4*)&vrow[cp*4] = st;
    }
}

// ---- topk stage 1 (MFMA Gram, packed-key bubble selection, XCD-swizzled) ----
__global__ __launch_bounds__(512, 8) void topk_mfma(const u16* hht, const u16* hlt,
                                                    const float* sqp, u32* partk) {
    __shared__ u16 ca_hi[128*64];
    __shared__ u16 ca_lo[128*64];
    __shared__ float sq_s[128];

    int tid = threadIdx.x;
    int b = (blockIdx.x & 7) * 200 + (blockIdx.x >> 3);   // bijective XCD swizzle (1600=8x200)
    int chunk = b & 7, pg = (b >> 3) & 7, win = b >> 6;
    int wi = win / 5, wj = win % 5;
    int base = wi*32*WWID + wj*32;

    #pragma unroll
    for (int r = 0; r < 2; r++) {
        int task = r*512 + tid;
        int blk = task >> 7, row = task & 127;
        int swz = (blk ^ (row & 7)) * 8;
        int ml = chunk*128 + row;
        long gp = base + (ml>>5)*WWID + (ml&31);
        *(uint4*)&ca_hi[row*64 + swz] = *(const uint4*)&hht[gp*64 + blk*8];
        *(uint4*)&ca_lo[row*64 + swz] = *(const uint4*)&hlt[gp*64 + blk*8];
    }
    if (tid < 128) {
        int ml = chunk*128 + tid;
        sq_s[tid] = sqp[base + (ml>>5)*WWID + (ml&31)];
    }
    __syncthreads();

    int w = tid >> 6, lane = tid & 63;
    int lm = lane & 15, lg = lane >> 4;

    int nl = pg*128 + w*16 + lm;
    long gpx = base + (nl>>5)*WWID + (nl&31);

    f32x4 acc[8];
    #pragma unroll
    for (int t = 0; t < 8; t++) acc[t] = (f32x4){0.f, 0.f, 0.f, 0.f};

    #pragma unroll
    for (int s = 0; s < 2; s++) {
        int lblk = 4*s + lg;
        int ko = lblk * 8;
        bf16x8 bh = *(const bf16x8*)&hht[gpx*64 + ko];
        bf16x8 bl = *(const bf16x8*)&hlt[gpx*64 + ko];
        #pragma unroll
        for (int t = 0; t < 8; t++) {
            int aoff = (t*16 + lm)*64 + (lblk ^ (lm & 7))*8;
            bf16x8 ah = *(const bf16x8*)&ca_hi[aoff];
            bf16x8 al = *(const bf16x8*)&ca_lo[aoff];
            acc[t] = __builtin_amdgcn_mfma_f32_16x16x32_bf16(ah, bh, acc[t], 0, 0, 0);
            acc[t] = __builtin_amdgcn_mfma_f32_16x16x32_bf16(ah, bl, acc[t], 0, 0, 0);
            acc[t] = __builtin_amdgcn_mfma_f32_16x16x32_bf16(al, bh, acc[t], 0, 0, 0);
        }
    }

    int rn = nl >> 5, cn = nl & 31;
    int rowok[8], colok[8];
    #pragma unroll
    for (int t = 0; t < 8; t++) {
        int rm = chunk*4 + (t >> 1);
        int dr = rn - rm; dr = dr < 0 ? -dr : dr;
        rowok[t] = (dr <= 1);
    }
    #pragma unroll
    for (int j = 0; j < 8; j++) {
        int cm = (j >> 2)*16 + lg*4 + (j & 3);
        int dc = cn - cm; dc = dc < 0 ? -dc : dc;
        colok[j] = (dc <= 1);
    }

    u32 k8[8];
    #pragma unroll
    for (int s = 0; s < 8; s++) k8[s] = 0xFFFFFFFFu;

    #pragma unroll
    for (int t = 0; t < 8; t++) {
        #pragma unroll
        for (int r = 0; r < 4; r++) {
            int cl = t*16 + lg*4 + r;
            int ml = chunk*128 + cl;
            float d = fmaf(-2.0f, acc[t][r], sq_s[cl]);
            u32 u = __float_as_uint(d);
            u32 key = u ^ (0x80000000u | (u32)((int)u >> 31));
            key = (key & 0xFFFFFC00u) | (u32)ml;
            bool bad = rowok[t] && colok[(t & 1)*4 + r];
            key = bad ? 0xFFFFFFFFu : key;
            #pragma unroll
            for (int s = 0; s < 8; s++) {
                u32 lo = min(k8[s], key);
                u32 hi = max(k8[s], key);
                k8[s] = lo; key = hi;
            }
        }
    }

    // after the two merges, all 4 lg-groups hold IDENTICAL sorted k8
    #pragma unroll
    for (int st = 0; st < 2; st++) {
        int mk = (st == 0) ? 16 : 32;
        u32 o[8];
        #pragma unroll
        for (int s = 0; s < 8; s++) o[s] = (u32)__shfl_xor((int)k8[s], mk, 64);
        u32 c0 = min(k8[0], o[7]);
        u32 c1 = min(k8[1], o[6]);
        u32 c2 = min(k8[2], o[5]);
        u32 c3 = min(k8[3], o[4]);
        u32 c4 = min(k8[4], o[3]);
        u32 c5 = min(k8[5], o[2]);
        u32 c6 = min(k8[6], o[1]);
        u32 c7 = min(k8[7], o[0]);
        u32 a, bb;
        a = min(c0,c4); bb = max(c0,c4); c0 = a; c4 = bb;
        a = min(c1,c5); bb = max(c1,c5); c1 = a; c5 = bb;
        a = min(c2,c6); bb = max(c2,c6); c2 = a; c6 = bb;
        a = min(c3,c7); bb = max(c3,c7); c3 = a; c7 = bb;
        a = min(c0,c2); bb = max(c0,c2); c0 = a; c2 = bb;
        a = min(c1,c3); bb = max(c1,c3); c1 = a; c3 = bb;
        a = min(c4,c6); bb = max(c4,c6); c4 = a; c6 = bb;
        a = min(c5,c7); bb = max(c5,c7); c5 = a; c7 = bb;
        a = min(c0,c1); bb = max(c0,c1); c0 = a; c1 = bb;
        a = min(c2,c3); bb = max(c2,c3); c2 = a; c3 = bb;
        a = min(c4,c5); bb = max(c4,c5); c4 = a; c5 = bb;
        a = min(c6,c7); bb = max(c6,c7); c6 = a; c7 = bb;
        k8[0]=c0; k8[1]=c1; k8[2]=c2; k8[3]=c3; k8[4]=c4; k8[5]=c5; k8[6]=c6; k8[7]=c7;
    }

    // coalesced store: layout partk[chunk][s][NPIX]; lane (lm,lg) writes s=2*lg, 2*lg+1
    {
        int n = base + (nl >> 5)*WWID + (nl & 31);
        u32 v0, v1;
        if      (lg == 0) { v0 = k8[0]; v1 = k8[1]; }
        else if (lg == 1) { v0 = k8[2]; v1 = k8[3]; }
        else if (lg == 2) { v0 = k8[4]; v1 = k8[5]; }
        else              { v0 = k8[6]; v1 = k8[7]; }
        u32* pk = partk + (long)chunk*8*NPIX + (long)(2*lg)*NPIX + n;
        pk[0]    = v0;
        pk[NPIX] = v1;
    }
}

// ---- topk stage 2: merge 8 chunk-lists of 8 keys -> top8; decode idx + d ----
__global__ __launch_bounds__(256) void topk_merge(const u32* partk, const float* sqp,
                                                  int* edge, float* s2e) {
    int n = blockIdx.x * 256 + threadIdx.x;
    u32 k8[8];
    #pragma unroll
    for (int s = 0; s < 8; s++) k8[s] = 0xFFFFFFFFu;
    for (int c = 0; c < 8; c++) {
        const u32* pk = partk + (long)c*8*NPIX + n;
        #pragma unroll
        for (int j = 0; j < 8; j++) {
            u32 key = pk[(long)j*NPIX];
            #pragma unroll
            for (int s = 0; s < 8; s++) {
                u32 lo = min(k8[s], key);
                u32 hi = max(k8[s], key);
                k8[s] = lo; key = hi;
            }
        }
    }
    int y = n / WWID, x = n % WWID;
    int wy = (y >> 5) << 5, wx = (x >> 5) << 5;
    float sqn = sqp[n];
    #pragma unroll
    for (int s = 0; s < 8; s++) {
        u32 key = k8[s];
        int ml = (int)(key & 1023u);
        u32 uf = key & 0xFFFFFC00u;
        u32 u = (uf & 0x80000000u) ? (uf ^ 0x80000000u) : ~uf;
        float d = __uint_as_float(u);
        edge[n*8 + s] = (wy + (ml >> 5)) * WWID + (wx + (ml & 31));
        s2e[n*8 + s] = d + sqn;
    }
}

// ---- ecc: register-theta, bf16 theta LDS (phase B only), shfl tmp/gamma, XCD swizzle ----
__global__ __launch_bounds__(128, 4) void ecc_kernel(const float* ws, const int* edge,
                                                     const float* s2e, const u16* vtb,
                                                     u16* ubar) {
    const float* b0f = ws + OFF_B0;
    const float* bkf = ws + OFF_BK;
    const float* wkt = ws + OFF_WKT;
    const float* w0v = ws + OFF_W0V;

    __shared__ u16 th_s[128][50];   // theta bf16, row stride 100 B

    int tid = threadIdx.x;
    int sb = (blockIdx.x & 7) * 200 + (blockIdx.x >> 3);   // bijective XCD swizzle
    int gt = sb * 128 + tid;        // edge id = n*8+k
    int n = gt >> 3;
    int m = edge[gt];

    float th[48];
    {
        const float4* wm4 = (const float4*)(w0v + (long)m * 48);
        const float4* wn4 = (const float4*)(w0v + (long)n * 48);
        #pragma unroll
        for (int i = 0; i < 12; i++) {
            float4 a = wm4[i];
            float4 b = wn4[i];
            float x0 = a.x - b.x + b0f[4*i+0];
            float x1 = a.y - b.y + b0f[4*i+1];
            float x2 = a.z - b.z + b0f[4*i+2];
            float x3 = a.w - b.w + b0f[4*i+3];
            th[4*i+0] = (x0 >= 0.f) ? x0 : 0.01f * x0;
            th[4*i+1] = (x1 >= 0.f) ? x1 : 0.01f * x1;
            th[4*i+2] = (x2 >= 0.f) ? x2 : 0.01f * x2;
            th[4*i+3] = (x3 >= 0.f) ? x3 : 0.01f * x3;
        }
    }
    float gamma = expf(-s2e[gt] * 0.1f);

    #pragma unroll
    for (int i = 0; i < 24; i++) {
        ushort2 pr;
        pr.x = f2bf(th[2*i]);
        pr.y = f2bf(th[2*i+1]);
        *(ushort2*)&th_s[tid][2*i] = pr;
    }

    float kap[12];
    #pragma unroll
    for (int r = 0; r < 12; r++) kap[r] = bkf[r];
    #pragma unroll
    for (int c = 0; c < 48; c++) {
        float t = th[c];
        const float* wkc = wkt + c*12;
        #pragma unroll
        for (int r = 0; r < 12; r++) kap[r] = fmaf(wkc[r], t, kap[r]);
    }

    float sr[12];
    #pragma unroll
    for (int r = 0; r < 12; r++) sr[r] = 0.f;
    const u16* vrow = vtb + (long)m * 192;
    #pragma unroll
    for (int j = 0; j < 24; j++) {
        uint4 vv = *(const uint4*)&vrow[j*8];
        #pragma unroll
        for (int half = 0; half < 2; half++) {
            int cp = 2*j + half;
            u32 w0_ = half ? vv.z : vv.x;
            u32 w1_ = half ? vv.w : vv.y;
            float vx = bf2f((u16)(w0_ & 0xffff));
            float vy = bf2f((u16)(w0_ >> 16));
            float vz = bf2f((u16)(w1_ & 0xffff));
            float vw = bf2f((u16)(w1_ >> 16));
            int i1 = (cp + 1 < 48) ? cp + 1 : cp - 47;
            int i2 = (cp + 2 < 48) ? cp + 2 : cp - 46;
            float t0 = th[cp], t1 = th[i1], t2 = th[i2];
            sr[0] = fmaf(t0, vx, sr[0]); sr[1]  = fmaf(t1, vx, sr[1]);  sr[2]  = fmaf(t2, vx, sr[2]);
            sr[3] = fmaf(t0, vy, sr[3]); sr[4]  = fmaf(t1, vy, sr[4]);  sr[5]  = fmaf(t2, vy, sr[5]);
            sr[6] = fmaf(t0, vz, sr[6]); sr[7]  = fmaf(t1, vz, sr[7]);  sr[8]  = fmaf(t2, vz, sr[8]);
            sr[9] = fmaf(t0, vw, sr[9]); sr[10] = fmaf(t1, vw, sr[10]); sr[11] = fmaf(t2, vw, sr[11]);
        }
    }

    float tmp[12];
    #pragma unroll
    for (int r = 0; r < 12; r++) tmp[r] = kap[r] * sr[r];

    __syncthreads();

    int pix = tid >> 3, sh = tid & 7;
    float acc0[6], acc1[6], acc2[6], acc3[6];
    #pragma unroll
    for (int j = 0; j < 6; j++) { acc0[j] = 0.f; acc1[j] = 0.f; acc2[j] = 0.f; acc3[j] = 0.f; }
    #pragma unroll 1
    for (int e = 0; e < 8; e++) {
        int srcl = (tid & 56) + e;
        int row  = (tid & 120) + e;
        float tm[12];
        #pragma unroll
        for (int r = 0; r < 12; r++) tm[r] = __shfl(tmp[r], srcl, 64);
        float ge = __shfl(gamma, srcl, 64);
        #pragma unroll
        for (int j = 0; j < 6; j++) {
            int cp = sh + 8*j;
            int i1 = (cp + 1 < 48) ? cp + 1 : cp - 47;
            int i2 = (cp + 2 < 48) ? cp + 2 : cp - 46;
            float t0 = bf2f(th_s[row][cp]);
            float t1 = bf2f(th_s[row][i1]);
            float t2 = bf2f(th_s[row][i2]);
            float u0 = tm[0]*t0 + tm[1]*t1 + tm[2]*t2;
            float u1 = tm[3]*t0 + tm[4]*t1 + tm[5]*t2;
            float u2 = tm[6]*t0 + tm[7]*t1 + tm[8]*t2;
            float u3 = tm[9]*t0 + tm[10]*t1 + tm[11]*t2;
            acc0[j] = fmaf(ge, u0, acc0[j]);
            acc1[j] = fmaf(ge, u1, acc1[j]);
            acc2[j] = fmaf(ge, u2, acc2[j]);
            acc3[j] = fmaf(ge, u3, acc3[j]);
        }
    }
    u16* ub = ubar + (long)(sb * 16 + pix) * 192;
    #pragma unroll
    for (int j = 0; j < 6; j++) {
        int cp = sh + 8*j;
        ushort4 st;
        st.x = f2bf(acc0[j]); st.y = f2bf(acc1[j]);
        st.z = f2bf(acc2[j]); st.w = f2bf(acc3[j]);
        *(ushort4*)&ub[cp*4] = st;
    }
}

// ---- wl: 64 pixels x 4 wave-uniform 12-output groups per block; writes 0.5*hNL ----
__global__ __launch_bounds__(256) void wl_kernel(const float* ws, const u16* ubar, float* outp) {
    const float* wlt = ws + OFF_WLT;
    int tid = threadIdx.x;
    int p = blockIdx.x * 64 + (tid & 63);
    int ob = (tid >> 6) * 12;          // wave-uniform -> scalar WL loads
    const u16* ub = ubar + (long)p * 192;
    float out[12];
    #pragma unroll
    for (int o = 0; o < 12; o++) out[o] = 0.f;
    for (int j = 0; j < 24; j++) {     // 2 cp per uint4
        uint4 vv = *(const uint4*)&ub[j*8];
        #pragma unroll
        for (int half = 0; half < 2; half++) {
            int cp = 2*j + half;
            u32 a_ = half ? vv.z : vv.x;
            u32 b_ = half ? vv.w : vv.y;
            float ux = bf2f((u16)(a_ & 0xffff));
            float uy = bf2f((u16)(a_ >> 16));
            float uz = bf2f((u16)(b_ & 0xffff));
            float uw = bf2f((u16)(b_ >> 16));
            const float* wl = wlt + cp * 192 + ob * 4;
            #pragma unroll
            for (int o = 0; o < 12; o++) {
                float a = out[o];
                a = fmaf(wl[4*o+0], ux, a);
                a = fmaf(wl[4*o+1], uy, a);
                a = fmaf(wl[4*o+2], uz, a);
                a = fmaf(wl[4*o+3], uw, a);
                out[o] = a;
            }
        }
    }
    #pragma unroll
    for (int o = 0; o < 12; o++) outp[(ob + o)*NPIX + p] = 0.0625f * out[o];  // 0.5 * (1/8)
}

// ---- conv 3x3 (reflect pad), OCH=4/thread, XCD-chunked swizzle, adds 0.5*hL + bias ----
#define OCH 4
__global__ __launch_bounds__(320) void conv_kernel(const float* h, const float* wc,
                                                   const float* bias, float* outp) {
    // 960 blocks = 8 XCD x 120; XCD k owns yp in [10k,10k+10) for all 12 og groups
    int sb = (blockIdx.x & 7) * 120 + (blockIdx.x >> 3);
    int og = sb % 12;
    int yp = sb / 12;          // 0..79
    int t  = threadIdx.x;
    int ty = t / 160;
    int x  = t % 160;
    int y  = yp * 2 + ty;

    int idx9[9];
    #pragma unroll
    for (int dy = 0; dy < 3; dy++) {
        int yy = y + dy - 1;
        yy = yy < 0 ? -yy : (yy >= HH ? 2*HH - 2 - yy : yy);
        #pragma unroll
        for (int dx = 0; dx < 3; dx++) {
            int xx = x + dx - 1;
            xx = xx < 0 ? -xx : (xx >= WWID ? 2*WWID - 2 - xx : xx);
            idx9[dy*3 + dx] = yy * WWID + xx;
        }
    }

    float acc[OCH];
    #pragma unroll
    for (int oi = 0; oi < OCH; oi++) acc[oi] = 0.f;

    const float* wbase = wc + og * OCH * 432;   // block-uniform -> s_load
    for (int c = 0; c < 48; c++) {
        float v[9];
        #pragma unroll
        for (int k = 0; k < 9; k++) v[k] = h[c*NPIX + idx9[k]];
        #pragma unroll
        for (int oi = 0; oi < OCH; oi++) {
            const float* w9 = wbase + oi*432 + c*9;
            float a = acc[oi];
            a = fmaf(v[0], w9[0], a);
            a = fmaf(v[1], w9[1], a);
            a = fmaf(v[2], w9[2], a);
            a = fmaf(v[3], w9[3], a);
            a = fmaf(v[4], w9[4], a);
            a = fmaf(v[5], w9[5], a);
            a = fmaf(v[6], w9[6], a);
            a = fmaf(v[7], w9[7], a);
            a = fmaf(v[8], w9[8], a);
            acc[oi] = a;
        }
    }

    int p = y * WWID + x;
    #pragma unroll
    for (int oi = 0; oi < OCH; oi++) {
        int o = og * OCH + oi;
        outp[o*NPIX + p] = outp[o*NPIX + p] + 0.5f * acc[oi] + bias[o];
    }
}

extern "C" void kernel_launch(void* const* d_in, const int* in_sizes, int n_in,
                              void* d_out, int out_size, void* d_ws, size_t ws_size,
                              hipStream_t stream) {
    const float* h    = (const float*)d_in[0];
    const float* W0   = (const float*)d_in[1];
    const float* b0   = (const float*)d_in[2];
    const float* WL   = (const float*)d_in[3];
    const float* WR   = (const float*)d_in[4];
    const float* Wk   = (const float*)d_in[5];
    const float* bk   = (const float*)d_in[6];
    const float* Wc   = (const float*)d_in[7];
    const float* bias = (const float*)d_in[8];

    float* ws     = (float*)d_ws;
    float* sqp    = ws + OFF_SQP;
    int*   edge   = (int*)(ws + OFF_EDGE);
    float* s2e    = ws + OFF_S2E;
    float* w0v    = ws + OFF_W0V;
    u16*   vtb    = (u16*)(ws + OFF_VTB);
    u32*   partk  = (u32*)(ws + OFF_PARTK);
    u16*   ubar   = (u16*)(ws + OFF_UBAR);
    u16*   hht    = (u16*)(ws + OFF_UBAR);            // aliases ubar (dead before ecc)
    u16*   hlt    = hht + 25600*64;
    float* outp   = (float*)d_out;

    prep_kernel<<<dim3(16), dim3(256), 0, stream>>>(b0, WL, WR, Wk, bk, ws);
    pix_pre<<<dim3(400), dim3(256), 0, stream>>>(h, W0, w0v, sqp, hht, hlt);
    topk_mfma<<<dim3(1600), dim3(512), 0, stream>>>(hht, hlt, sqp, partk);
    topk_merge<<<dim3(100), dim3(256), 0, stream>>>(partk, sqp, edge, s2e);
    vt_pre<<<dim3(400), dim3(256), 0, stream>>>(h, ws, vtb);   // overwrites part region
    ecc_kernel<<<dim3(1600), dim3(128), 0, stream>>>(ws, edge, s2e, vtb, ubar);
    wl_kernel<<<dim3(400), dim3(256), 0, stream>>>(ws, ubar, outp);
    conv_kernel<<<dim3(960), dim3(320), 0, stream>>>(h, Wc, bias, outp);
}

// Round 14
// 220.848 us; speedup vs baseline: 3.0777x; 1.0077x over previous
//
#include <hip/hip_runtime.h>

#define CC    48
#define HH    160
#define WWID  160
#define NPIX  25600
#define KK    8

typedef unsigned short u16;
typedef unsigned int u32;
typedef __attribute__((ext_vector_type(8))) short bf16x8;
typedef __attribute__((ext_vector_type(4))) float f32x4;

__device__ __forceinline__ float bf2f(u16 u) {
    return __uint_as_float(((unsigned int)u) << 16);
}
__device__ __forceinline__ u16 f2bf(float f) {
    unsigned int x = __float_as_uint(f);
    return (u16)((x + 0x7FFFu + ((x >> 16) & 1u)) >> 16);
}

// ws float-offset layout — NON-ALIASED (ws_size ~268 MB per harness fill; high-water 36.1 MB)
#define OFF_B0    0        // 48
#define OFF_BK    48       // 12
#define OFF_WKT   60       // 576     wkt[c*12+r] = Wk[r][c]
#define OFF_WRT   636      // 9216    wrt[cp*192 + i] = WR[i][cp]
#define OFF_WLT   9852     // 9216    wlt[cp*192 + i] = WL[i][cp]
#define OFF_SQP   19068    // 25600
#define OFF_W0V   44668    // 1228800
#define OFF_VTB   1273468  // u16[25600*192]  (2457600 f)
#define OFF_HHT   3731068  // u16[25600*64]   (819200 f)
#define OFF_HLT   4550268  // u16[25600*64]   (819200 f)
#define OFF_PARTK 5369468  // u32[8][8][NPIX] (1638400 f)
#define OFF_UBAR  7007868  // u16[25600*192]  (2457600 f) -> ends 9465468 (36.1 MB)

__global__ void prep_kernel(const float* b0, const float* WL, const float* WR,
                            const float* Wk, const float* bk, float* ws) {
    float* b0f  = ws + OFF_B0;
    float* bkf  = ws + OFF_BK;
    float* wkt  = ws + OFF_WKT;
    float* wrt  = ws + OFF_WRT;
    float* wlt  = ws + OFF_WLT;
    int t = blockIdx.x * 256 + threadIdx.x;
    int stride = gridDim.x * 256;
    for (int i = t; i < 9216; i += stride) {
        int cp = i / 192, r = i % 192;
        wrt[i] = WR[r*48 + cp];
        wlt[i] = WL[r*48 + cp];
    }
    for (int i = t; i < 576; i += stride) { int c = i / 12, r = i % 12; wkt[i] = Wk[r*48 + c]; }
    for (int i = t; i < 48; i += stride) { b0f[i] = b0[i]; }
    for (int i = t; i < 12; i += stride) { bkf[i] = bk[i]; }
}

// fused per-pixel precompute: sq, bf16 hi/lo split, W0V (6 rows/group), VT (6 cps/group)
// block 512 = 64 px x 8 wave-uniform groups; grid 400
__global__ __launch_bounds__(512) void pixvt(const float* h, const float* W0,
                                             const float* ws, float* w0v, float* sqp,
                                             u16* hht, u16* hlt, u16* vtb) {
    const float* wrt = ws + OFF_WRT;
    int tid = threadIdx.x;
    int p = blockIdx.x * 64 + (tid & 63);
    int g = tid >> 6;    // 0..7, wave-uniform
    float f[48];
    #pragma unroll
    for (int c = 0; c < 48; c++) f[c] = h[c*NPIX + p];

    if (g == 0) {
        float sq = 0.f;
        #pragma unroll
        for (int c = 0; c < 48; c++) sq = fmaf(f[c], f[c], sq);
        sqp[p] = sq;
    }
    if (g < 2) {
        u16 hi24[24], lo24[24];
        #pragma unroll
        for (int k = 0; k < 24; k++) {
            float v = f[g*24 + k];
            u16 hi = f2bf(v);
            hi24[k] = hi;
            lo24[k] = f2bf(v - bf2f(hi));
        }
        uint4* dh = (uint4*)&hht[(long)p*64 + g*24];
        uint4* dl = (uint4*)&hlt[(long)p*64 + g*24];
        const uint4* sh4 = (const uint4*)hi24;
        const uint4* sl4 = (const uint4*)lo24;
        dh[0] = sh4[0]; dh[1] = sh4[1]; dh[2] = sh4[2];
        dl[0] = sl4[0]; dl[1] = sl4[1]; dl[2] = sl4[2];
        if (g == 1) {
            uint4 z = make_uint4(0, 0, 0, 0);
            uint4* zh = (uint4*)&hht[(long)p*64 + 48];
            uint4* zl = (uint4*)&hlt[(long)p*64 + 48];
            zh[0] = z; zh[1] = z;
            zl[0] = z; zl[1] = z;
        }
    }

    for (int o = g*6; o < g*6 + 6; o++) {          // W0V rows (o wave-uniform -> s_load)
        const float* wr = W0 + o*48;
        float a0 = 0.f, a1 = 0.f, a2 = 0.f, a3 = 0.f;
        #pragma unroll
        for (int c4 = 0; c4 < 12; c4++) {
            a0 = fmaf(wr[c4*4+0], f[c4*4+0], a0);
            a1 = fmaf(wr[c4*4+1], f[c4*4+1], a1);
            a2 = fmaf(wr[c4*4+2], f[c4*4+2], a2);
            a3 = fmaf(wr[c4*4+3], f[c4*4+3], a3);
        }
        w0v[(long)p*48 + o] = (a0 + a1) + (a2 + a3);
    }

    u16* vrow = vtb + (long)p * 192;
    for (int cp = g*6; cp < g*6 + 6; cp++) {       // VT cps (wave-uniform)
        const float* wr = wrt + cp * 192;
        float v0 = 0.f, v1 = 0.f, v2 = 0.f, v3 = 0.f;
        #pragma unroll
        for (int c = 0; c < 48; c++) {
            float vc = f[c];
            v0 = fmaf(wr[4*c+0], vc, v0);
            v1 = fmaf(wr[4*c+1], vc, v1);
            v2 = fmaf(wr[4*c+2], vc, v2);
            v3 = fmaf(wr[4*c+3], vc, v3);
        }
        ushort4 st;
        st.x = f2bf(v0); st.y = f2bf(v1); st.z = f2bf(v2); st.w = f2bf(v3);
        *(ushort4*)&vrow[cp*4] = st;
    }
}

// ---- topk stage 1 (MFMA Gram, packed-key bubble selection, XCD-swizzled) ----
__global__ __launch_bounds__(512, 8) void topk_mfma(const u16* hht, const u16* hlt,
                                                    const float* sqp, u32* partk) {
    __shared__ u16 ca_hi[128*64];
    __shared__ u16 ca_lo[128*64];
    __shared__ float sq_s[128];

    int tid = threadIdx.x;
    int b = (blockIdx.x & 7) * 200 + (blockIdx.x >> 3);   // bijective XCD swizzle (1600=8x200)
    int chunk = b & 7, pg = (b >> 3) & 7, win = b >> 6;
    int wi = win / 5, wj = win % 5;
    int base = wi*32*WWID + wj*32;

    #pragma unroll
    for (int r = 0; r < 2; r++) {
        int task = r*512 + tid;
        int blk = task >> 7, row = task & 127;
        int swz = (blk ^ (row & 7)) * 8;
        int ml = chunk*128 + row;
        long gp = base + (ml>>5)*WWID + (ml&31);
        *(uint4*)&ca_hi[row*64 + swz] = *(const uint4*)&hht[gp*64 + blk*8];
        *(uint4*)&ca_lo[row*64 + swz] = *(const uint4*)&hlt[gp*64 + blk*8];
    }
    if (tid < 128) {
        int ml = chunk*128 + tid;
        sq_s[tid] = sqp[base + (ml>>5)*WWID + (ml&31)];
    }
    __syncthreads();

    int w = tid >> 6, lane = tid & 63;
    int lm = lane & 15, lg = lane >> 4;

    int nl = pg*128 + w*16 + lm;
    long gpx = base + (nl>>5)*WWID + (nl&31);

    f32x4 acc[8];
    #pragma unroll
    for (int t = 0; t < 8; t++) acc[t] = (f32x4){0.f, 0.f, 0.f, 0.f};

    #pragma unroll
    for (int s = 0; s < 2; s++) {
        int lblk = 4*s + lg;
        int ko = lblk * 8;
        bf16x8 bh = *(const bf16x8*)&hht[gpx*64 + ko];
        bf16x8 bl = *(const bf16x8*)&hlt[gpx*64 + ko];
        #pragma unroll
        for (int t = 0; t < 8; t++) {
            int aoff = (t*16 + lm)*64 + (lblk ^ (lm & 7))*8;
            bf16x8 ah = *(const bf16x8*)&ca_hi[aoff];
            bf16x8 al = *(const bf16x8*)&ca_lo[aoff];
            acc[t] = __builtin_amdgcn_mfma_f32_16x16x32_bf16(ah, bh, acc[t], 0, 0, 0);
            acc[t] = __builtin_amdgcn_mfma_f32_16x16x32_bf16(ah, bl, acc[t], 0, 0, 0);
            acc[t] = __builtin_amdgcn_mfma_f32_16x16x32_bf16(al, bh, acc[t], 0, 0, 0);
        }
    }

    int rn = nl >> 5, cn = nl & 31;
    int rowok[8], colok[8];
    #pragma unroll
    for (int t = 0; t < 8; t++) {
        int rm = chunk*4 + (t >> 1);
        int dr = rn - rm; dr = dr < 0 ? -dr : dr;
        rowok[t] = (dr <= 1);
    }
    #pragma unroll
    for (int j = 0; j < 8; j++) {
        int cm = (j >> 2)*16 + lg*4 + (j & 3);
        int dc = cn - cm; dc = dc < 0 ? -dc : dc;
        colok[j] = (dc <= 1);
    }

    u32 k8[8];
    #pragma unroll
    for (int s = 0; s < 8; s++) k8[s] = 0xFFFFFFFFu;

    #pragma unroll
    for (int t = 0; t < 8; t++) {
        #pragma unroll
        for (int r = 0; r < 4; r++) {
            int cl = t*16 + lg*4 + r;
            int ml = chunk*128 + cl;
            float d = fmaf(-2.0f, acc[t][r], sq_s[cl]);
            u32 u = __float_as_uint(d);
            u32 key = u ^ (0x80000000u | (u32)((int)u >> 31));
            key = (key & 0xFFFFFC00u) | (u32)ml;
            bool bad = rowok[t] && colok[(t & 1)*4 + r];
            key = bad ? 0xFFFFFFFFu : key;
            #pragma unroll
            for (int s = 0; s < 8; s++) {
                u32 lo = min(k8[s], key);
                u32 hi = max(k8[s], key);
                k8[s] = lo; key = hi;
            }
        }
    }

    // after the two merges, all 4 lg-groups hold IDENTICAL sorted k8
    #pragma unroll
    for (int st = 0; st < 2; st++) {
        int mk = (st == 0) ? 16 : 32;
        u32 o[8];
        #pragma unroll
        for (int s = 0; s < 8; s++) o[s] = (u32)__shfl_xor((int)k8[s], mk, 64);
        u32 c0 = min(k8[0], o[7]);
        u32 c1 = min(k8[1], o[6]);
        u32 c2 = min(k8[2], o[5]);
        u32 c3 = min(k8[3], o[4]);
        u32 c4 = min(k8[4], o[3]);
        u32 c5 = min(k8[5], o[2]);
        u32 c6 = min(k8[6], o[1]);
        u32 c7 = min(k8[7], o[0]);
        u32 a, bb;
        a = min(c0,c4); bb = max(c0,c4); c0 = a; c4 = bb;
        a = min(c1,c5); bb = max(c1,c5); c1 = a; c5 = bb;
        a = min(c2,c6); bb = max(c2,c6); c2 = a; c6 = bb;
        a = min(c3,c7); bb = max(c3,c7); c3 = a; c7 = bb;
        a = min(c0,c2); bb = max(c0,c2); c0 = a; c2 = bb;
        a = min(c1,c3); bb = max(c1,c3); c1 = a; c3 = bb;
        a = min(c4,c6); bb = max(c4,c6); c4 = a; c6 = bb;
        a = min(c5,c7); bb = max(c5,c7); c5 = a; c7 = bb;
        a = min(c0,c1); bb = max(c0,c1); c0 = a; c1 = bb;
        a = min(c2,c3); bb = max(c2,c3); c2 = a; c3 = bb;
        a = min(c4,c5); bb = max(c4,c5); c4 = a; c5 = bb;
        a = min(c6,c7); bb = max(c6,c7); c6 = a; c7 = bb;
        k8[0]=c0; k8[1]=c1; k8[2]=c2; k8[3]=c3; k8[4]=c4; k8[5]=c5; k8[6]=c6; k8[7]=c7;
    }

    // coalesced store: partk[chunk][s][NPIX]; lane (lm,lg) writes s=2*lg, 2*lg+1
    {
        int n = base + (nl >> 5)*WWID + (nl & 31);
        u32 v0, v1;
        if      (lg == 0) { v0 = k8[0]; v1 = k8[1]; }
        else if (lg == 1) { v0 = k8[2]; v1 = k8[3]; }
        else if (lg == 2) { v0 = k8[4]; v1 = k8[5]; }
        else              { v0 = k8[6]; v1 = k8[7]; }
        u32* pk = partk + (long)chunk*8*NPIX + (long)(2*lg)*NPIX + n;
        pk[0]    = v0;
        pk[NPIX] = v1;
    }
}

// ---- ecc (fused chunk-merge): per-lane chunk list, shfl bitonic merge, rank mux ----
__global__ __launch_bounds__(128, 4) void ecc_kernel(const float* ws, const u32* partk,
                                                     const u16* vtb, u16* ubar) {
    const float* b0f = ws + OFF_B0;
    const float* bkf = ws + OFF_BK;
    const float* wkt = ws + OFF_WKT;
    const float* w0v = ws + OFF_W0V;
    const float* sqp = ws + OFF_SQP;

    __shared__ u16 th_s[128][50];   // theta bf16

    int tid = threadIdx.x;
    int sb = (blockIdx.x & 7) * 200 + (blockIdx.x >> 3);   // bijective XCD swizzle
    int pix = tid >> 3, sh = tid & 7;
    int n = sb * 16 + pix;

    // merge the 8 chunk-lists (lane sh owns chunk sh's sorted 8)
    u32 k8[8];
    {
        const u32* pk = partk + (long)sh*8*NPIX + n;
        #pragma unroll
        for (int s = 0; s < 8; s++) k8[s] = pk[(long)s*NPIX];
    }
    #pragma unroll
    for (int st = 0; st < 3; st++) {
        int mk = 1 << st;
        u32 o[8];
        #pragma unroll
        for (int s = 0; s < 8; s++) o[s] = (u32)__shfl_xor((int)k8[s], mk, 64);
        u32 c0 = min(k8[0], o[7]);
        u32 c1 = min(k8[1], o[6]);
        u32 c2 = min(k8[2], o[5]);
        u32 c3 = min(k8[3], o[4]);
        u32 c4 = min(k8[4], o[3]);
        u32 c5 = min(k8[5], o[2]);
        u32 c6 = min(k8[6], o[1]);
        u32 c7 = min(k8[7], o[0]);
        u32 a, bb;
        a = min(c0,c4); bb = max(c0,c4); c0 = a; c4 = bb;
        a = min(c1,c5); bb = max(c1,c5); c1 = a; c5 = bb;
        a = min(c2,c6); bb = max(c2,c6); c2 = a; c6 = bb;
        a = min(c3,c7); bb = max(c3,c7); c3 = a; c7 = bb;
        a = min(c0,c2); bb = max(c0,c2); c0 = a; c2 = bb;
        a = min(c1,c3); bb = max(c1,c3); c1 = a; c3 = bb;
        a = min(c4,c6); bb = max(c4,c6); c4 = a; c6 = bb;
        a = min(c5,c7); bb = max(c5,c7); c5 = a; c7 = bb;
        a = min(c0,c1); bb = max(c0,c1); c0 = a; c1 = bb;
        a = min(c2,c3); bb = max(c2,c3); c2 = a; c3 = bb;
        a = min(c4,c5); bb = max(c4,c5); c4 = a; c5 = bb;
        a = min(c6,c7); bb = max(c6,c7); c6 = a; c7 = bb;
        k8[0]=c0; k8[1]=c1; k8[2]=c2; k8[3]=c3; k8[4]=c4; k8[5]=c5; k8[6]=c6; k8[7]=c7;
    }
    // lane sh takes rank sh (3-level mux, no runtime indexing)
    u32 key;
    {
        u32 m0 = (sh & 1) ? k8[1] : k8[0];
        u32 m1 = (sh & 1) ? k8[3] : k8[2];
        u32 m2 = (sh & 1) ? k8[5] : k8[4];
        u32 m3 = (sh & 1) ? k8[7] : k8[6];
        u32 n0 = (sh & 2) ? m1 : m0;
        u32 n1 = (sh & 2) ? m3 : m2;
        key = (sh & 4) ? n1 : n0;
    }
    int ml = (int)(key & 1023u);
    u32 uf = key & 0xFFFFFC00u;
    u32 uu = (uf & 0x80000000u) ? (uf ^ 0x80000000u) : ~uf;
    float d = __uint_as_float(uu);
    int y = n / WWID, x = n % WWID;
    int wy = (y >> 5) << 5, wx = (x >> 5) << 5;
    int m = (wy + (ml >> 5)) * WWID + (wx + (ml & 31));
    float gamma = expf(-(d + sqp[n]) * 0.1f);

    float th[48];
    {
        const float4* wm4 = (const float4*)(w0v + (long)m * 48);
        const float4* wn4 = (const float4*)(w0v + (long)n * 48);
        #pragma unroll
        for (int i = 0; i < 12; i++) {
            float4 a = wm4[i];
            float4 b = wn4[i];
            float x0 = a.x - b.x + b0f[4*i+0];
            float x1 = a.y - b.y + b0f[4*i+1];
            float x2 = a.z - b.z + b0f[4*i+2];
            float x3 = a.w - b.w + b0f[4*i+3];
            th[4*i+0] = (x0 >= 0.f) ? x0 : 0.01f * x0;
            th[4*i+1] = (x1 >= 0.f) ? x1 : 0.01f * x1;
            th[4*i+2] = (x2 >= 0.f) ? x2 : 0.01f * x2;
            th[4*i+3] = (x3 >= 0.f) ? x3 : 0.01f * x3;
        }
    }

    #pragma unroll
    for (int i = 0; i < 24; i++) {
        ushort2 pr;
        pr.x = f2bf(th[2*i]);
        pr.y = f2bf(th[2*i+1]);
        *(ushort2*)&th_s[tid][2*i] = pr;
    }

    float kap[12];
    #pragma unroll
    for (int r = 0; r < 12; r++) kap[r] = bkf[r];
    #pragma unroll
    for (int c = 0; c < 48; c++) {
        float t = th[c];
        const float* wkc = wkt + c*12;
        #pragma unroll
        for (int r = 0; r < 12; r++) kap[r] = fmaf(wkc[r], t, kap[r]);
    }

    float sr[12];
    #pragma unroll
    for (int r = 0; r < 12; r++) sr[r] = 0.f;
    const u16* vrow = vtb + (long)m * 192;
    #pragma unroll
    for (int j = 0; j < 24; j++) {
        uint4 vv = *(const uint4*)&vrow[j*8];
        #pragma unroll
        for (int half = 0; half < 2; half++) {
            int cp = 2*j + half;
            u32 w0_ = half ? vv.z : vv.x;
            u32 w1_ = half ? vv.w : vv.y;
            float vx = bf2f((u16)(w0_ & 0xffff));
            float vy = bf2f((u16)(w0_ >> 16));
            float vz = bf2f((u16)(w1_ & 0xffff));
            float vw = bf2f((u16)(w1_ >> 16));
            int i1 = (cp + 1 < 48) ? cp + 1 : cp - 47;
            int i2 = (cp + 2 < 48) ? cp + 2 : cp - 46;
            float t0 = th[cp], t1 = th[i1], t2 = th[i2];
            sr[0] = fmaf(t0, vx, sr[0]); sr[1]  = fmaf(t1, vx, sr[1]);  sr[2]  = fmaf(t2, vx, sr[2]);
            sr[3] = fmaf(t0, vy, sr[3]); sr[4]  = fmaf(t1, vy, sr[4]);  sr[5]  = fmaf(t2, vy, sr[5]);
            sr[6] = fmaf(t0, vz, sr[6]); sr[7]  = fmaf(t1, vz, sr[7]);  sr[8]  = fmaf(t2, vz, sr[8]);
            sr[9] = fmaf(t0, vw, sr[9]); sr[10] = fmaf(t1, vw, sr[10]); sr[11] = fmaf(t2, vw, sr[11]);
        }
    }

    float tmp[12];
    #pragma unroll
    for (int r = 0; r < 12; r++) tmp[r] = kap[r] * sr[r];

    __syncthreads();

    float acc0[6], acc1[6], acc2[6], acc3[6];
    #pragma unroll
    for (int j = 0; j < 6; j++) { acc0[j] = 0.f; acc1[j] = 0.f; acc2[j] = 0.f; acc3[j] = 0.f; }
    #pragma unroll 1
    for (int e = 0; e < 8; e++) {
        int srcl = (tid & 56) + e;
        int row  = (tid & 120) + e;
        float tm[12];
        #pragma unroll
        for (int r = 0; r < 12; r++) tm[r] = __shfl(tmp[r], srcl, 64);
        float ge = __shfl(gamma, srcl, 64);
        #pragma unroll
        for (int j = 0; j < 6; j++) {
            int cp = sh + 8*j;
            int i1 = (cp + 1 < 48) ? cp + 1 : cp - 47;
            int i2 = (cp + 2 < 48) ? cp + 2 : cp - 46;
            float t0 = bf2f(th_s[row][cp]);
            float t1 = bf2f(th_s[row][i1]);
            float t2 = bf2f(th_s[row][i2]);
            float u0 = tm[0]*t0 + tm[1]*t1 + tm[2]*t2;
            float u1 = tm[3]*t0 + tm[4]*t1 + tm[5]*t2;
            float u2 = tm[6]*t0 + tm[7]*t1 + tm[8]*t2;
            float u3 = tm[9]*t0 + tm[10]*t1 + tm[11]*t2;
            acc0[j] = fmaf(ge, u0, acc0[j]);
            acc1[j] = fmaf(ge, u1, acc1[j]);
            acc2[j] = fmaf(ge, u2, acc2[j]);
            acc3[j] = fmaf(ge, u3, acc3[j]);
        }
    }
    u16* ub = ubar + (long)n * 192;
    #pragma unroll
    for (int j = 0; j < 6; j++) {
        int cp = sh + 8*j;
        ushort4 st;
        st.x = f2bf(acc0[j]); st.y = f2bf(acc1[j]);
        st.z = f2bf(acc2[j]); st.w = f2bf(acc3[j]);
        *(ushort4*)&ub[cp*4] = st;
    }
}

// ---- wl: 64 pixels x 8 wave-uniform 6-output groups (512 thr); writes 0.5*hNL ----
__global__ __launch_bounds__(512) void wl_kernel(const float* ws, const u16* ubar, float* outp) {
    const float* wlt = ws + OFF_WLT;
    int tid = threadIdx.x;
    int p = blockIdx.x * 64 + (tid & 63);
    int ob = (tid >> 6) * 6;           // wave-uniform -> scalar WL loads
    const u16* ub = ubar + (long)p * 192;
    float out[6];
    #pragma unroll
    for (int o = 0; o < 6; o++) out[o] = 0.f;
    for (int j = 0; j < 24; j++) {     // 2 cp per uint4
        uint4 vv = *(const uint4*)&ub[j*8];
        #pragma unroll
        for (int half = 0; half < 2; half++) {
            int cp = 2*j + half;
            u32 a_ = half ? vv.z : vv.x;
            u32 b_ = half ? vv.w : vv.y;
            float ux = bf2f((u16)(a_ & 0xffff));
            float uy = bf2f((u16)(a_ >> 16));
            float uz = bf2f((u16)(b_ & 0xffff));
            float uw = bf2f((u16)(b_ >> 16));
            const float* wl = wlt + cp * 192 + ob * 4;
            #pragma unroll
            for (int o = 0; o < 6; o++) {
                float a = out[o];
                a = fmaf(wl[4*o+0], ux, a);
                a = fmaf(wl[4*o+1], uy, a);
                a = fmaf(wl[4*o+2], uz, a);
                a = fmaf(wl[4*o+3], uw, a);
                out[o] = a;
            }
        }
    }
    #pragma unroll
    for (int o = 0; o < 6; o++) outp[(ob + o)*NPIX + p] = 0.0625f * out[o];  // 0.5 * (1/8)
}

// ---- conv 3x3 (reflect pad), OCH=4/thread, XCD-chunked swizzle, adds 0.5*hL + bias ----
#define OCH 4
__global__ __launch_bounds__(320) void conv_kernel(const float* h, const float* wc,
                                                   const float* bias, float* outp) {
    int sb = (blockIdx.x & 7) * 120 + (blockIdx.x >> 3);
    int og = sb % 12;
    int yp = sb / 12;
    int t  = threadIdx.x;
    int ty = t / 160;
    int x  = t % 160;
    int y  = yp * 2 + ty;

    int idx9[9];
    #pragma unroll
    for (int dy = 0; dy < 3; dy++) {
        int yy = y + dy - 1;
        yy = yy < 0 ? -yy : (yy >= HH ? 2*HH - 2 - yy : yy);
        #pragma unroll
        for (int dx = 0; dx < 3; dx++) {
            int xx = x + dx - 1;
            xx = xx < 0 ? -xx : (xx >= WWID ? 2*WWID - 2 - xx : xx);
            idx9[dy*3 + dx] = yy * WWID + xx;
        }
    }

    float acc[OCH];
    #pragma unroll
    for (int oi = 0; oi < OCH; oi++) acc[oi] = 0.f;

    const float* wbase = wc + og * OCH * 432;
    for (int c = 0; c < 48; c++) {
        float v[9];
        #pragma unroll
        for (int k = 0; k < 9; k++) v[k] = h[c*NPIX + idx9[k]];
        #pragma unroll
        for (int oi = 0; oi < OCH; oi++) {
            const float* w9 = wbase + oi*432 + c*9;
            float a = acc[oi];
            a = fmaf(v[0], w9[0], a);
            a = fmaf(v[1], w9[1], a);
            a = fmaf(v[2], w9[2], a);
            a = fmaf(v[3], w9[3], a);
            a = fmaf(v[4], w9[4], a);
            a = fmaf(v[5], w9[5], a);
            a = fmaf(v[6], w9[6], a);
            a = fmaf(v[7], w9[7], a);
            a = fmaf(v[8], w9[8], a);
            acc[oi] = a;
        }
    }

    int p = y * WWID + x;
    #pragma unroll
    for (int oi = 0; oi < OCH; oi++) {
        int o = og * OCH + oi;
        outp[o*NPIX + p] = outp[o*NPIX + p] + 0.5f * acc[oi] + bias[o];
    }
}

extern "C" void kernel_launch(void* const* d_in, const int* in_sizes, int n_in,
                              void* d_out, int out_size, void* d_ws, size_t ws_size,
                              hipStream_t stream) {
    const float* h    = (const float*)d_in[0];
    const float* W0   = (const float*)d_in[1];
    const float* b0   = (const float*)d_in[2];
    const float* WL   = (const float*)d_in[3];
    const float* WR   = (const float*)d_in[4];
    const float* Wk   = (const float*)d_in[5];
    const float* bk   = (const float*)d_in[6];
    const float* Wc   = (const float*)d_in[7];
    const float* bias = (const float*)d_in[8];

    float* ws     = (float*)d_ws;
    float* sqp    = ws + OFF_SQP;
    float* w0v    = ws + OFF_W0V;
    u16*   vtb    = (u16*)(ws + OFF_VTB);
    u16*   hht    = (u16*)(ws + OFF_HHT);
    u16*   hlt    = (u16*)(ws + OFF_HLT);
    u32*   partk  = (u32*)(ws + OFF_PARTK);
    u16*   ubar   = (u16*)(ws + OFF_UBAR);
    float* outp   = (float*)d_out;

    prep_kernel<<<dim3(16), dim3(256), 0, stream>>>(b0, WL, WR, Wk, bk, ws);
    pixvt<<<dim3(400), dim3(512), 0, stream>>>(h, W0, ws, w0v, sqp, hht, hlt, vtb);
    topk_mfma<<<dim3(1600), dim3(512), 0, stream>>>(hht, hlt, sqp, partk);
    ecc_kernel<<<dim3(1600), dim3(128), 0, stream>>>(ws, partk, vtb, ubar);
    wl_kernel<<<dim3(400), dim3(512), 0, stream>>>(ws, ubar, outp);
    conv_kernel<<<dim3(960), dim3(320), 0, stream>>>(h, Wc, bias, outp);
}

// Round 15
// 177.481 us; speedup vs baseline: 3.8297x; 1.2443x over previous
//
#include <hip/hip_runtime.h>

#define CC    48
#define HH    160
#define WWID  160
#define NPIX  25600
#define KK    8

typedef unsigned short u16;
typedef unsigned int u32;
typedef __attribute__((ext_vector_type(8))) short bf16x8;
typedef __attribute__((ext_vector_type(4))) float f32x4;

__device__ __forceinline__ float bf2f(u16 u) {
    return __uint_as_float(((unsigned int)u) << 16);
}
__device__ __forceinline__ u16 f2bf(float f) {
    unsigned int x = __float_as_uint(f);
    return (u16)((x + 0x7FFFu + ((x >> 16) & 1u)) >> 16);
}

// ws float-offset layout — non-aliased, high-water 36.1 MB
#define OFF_B0    0        // 48
#define OFF_BK    48       // 12
#define OFF_WKT   60       // 576     wkt[c*12+r] = Wk[r][c]
#define OFF_WLT   636      // 9216    wlt[cp*192 + i] = WL[i][cp]
#define OFF_WBH   9852     // u16[256*64]: combined weight bf16-hi  (8192 f)
#define OFF_WBL   18044    // u16[256*64]: combined weight bf16-lo  (8192 f)
#define OFF_SQP   26236    // 25600
#define OFF_W0V   51836    // float[25600*48]
#define OFF_VTB   1280636  // u16[25600*192]
#define OFF_HHT   3738236  // u16[25600*64]
#define OFF_HLT   4557436  // u16[25600*64]
#define OFF_PARTK 5376636  // u32[8][8][NPIX]
#define OFF_UBAR  7015036  // u16[25600*192] -> ends 9472636

__global__ void prep_kernel(const float* W0, const float* b0, const float* WL,
                            const float* WR, const float* Wk, const float* bk,
                            float* ws) {
    float* b0f = ws + OFF_B0;
    float* bkf = ws + OFF_BK;
    float* wkt = ws + OFF_WKT;
    float* wlt = ws + OFF_WLT;
    u16*   wbh = (u16*)(ws + OFF_WBH);
    u16*   wbl = (u16*)(ws + OFF_WBL);
    int t = blockIdx.x * 256 + threadIdx.x;
    int stride = gridDim.x * 256;
    for (int i = t; i < 9216; i += stride) {
        int cp = i / 192, r = i % 192;
        wlt[i] = WL[r*48 + cp];
    }
    // combined B matrix: cols 0..191 = VT (col=cp*4+q -> WR[(4k+q)*48+cp]),
    // cols 192..239 = W0V (W0[o*48+k]), else 0; k 48..63 = 0.
    for (int i = t; i < 16384; i += stride) {
        int col = i >> 6, k = i & 63;
        float v = 0.f;
        if (k < 48) {
            if (col < 192)      v = WR[(4*k + (col & 3))*48 + (col >> 2)];
            else if (col < 240) v = W0[(col - 192)*48 + k];
        }
        u16 hi = f2bf(v);
        wbh[i] = hi;
        wbl[i] = f2bf(v - bf2f(hi));
    }
    for (int i = t; i < 576; i += stride) { int c = i / 12, r = i % 12; wkt[i] = Wk[r*48 + c]; }
    for (int i = t; i < 48; i += stride) { b0f[i] = b0[i]; }
    for (int i = t; i < 12; i += stride) { bkf[i] = bk[i]; }
}

// per-pixel: sq + bf16 hi/lo split rows (contiguous 128 B/row writes)
__global__ __launch_bounds__(256) void split_kernel(const float* h, float* sqp,
                                                    u16* hht, u16* hlt) {
    int p = blockIdx.x * 256 + threadIdx.x;
    float sq = 0.f;
    u16 hh[64], hl[64];
    #pragma unroll
    for (int c = 0; c < 48; c++) {
        float v = h[c*NPIX + p];
        sq = fmaf(v, v, sq);
        u16 hi = f2bf(v);
        hh[c] = hi;
        hl[c] = f2bf(v - bf2f(hi));
    }
    #pragma unroll
    for (int c = 48; c < 64; c++) { hh[c] = 0; hl[c] = 0; }
    sqp[p] = sq;
    uint4* dh = (uint4*)&hht[(long)p*64];
    uint4* dl = (uint4*)&hlt[(long)p*64];
    const uint4* s1 = (const uint4*)hh;
    const uint4* s2 = (const uint4*)hl;
    #pragma unroll
    for (int i = 0; i < 8; i++) { dh[i] = s1[i]; dl[i] = s2[i]; }
}

// ---- pixvt via MFMA: per block 64 px x 256 weight-cols (192 VT bf16 + 48 W0V f32) ----
__global__ __launch_bounds__(512) void pixvt_mfma(const u16* hht, const u16* hlt,
                                                  const float* ws, float* w0v, u16* vtb) {
    __shared__ __align__(16) char smem[38912];
    u16*   a_hi = (u16*)smem;              // [64][64] (phase 1)
    u16*   a_lo = (u16*)(smem + 8192);
    u16*   vt_s = (u16*)smem;              // [64][200] u16 (phase 2)
    float* w0_s = (float*)(smem + 25600);  // [64][52]  f32

    const u16* wbh = (const u16*)(ws + OFF_WBH);
    const u16* wbl = (const u16*)(ws + OFF_WBL);

    int tid = threadIdx.x;
    int pbase = blockIdx.x * 64;

    // stage A (64 px, hi/lo), XOR-swizzled rows (topk-proven pattern)
    {
        int blk = tid >> 6, row = tid & 63;
        int swz = (blk ^ (row & 7)) * 8;
        *(uint4*)&a_hi[row*64 + swz] = *(const uint4*)&hht[(long)(pbase + row)*64 + blk*8];
        *(uint4*)&a_lo[row*64 + swz] = *(const uint4*)&hlt[(long)(pbase + row)*64 + blk*8];
    }
    __syncthreads();

    int w = tid >> 6, lane = tid & 63;
    int lm = lane & 15, lg = lane >> 4;
    int c2a = 2*w, c2b = 2*w + 1;       // col-tiles (15 real tiles; tile 15 is zero-pad)

    f32x4 acc0[4], acc1[4];
    #pragma unroll
    for (int t = 0; t < 4; t++) { acc0[t] = (f32x4){0.f,0.f,0.f,0.f}; acc1[t] = (f32x4){0.f,0.f,0.f,0.f}; }

    #pragma unroll
    for (int s = 0; s < 2; s++) {
        int lblk = 4*s + lg;
        int aswz = (lblk ^ (lm & 7)) * 8;
        bf16x8 ah0 = *(const bf16x8*)&a_hi[( 0 + lm)*64 + aswz];
        bf16x8 ah1 = *(const bf16x8*)&a_hi[(16 + lm)*64 + aswz];
        bf16x8 ah2 = *(const bf16x8*)&a_hi[(32 + lm)*64 + aswz];
        bf16x8 ah3 = *(const bf16x8*)&a_hi[(48 + lm)*64 + aswz];
        bf16x8 al0 = *(const bf16x8*)&a_lo[( 0 + lm)*64 + aswz];
        bf16x8 al1 = *(const bf16x8*)&a_lo[(16 + lm)*64 + aswz];
        bf16x8 al2 = *(const bf16x8*)&a_lo[(32 + lm)*64 + aswz];
        bf16x8 al3 = *(const bf16x8*)&a_lo[(48 + lm)*64 + aswz];
        {
            int col = c2a*16 + lm;
            bf16x8 bh = *(const bf16x8*)&wbh[col*64 + lblk*8];
            bf16x8 bl = *(const bf16x8*)&wbl[col*64 + lblk*8];
            acc0[0] = __builtin_amdgcn_mfma_f32_16x16x32_bf16(ah0, bh, acc0[0], 0, 0, 0);
            acc0[0] = __builtin_amdgcn_mfma_f32_16x16x32_bf16(ah0, bl, acc0[0], 0, 0, 0);
            acc0[0] = __builtin_amdgcn_mfma_f32_16x16x32_bf16(al0, bh, acc0[0], 0, 0, 0);
            acc0[1] = __builtin_amdgcn_mfma_f32_16x16x32_bf16(ah1, bh, acc0[1], 0, 0, 0);
            acc0[1] = __builtin_amdgcn_mfma_f32_16x16x32_bf16(ah1, bl, acc0[1], 0, 0, 0);
            acc0[1] = __builtin_amdgcn_mfma_f32_16x16x32_bf16(al1, bh, acc0[1], 0, 0, 0);
            acc0[2] = __builtin_amdgcn_mfma_f32_16x16x32_bf16(ah2, bh, acc0[2], 0, 0, 0);
            acc0[2] = __builtin_amdgcn_mfma_f32_16x16x32_bf16(ah2, bl, acc0[2], 0, 0, 0);
            acc0[2] = __builtin_amdgcn_mfma_f32_16x16x32_bf16(al2, bh, acc0[2], 0, 0, 0);
            acc0[3] = __builtin_amdgcn_mfma_f32_16x16x32_bf16(ah3, bh, acc0[3], 0, 0, 0);
            acc0[3] = __builtin_amdgcn_mfma_f32_16x16x32_bf16(ah3, bl, acc0[3], 0, 0, 0);
            acc0[3] = __builtin_amdgcn_mfma_f32_16x16x32_bf16(al3, bh, acc0[3], 0, 0, 0);
        }
        if (c2b < 15) {
            int col = c2b*16 + lm;
            bf16x8 bh = *(const bf16x8*)&wbh[col*64 + lblk*8];
            bf16x8 bl = *(const bf16x8*)&wbl[col*64 + lblk*8];
            acc1[0] = __builtin_amdgcn_mfma_f32_16x16x32_bf16(ah0, bh, acc1[0], 0, 0, 0);
            acc1[0] = __builtin_amdgcn_mfma_f32_16x16x32_bf16(ah0, bl, acc1[0], 0, 0, 0);
            acc1[0] = __builtin_amdgcn_mfma_f32_16x16x32_bf16(al0, bh, acc1[0], 0, 0, 0);
            acc1[1] = __builtin_amdgcn_mfma_f32_16x16x32_bf16(ah1, bh, acc1[1], 0, 0, 0);
            acc1[1] = __builtin_amdgcn_mfma_f32_16x16x32_bf16(ah1, bl, acc1[1], 0, 0, 0);
            acc1[1] = __builtin_amdgcn_mfma_f32_16x16x32_bf16(al1, bh, acc1[1], 0, 0, 0);
            acc1[2] = __builtin_amdgcn_mfma_f32_16x16x32_bf16(ah2, bh, acc1[2], 0, 0, 0);
            acc1[2] = __builtin_amdgcn_mfma_f32_16x16x32_bf16(ah2, bl, acc1[2], 0, 0, 0);
            acc1[2] = __builtin_amdgcn_mfma_f32_16x16x32_bf16(al2, bh, acc1[2], 0, 0, 0);
            acc1[3] = __builtin_amdgcn_mfma_f32_16x16x32_bf16(ah3, bh, acc1[3], 0, 0, 0);
            acc1[3] = __builtin_amdgcn_mfma_f32_16x16x32_bf16(ah3, bl, acc1[3], 0, 0, 0);
            acc1[3] = __builtin_amdgcn_mfma_f32_16x16x32_bf16(al3, bh, acc1[3], 0, 0, 0);
        }
    }
    __syncthreads();   // A region dead; re-purpose smem as C staging

    // stage C: C row = px (t*16 + lg*4 + r), col = ct*16 + lm  (m89-verified mapping)
    {
        int col = c2a*16 + lm;
        if (c2a < 12) {
            #pragma unroll
            for (int t = 0; t < 4; t++)
                #pragma unroll
                for (int r = 0; r < 4; r++)
                    vt_s[(t*16 + lg*4 + r)*200 + col] = f2bf(acc0[t][r]);
        } else {
            int o = col - 192;
            #pragma unroll
            for (int t = 0; t < 4; t++)
                #pragma unroll
                for (int r = 0; r < 4; r++)
                    w0_s[(t*16 + lg*4 + r)*52 + o] = acc0[t][r];
        }
    }
    if (c2b < 15) {
        int col = c2b*16 + lm;
        if (c2b < 12) {
            #pragma unroll
            for (int t = 0; t < 4; t++)
                #pragma unroll
                for (int r = 0; r < 4; r++)
                    vt_s[(t*16 + lg*4 + r)*200 + col] = f2bf(acc1[t][r]);
        } else {
            int o = col - 192;
            #pragma unroll
            for (int t = 0; t < 4; t++)
                #pragma unroll
                for (int r = 0; r < 4; r++)
                    w0_s[(t*16 + lg*4 + r)*52 + o] = acc1[t][r];
        }
    }
    __syncthreads();

    // coalesced write-out
    {
        int px = tid >> 3, c8 = tid & 7;
        #pragma unroll
        for (int j = 0; j < 3; j++) {
            int ch = c8 + 8*j;    // 0..23 chunks of 8 u16
            uint4 v = *(const uint4*)&vt_s[px*200 + ch*8];
            *(uint4*)&vtb[(long)(pbase + px)*192 + ch*8] = v;
        }
        float* dst = w0v + (long)(pbase + px)*48 + c8*6;
        const float* src = w0_s + px*52 + c8*6;
        #pragma unroll
        for (int k = 0; k < 3; k++) {
            float2 v2 = *(const float2*)&src[k*2];
            *(float2*)&dst[k*2] = v2;
        }
    }
}

// ---- topk stage 1 (MFMA Gram, packed-key bubble selection, XCD-swizzled) ----
__global__ __launch_bounds__(512, 8) void topk_mfma(const u16* hht, const u16* hlt,
                                                    const float* sqp, u32* partk) {
    __shared__ u16 ca_hi[128*64];
    __shared__ u16 ca_lo[128*64];
    __shared__ float sq_s[128];

    int tid = threadIdx.x;
    int b = (blockIdx.x & 7) * 200 + (blockIdx.x >> 3);   // bijective XCD swizzle (1600=8x200)
    int chunk = b & 7, pg = (b >> 3) & 7, win = b >> 6;
    int wi = win / 5, wj = win % 5;
    int base = wi*32*WWID + wj*32;

    #pragma unroll
    for (int r = 0; r < 2; r++) {
        int task = r*512 + tid;
        int blk = task >> 7, row = task & 127;
        int swz = (blk ^ (row & 7)) * 8;
        int ml = chunk*128 + row;
        long gp = base + (ml>>5)*WWID + (ml&31);
        *(uint4*)&ca_hi[row*64 + swz] = *(const uint4*)&hht[gp*64 + blk*8];
        *(uint4*)&ca_lo[row*64 + swz] = *(const uint4*)&hlt[gp*64 + blk*8];
    }
    if (tid < 128) {
        int ml = chunk*128 + tid;
        sq_s[tid] = sqp[base + (ml>>5)*WWID + (ml&31)];
    }
    __syncthreads();

    int w = tid >> 6, lane = tid & 63;
    int lm = lane & 15, lg = lane >> 4;

    int nl = pg*128 + w*16 + lm;
    long gpx = base + (nl>>5)*WWID + (nl&31);

    f32x4 acc[8];
    #pragma unroll
    for (int t = 0; t < 8; t++) acc[t] = (f32x4){0.f, 0.f, 0.f, 0.f};

    #pragma unroll
    for (int s = 0; s < 2; s++) {
        int lblk = 4*s + lg;
        int ko = lblk * 8;
        bf16x8 bh = *(const bf16x8*)&hht[gpx*64 + ko];
        bf16x8 bl = *(const bf16x8*)&hlt[gpx*64 + ko];
        #pragma unroll
        for (int t = 0; t < 8; t++) {
            int aoff = (t*16 + lm)*64 + (lblk ^ (lm & 7))*8;
            bf16x8 ah = *(const bf16x8*)&ca_hi[aoff];
            bf16x8 al = *(const bf16x8*)&ca_lo[aoff];
            acc[t] = __builtin_amdgcn_mfma_f32_16x16x32_bf16(ah, bh, acc[t], 0, 0, 0);
            acc[t] = __builtin_amdgcn_mfma_f32_16x16x32_bf16(ah, bl, acc[t], 0, 0, 0);
            acc[t] = __builtin_amdgcn_mfma_f32_16x16x32_bf16(al, bh, acc[t], 0, 0, 0);
        }
    }

    int rn = nl >> 5, cn = nl & 31;
    int rowok[8], colok[8];
    #pragma unroll
    for (int t = 0; t < 8; t++) {
        int rm = chunk*4 + (t >> 1);
        int dr = rn - rm; dr = dr < 0 ? -dr : dr;
        rowok[t] = (dr <= 1);
    }
    #pragma unroll
    for (int j = 0; j < 8; j++) {
        int cm = (j >> 2)*16 + lg*4 + (j & 3);
        int dc = cn - cm; dc = dc < 0 ? -dc : dc;
        colok[j] = (dc <= 1);
    }

    u32 k8[8];
    #pragma unroll
    for (int s = 0; s < 8; s++) k8[s] = 0xFFFFFFFFu;

    #pragma unroll
    for (int t = 0; t < 8; t++) {
        #pragma unroll
        for (int r = 0; r < 4; r++) {
            int cl = t*16 + lg*4 + r;
            int ml = chunk*128 + cl;
            float d = fmaf(-2.0f, acc[t][r], sq_s[cl]);
            u32 u = __float_as_uint(d);
            u32 key = u ^ (0x80000000u | (u32)((int)u >> 31));
            key = (key & 0xFFFFFC00u) | (u32)ml;
            bool bad = rowok[t] && colok[(t & 1)*4 + r];
            key = bad ? 0xFFFFFFFFu : key;
            #pragma unroll
            for (int s = 0; s < 8; s++) {
                u32 lo = min(k8[s], key);
                u32 hi = max(k8[s], key);
                k8[s] = lo; key = hi;
            }
        }
    }

    #pragma unroll
    for (int st = 0; st < 2; st++) {
        int mk = (st == 0) ? 16 : 32;
        u32 o[8];
        #pragma unroll
        for (int s = 0; s < 8; s++) o[s] = (u32)__shfl_xor((int)k8[s], mk, 64);
        u32 c0 = min(k8[0], o[7]);
        u32 c1 = min(k8[1], o[6]);
        u32 c2 = min(k8[2], o[5]);
        u32 c3 = min(k8[3], o[4]);
        u32 c4 = min(k8[4], o[3]);
        u32 c5 = min(k8[5], o[2]);
        u32 c6 = min(k8[6], o[1]);
        u32 c7 = min(k8[7], o[0]);
        u32 a, bb;
        a = min(c0,c4); bb = max(c0,c4); c0 = a; c4 = bb;
        a = min(c1,c5); bb = max(c1,c5); c1 = a; c5 = bb;
        a = min(c2,c6); bb = max(c2,c6); c2 = a; c6 = bb;
        a = min(c3,c7); bb = max(c3,c7); c3 = a; c7 = bb;
        a = min(c0,c2); bb = max(c0,c2); c0 = a; c2 = bb;
        a = min(c1,c3); bb = max(c1,c3); c1 = a; c3 = bb;
        a = min(c4,c6); bb = max(c4,c6); c4 = a; c6 = bb;
        a = min(c5,c7); bb = max(c5,c7); c5 = a; c7 = bb;
        a = min(c0,c1); bb = max(c0,c1); c0 = a; c1 = bb;
        a = min(c2,c3); bb = max(c2,c3); c2 = a; c3 = bb;
        a = min(c4,c5); bb = max(c4,c5); c4 = a; c5 = bb;
        a = min(c6,c7); bb = max(c6,c7); c6 = a; c7 = bb;
        k8[0]=c0; k8[1]=c1; k8[2]=c2; k8[3]=c3; k8[4]=c4; k8[5]=c5; k8[6]=c6; k8[7]=c7;
    }

    {
        int n = base + (nl >> 5)*WWID + (nl & 31);
        u32 v0, v1;
        if      (lg == 0) { v0 = k8[0]; v1 = k8[1]; }
        else if (lg == 1) { v0 = k8[2]; v1 = k8[3]; }
        else if (lg == 2) { v0 = k8[4]; v1 = k8[5]; }
        else              { v0 = k8[6]; v1 = k8[7]; }
        u32* pk = partk + (long)chunk*8*NPIX + (long)(2*lg)*NPIX + n;
        pk[0]    = v0;
        pk[NPIX] = v1;
    }
}

// ---- ecc (fused chunk-merge): per-lane chunk list, shfl bitonic merge, rank mux ----
__global__ __launch_bounds__(128, 4) void ecc_kernel(const float* ws, const u32* partk,
                                                     const u16* vtb, u16* ubar) {
    const float* b0f = ws + OFF_B0;
    const float* bkf = ws + OFF_BK;
    const float* wkt = ws + OFF_WKT;
    const float* w0v = ws + OFF_W0V;
    const float* sqp = ws + OFF_SQP;

    __shared__ u16 th_s[128][50];

    int tid = threadIdx.x;
    int sb = (blockIdx.x & 7) * 200 + (blockIdx.x >> 3);
    int pix = tid >> 3, sh = tid & 7;
    int n = sb * 16 + pix;

    u32 k8[8];
    {
        const u32* pk = partk + (long)sh*8*NPIX + n;
        #pragma unroll
        for (int s = 0; s < 8; s++) k8[s] = pk[(long)s*NPIX];
    }
    #pragma unroll
    for (int st = 0; st < 3; st++) {
        int mk = 1 << st;
        u32 o[8];
        #pragma unroll
        for (int s = 0; s < 8; s++) o[s] = (u32)__shfl_xor((int)k8[s], mk, 64);
        u32 c0 = min(k8[0], o[7]);
        u32 c1 = min(k8[1], o[6]);
        u32 c2 = min(k8[2], o[5]);
        u32 c3 = min(k8[3], o[4]);
        u32 c4 = min(k8[4], o[3]);
        u32 c5 = min(k8[5], o[2]);
        u32 c6 = min(k8[6], o[1]);
        u32 c7 = min(k8[7], o[0]);
        u32 a, bb;
        a = min(c0,c4); bb = max(c0,c4); c0 = a; c4 = bb;
        a = min(c1,c5); bb = max(c1,c5); c1 = a; c5 = bb;
        a = min(c2,c6); bb = max(c2,c6); c2 = a; c6 = bb;
        a = min(c3,c7); bb = max(c3,c7); c3 = a; c7 = bb;
        a = min(c0,c2); bb = max(c0,c2); c0 = a; c2 = bb;
        a = min(c1,c3); bb = max(c1,c3); c1 = a; c3 = bb;
        a = min(c4,c6); bb = max(c4,c6); c4 = a; c6 = bb;
        a = min(c5,c7); bb = max(c5,c7); c5 = a; c7 = bb;
        a = min(c0,c1); bb = max(c0,c1); c0 = a; c1 = bb;
        a = min(c2,c3); bb = max(c2,c3); c2 = a; c3 = bb;
        a = min(c4,c5); bb = max(c4,c5); c4 = a; c5 = bb;
        a = min(c6,c7); bb = max(c6,c7); c6 = a; c7 = bb;
        k8[0]=c0; k8[1]=c1; k8[2]=c2; k8[3]=c3; k8[4]=c4; k8[5]=c5; k8[6]=c6; k8[7]=c7;
    }
    u32 key;
    {
        u32 m0 = (sh & 1) ? k8[1] : k8[0];
        u32 m1 = (sh & 1) ? k8[3] : k8[2];
        u32 m2 = (sh & 1) ? k8[5] : k8[4];
        u32 m3 = (sh & 1) ? k8[7] : k8[6];
        u32 n0 = (sh & 2) ? m1 : m0;
        u32 n1 = (sh & 2) ? m3 : m2;
        key = (sh & 4) ? n1 : n0;
    }
    int ml = (int)(key & 1023u);
    u32 uf = key & 0xFFFFFC00u;
    u32 uu = (uf & 0x80000000u) ? (uf ^ 0x80000000u) : ~uf;
    float d = __uint_as_float(uu);
    int y = n / WWID, x = n % WWID;
    int wy = (y >> 5) << 5, wx = (x >> 5) << 5;
    int m = (wy + (ml >> 5)) * WWID + (wx + (ml & 31));
    float gamma = expf(-(d + sqp[n]) * 0.1f);

    float th[48];
    {
        const float4* wm4 = (const float4*)(w0v + (long)m * 48);
        const float4* wn4 = (const float4*)(w0v + (long)n * 48);
        #pragma unroll
        for (int i = 0; i < 12; i++) {
            float4 a = wm4[i];
            float4 b = wn4[i];
            float x0 = a.x - b.x + b0f[4*i+0];
            float x1 = a.y - b.y + b0f[4*i+1];
            float x2 = a.z - b.z + b0f[4*i+2];
            float x3 = a.w - b.w + b0f[4*i+3];
            th[4*i+0] = (x0 >= 0.f) ? x0 : 0.01f * x0;
            th[4*i+1] = (x1 >= 0.f) ? x1 : 0.01f * x1;
            th[4*i+2] = (x2 >= 0.f) ? x2 : 0.01f * x2;
            th[4*i+3] = (x3 >= 0.f) ? x3 : 0.01f * x3;
        }
    }

    #pragma unroll
    for (int i = 0; i < 24; i++) {
        ushort2 pr;
        pr.x = f2bf(th[2*i]);
        pr.y = f2bf(th[2*i+1]);
        *(ushort2*)&th_s[tid][2*i] = pr;
    }

    float kap[12];
    #pragma unroll
    for (int r = 0; r < 12; r++) kap[r] = bkf[r];
    #pragma unroll
    for (int c = 0; c < 48; c++) {
        float t = th[c];
        const float* wkc = wkt + c*12;
        #pragma unroll
        for (int r = 0; r < 12; r++) kap[r] = fmaf(wkc[r], t, kap[r]);
    }

    float sr[12];
    #pragma unroll
    for (int r = 0; r < 12; r++) sr[r] = 0.f;
    const u16* vrow = vtb + (long)m * 192;
    #pragma unroll
    for (int j = 0; j < 24; j++) {
        uint4 vv = *(const uint4*)&vrow[j*8];
        #pragma unroll
        for (int half = 0; half < 2; half++) {
            int cp = 2*j + half;
            u32 w0_ = half ? vv.z : vv.x;
            u32 w1_ = half ? vv.w : vv.y;
            float vx = bf2f((u16)(w0_ & 0xffff));
            float vy = bf2f((u16)(w0_ >> 16));
            float vz = bf2f((u16)(w1_ & 0xffff));
            float vw = bf2f((u16)(w1_ >> 16));
            int i1 = (cp + 1 < 48) ? cp + 1 : cp - 47;
            int i2 = (cp + 2 < 48) ? cp + 2 : cp - 46;
            float t0 = th[cp], t1 = th[i1], t2 = th[i2];
            sr[0] = fmaf(t0, vx, sr[0]); sr[1]  = fmaf(t1, vx, sr[1]);  sr[2]  = fmaf(t2, vx, sr[2]);
            sr[3] = fmaf(t0, vy, sr[3]); sr[4]  = fmaf(t1, vy, sr[4]);  sr[5]  = fmaf(t2, vy, sr[5]);
            sr[6] = fmaf(t0, vz, sr[6]); sr[7]  = fmaf(t1, vz, sr[7]);  sr[8]  = fmaf(t2, vz, sr[8]);
            sr[9] = fmaf(t0, vw, sr[9]); sr[10] = fmaf(t1, vw, sr[10]); sr[11] = fmaf(t2, vw, sr[11]);
        }
    }

    float tmp[12];
    #pragma unroll
    for (int r = 0; r < 12; r++) tmp[r] = kap[r] * sr[r];

    __syncthreads();

    float acc0[6], acc1[6], acc2[6], acc3[6];
    #pragma unroll
    for (int j = 0; j < 6; j++) { acc0[j] = 0.f; acc1[j] = 0.f; acc2[j] = 0.f; acc3[j] = 0.f; }
    #pragma unroll 1
    for (int e = 0; e < 8; e++) {
        int srcl = (tid & 56) + e;
        int row  = (tid & 120) + e;
        float tm[12];
        #pragma unroll
        for (int r = 0; r < 12; r++) tm[r] = __shfl(tmp[r], srcl, 64);
        float ge = __shfl(gamma, srcl, 64);
        #pragma unroll
        for (int j = 0; j < 6; j++) {
            int cp = sh + 8*j;
            int i1 = (cp + 1 < 48) ? cp + 1 : cp - 47;
            int i2 = (cp + 2 < 48) ? cp + 2 : cp - 46;
            float t0 = bf2f(th_s[row][cp]);
            float t1 = bf2f(th_s[row][i1]);
            float t2 = bf2f(th_s[row][i2]);
            float u0 = tm[0]*t0 + tm[1]*t1 + tm[2]*t2;
            float u1 = tm[3]*t0 + tm[4]*t1 + tm[5]*t2;
            float u2 = tm[6]*t0 + tm[7]*t1 + tm[8]*t2;
            float u3 = tm[9]*t0 + tm[10]*t1 + tm[11]*t2;
            acc0[j] = fmaf(ge, u0, acc0[j]);
            acc1[j] = fmaf(ge, u1, acc1[j]);
            acc2[j] = fmaf(ge, u2, acc2[j]);
            acc3[j] = fmaf(ge, u3, acc3[j]);
        }
    }
    u16* ub = ubar + (long)n * 192;
    #pragma unroll
    for (int j = 0; j < 6; j++) {
        int cp = sh + 8*j;
        ushort4 st;
        st.x = f2bf(acc0[j]); st.y = f2bf(acc1[j]);
        st.z = f2bf(acc2[j]); st.w = f2bf(acc3[j]);
        *(ushort4*)&ub[cp*4] = st;
    }
}

// ---- wl: 64 pixels x 8 wave-uniform 6-output groups (512 thr); writes 0.5*hNL ----
__global__ __launch_bounds__(512) void wl_kernel(const float* ws, const u16* ubar, float* outp) {
    const float* wlt = ws + OFF_WLT;
    int tid = threadIdx.x;
    int p = blockIdx.x * 64 + (tid & 63);
    int ob = (tid >> 6) * 6;
    const u16* ub = ubar + (long)p * 192;
    float out[6];
    #pragma unroll
    for (int o = 0; o < 6; o++) out[o] = 0.f;
    for (int j = 0; j < 24; j++) {
        uint4 vv = *(const uint4*)&ub[j*8];
        #pragma unroll
        for (int half = 0; half < 2; half++) {
            int cp = 2*j + half;
            u32 a_ = half ? vv.z : vv.x;
            u32 b_ = half ? vv.w : vv.y;
            float ux = bf2f((u16)(a_ & 0xffff));
            float uy = bf2f((u16)(a_ >> 16));
            float uz = bf2f((u16)(b_ & 0xffff));
            float uw = bf2f((u16)(b_ >> 16));
            const float* wl = wlt + cp * 192 + ob * 4;
            #pragma unroll
            for (int o = 0; o < 6; o++) {
                float a = out[o];
                a = fmaf(wl[4*o+0], ux, a);
                a = fmaf(wl[4*o+1], uy, a);
                a = fmaf(wl[4*o+2], uz, a);
                a = fmaf(wl[4*o+3], uw, a);
                out[o] = a;
            }
        }
    }
    #pragma unroll
    for (int o = 0; o < 6; o++) outp[(ob + o)*NPIX + p] = 0.0625f * out[o];
}

// ---- conv 3x3 (reflect pad), OCH=4/thread, XCD-chunked swizzle, adds 0.5*hL + bias ----
#define OCH 4
__global__ __launch_bounds__(320) void conv_kernel(const float* h, const float* wc,
                                                   const float* bias, float* outp) {
    int sb = (blockIdx.x & 7) * 120 + (blockIdx.x >> 3);
    int og = sb % 12;
    int yp = sb / 12;
    int t  = threadIdx.x;
    int ty = t / 160;
    int x  = t % 160;
    int y  = yp * 2 + ty;

    int idx9[9];
    #pragma unroll
    for (int dy = 0; dy < 3; dy++) {
        int yy = y + dy - 1;
        yy = yy < 0 ? -yy : (yy >= HH ? 2*HH - 2 - yy : yy);
        #pragma unroll
        for (int dx = 0; dx < 3; dx++) {
            int xx = x + dx - 1;
            xx = xx < 0 ? -xx : (xx >= WWID ? 2*WWID - 2 - xx : xx);
            idx9[dy*3 + dx] = yy * WWID + xx;
        }
    }

    float acc[OCH];
    #pragma unroll
    for (int oi = 0; oi < OCH; oi++) acc[oi] = 0.f;

    const float* wbase = wc + og * OCH * 432;
    for (int c = 0; c < 48; c++) {
        float v[9];
        #pragma unroll
        for (int k = 0; k < 9; k++) v[k] = h[c*NPIX + idx9[k]];
        #pragma unroll
        for (int oi = 0; oi < OCH; oi++) {
            const float* w9 = wbase + oi*432 + c*9;
            float a = acc[oi];
            a = fmaf(v[0], w9[0], a);
            a = fmaf(v[1], w9[1], a);
            a = fmaf(v[2], w9[2], a);
            a = fmaf(v[3], w9[3], a);
            a = fmaf(v[4], w9[4], a);
            a = fmaf(v[5], w9[5], a);
            a = fmaf(v[6], w9[6], a);
            a = fmaf(v[7], w9[7], a);
            a = fmaf(v[8], w9[8], a);
            acc[oi] = a;
        }
    }

    int p = y * WWID + x;
    #pragma unroll
    for (int oi = 0; oi < OCH; oi++) {
        int o = og * OCH + oi;
        outp[o*NPIX + p] = outp[o*NPIX + p] + 0.5f * acc[oi] + bias[o];
    }
}

extern "C" void kernel_launch(void* const* d_in, const int* in_sizes, int n_in,
                              void* d_out, int out_size, void* d_ws, size_t ws_size,
                              hipStream_t stream) {
    const float* h    = (const float*)d_in[0];
    const float* W0   = (const float*)d_in[1];
    const float* b0   = (const float*)d_in[2];
    const float* WL   = (const float*)d_in[3];
    const float* WR   = (const float*)d_in[4];
    const float* Wk   = (const float*)d_in[5];
    const float* bk   = (const float*)d_in[6];
    const float* Wc   = (const float*)d_in[7];
    const float* bias = (const float*)d_in[8];

    float* ws     = (float*)d_ws;
    float* sqp    = ws + OFF_SQP;
    float* w0v    = ws + OFF_W0V;
    u16*   vtb    = (u16*)(ws + OFF_VTB);
    u16*   hht    = (u16*)(ws + OFF_HHT);
    u16*   hlt    = (u16*)(ws + OFF_HLT);
    u32*   partk  = (u32*)(ws + OFF_PARTK);
    u16*   ubar   = (u16*)(ws + OFF_UBAR);
    float* outp   = (float*)d_out;

    prep_kernel<<<dim3(16), dim3(256), 0, stream>>>(W0, b0, WL, WR, Wk, bk, ws);
    split_kernel<<<dim3(100), dim3(256), 0, stream>>>(h, sqp, hht, hlt);
    topk_mfma<<<dim3(1600), dim3(512), 0, stream>>>(hht, hlt, sqp, partk);
    pixvt_mfma<<<dim3(400), dim3(512), 0, stream>>>(hht, hlt, ws, w0v, vtb);
    ecc_kernel<<<dim3(1600), dim3(128), 0, stream>>>(ws, partk, vtb, ubar);
    wl_kernel<<<dim3(400), dim3(512), 0, stream>>>(ws, ubar, outp);
    conv_kernel<<<dim3(960), dim3(320), 0, stream>>>(h, Wc, bias, outp);
}

// Round 16
// 144.873 us; speedup vs baseline: 4.6917x; 1.2251x over previous
//
#include <hip/hip_runtime.h>

#define CC    48
#define HH    160
#define WWID  160
#define NPIX  25600
#define KK    8

typedef unsigned short u16;
typedef unsigned int u32;
typedef __attribute__((ext_vector_type(8))) short bf16x8;
typedef __attribute__((ext_vector_type(4))) float f32x4;

__device__ __forceinline__ float bf2f(u16 u) {
    return __uint_as_float(((unsigned int)u) << 16);
}
__device__ __forceinline__ u16 f2bf(float f) {
    unsigned int x = __float_as_uint(f);
    return (u16)((x + 0x7FFFu + ((x >> 16) & 1u)) >> 16);
}

// ws float-offset layout — non-aliased, high-water 36.1 MB
#define OFF_B0    0        // 48
#define OFF_BK    48       // 12
#define OFF_WKT   60       // 576     wkt[c*12+r] = Wk[r][c]
#define OFF_WBH   636      // u16[256*64]: pixvt combined weight bf16-hi (8192 f)
#define OFF_WBL   8828     // u16[256*64]: bf16-lo (8192 f)
#define OFF_WLH   17020    // u16[48*192]: WL' bf16-hi (4608 f)
#define OFF_WLL   21628    // u16[48*192]: WL' bf16-lo (4608 f)
#define OFF_SQP   26236    // 25600
#define OFF_W0V   51836    // float[25600*48]
#define OFF_VTB   1280636  // u16[25600*192]
#define OFF_HHT   3738236  // u16[25600*64]
#define OFF_HLT   4557436  // u16[25600*64]
#define OFF_PARTK 5376636  // u32[8][8][NPIX]
#define OFF_UBAR  7015036  // u16[25600*192] -> ends 9472636

__global__ void prep_kernel(const float* W0, const float* b0, const float* WL,
                            const float* WR, const float* Wk, const float* bk,
                            float* ws) {
    float* b0f = ws + OFF_B0;
    float* bkf = ws + OFF_BK;
    float* wkt = ws + OFF_WKT;
    u16*   wbh = (u16*)(ws + OFF_WBH);
    u16*   wbl = (u16*)(ws + OFF_WBL);
    u16*   wlh = (u16*)(ws + OFF_WLH);
    u16*   wll = (u16*)(ws + OFF_WLL);
    int t = blockIdx.x * 256 + threadIdx.x;
    int stride = gridDim.x * 256;
    // pixvt combined B: cols 0..191 = VT (WR[(4k+q)*48+cp]), 192..239 = W0 rows, else 0
    for (int i = t; i < 16384; i += stride) {
        int col = i >> 6, k = i & 63;
        float v = 0.f;
        if (k < 48) {
            if (col < 192)      v = WR[(4*k + (col & 3))*48 + (col >> 2)];
            else if (col < 240) v = W0[(col - 192)*48 + k];
        }
        u16 hi = f2bf(v);
        wbh[i] = hi;
        wbl[i] = f2bf(v - bf2f(hi));
    }
    // wl B: wlh[o*192 + k] = WL[(4o + (k&3))*48 + (k>>2)]
    for (int i = t; i < 9216; i += stride) {
        int o = i / 192, k = i % 192;
        float v = WL[(4*o + (k & 3))*48 + (k >> 2)];
        u16 hi = f2bf(v);
        wlh[i] = hi;
        wll[i] = f2bf(v - bf2f(hi));
    }
    for (int i = t; i < 576; i += stride) { int c = i / 12, r = i % 12; wkt[i] = Wk[r*48 + c]; }
    for (int i = t; i < 48; i += stride) { b0f[i] = b0[i]; }
    for (int i = t; i < 12; i += stride) { bkf[i] = bk[i]; }
}

// per-pixel: sq + bf16 hi/lo split rows (contiguous 128 B/row writes)
__global__ __launch_bounds__(256) void split_kernel(const float* h, float* sqp,
                                                    u16* hht, u16* hlt) {
    int p = blockIdx.x * 256 + threadIdx.x;
    float sq = 0.f;
    u16 hh[64], hl[64];
    #pragma unroll
    for (int c = 0; c < 48; c++) {
        float v = h[c*NPIX + p];
        sq = fmaf(v, v, sq);
        u16 hi = f2bf(v);
        hh[c] = hi;
        hl[c] = f2bf(v - bf2f(hi));
    }
    #pragma unroll
    for (int c = 48; c < 64; c++) { hh[c] = 0; hl[c] = 0; }
    sqp[p] = sq;
    uint4* dh = (uint4*)&hht[(long)p*64];
    uint4* dl = (uint4*)&hlt[(long)p*64];
    const uint4* s1 = (const uint4*)hh;
    const uint4* s2 = (const uint4*)hl;
    #pragma unroll
    for (int i = 0; i < 8; i++) { dh[i] = s1[i]; dl[i] = s2[i]; }
}

// ---- pixvt via MFMA: per block 64 px x 256 weight-cols (192 VT bf16 + 48 W0V f32) ----
__global__ __launch_bounds__(512) void pixvt_mfma(const u16* hht, const u16* hlt,
                                                  const float* ws, float* w0v, u16* vtb) {
    __shared__ __align__(16) char smem[38912];
    u16*   a_hi = (u16*)smem;              // [64][64] (phase 1)
    u16*   a_lo = (u16*)(smem + 8192);
    u16*   vt_s = (u16*)smem;              // [64][200] u16 (phase 2)
    float* w0_s = (float*)(smem + 25600);  // [64][52]  f32

    const u16* wbh = (const u16*)(ws + OFF_WBH);
    const u16* wbl = (const u16*)(ws + OFF_WBL);

    int tid = threadIdx.x;
    int pbase = blockIdx.x * 64;

    {
        int blk = tid >> 6, row = tid & 63;
        int swz = (blk ^ (row & 7)) * 8;
        *(uint4*)&a_hi[row*64 + swz] = *(const uint4*)&hht[(long)(pbase + row)*64 + blk*8];
        *(uint4*)&a_lo[row*64 + swz] = *(const uint4*)&hlt[(long)(pbase + row)*64 + blk*8];
    }
    __syncthreads();

    int w = tid >> 6, lane = tid & 63;
    int lm = lane & 15, lg = lane >> 4;
    int c2a = 2*w, c2b = 2*w + 1;

    f32x4 acc0[4], acc1[4];
    #pragma unroll
    for (int t = 0; t < 4; t++) { acc0[t] = (f32x4){0.f,0.f,0.f,0.f}; acc1[t] = (f32x4){0.f,0.f,0.f,0.f}; }

    #pragma unroll
    for (int s = 0; s < 2; s++) {
        int lblk = 4*s + lg;
        int aswz = (lblk ^ (lm & 7)) * 8;
        bf16x8 ah0 = *(const bf16x8*)&a_hi[( 0 + lm)*64 + aswz];
        bf16x8 ah1 = *(const bf16x8*)&a_hi[(16 + lm)*64 + aswz];
        bf16x8 ah2 = *(const bf16x8*)&a_hi[(32 + lm)*64 + aswz];
        bf16x8 ah3 = *(const bf16x8*)&a_hi[(48 + lm)*64 + aswz];
        bf16x8 al0 = *(const bf16x8*)&a_lo[( 0 + lm)*64 + aswz];
        bf16x8 al1 = *(const bf16x8*)&a_lo[(16 + lm)*64 + aswz];
        bf16x8 al2 = *(const bf16x8*)&a_lo[(32 + lm)*64 + aswz];
        bf16x8 al3 = *(const bf16x8*)&a_lo[(48 + lm)*64 + aswz];
        {
            int col = c2a*16 + lm;
            bf16x8 bh = *(const bf16x8*)&wbh[col*64 + lblk*8];
            bf16x8 bl = *(const bf16x8*)&wbl[col*64 + lblk*8];
            acc0[0] = __builtin_amdgcn_mfma_f32_16x16x32_bf16(ah0, bh, acc0[0], 0, 0, 0);
            acc0[0] = __builtin_amdgcn_mfma_f32_16x16x32_bf16(ah0, bl, acc0[0], 0, 0, 0);
            acc0[0] = __builtin_amdgcn_mfma_f32_16x16x32_bf16(al0, bh, acc0[0], 0, 0, 0);
            acc0[1] = __builtin_amdgcn_mfma_f32_16x16x32_bf16(ah1, bh, acc0[1], 0, 0, 0);
            acc0[1] = __builtin_amdgcn_mfma_f32_16x16x32_bf16(ah1, bl, acc0[1], 0, 0, 0);
            acc0[1] = __builtin_amdgcn_mfma_f32_16x16x32_bf16(al1, bh, acc0[1], 0, 0, 0);
            acc0[2] = __builtin_amdgcn_mfma_f32_16x16x32_bf16(ah2, bh, acc0[2], 0, 0, 0);
            acc0[2] = __builtin_amdgcn_mfma_f32_16x16x32_bf16(ah2, bl, acc0[2], 0, 0, 0);
            acc0[2] = __builtin_amdgcn_mfma_f32_16x16x32_bf16(al2, bh, acc0[2], 0, 0, 0);
            acc0[3] = __builtin_amdgcn_mfma_f32_16x16x32_bf16(ah3, bh, acc0[3], 0, 0, 0);
            acc0[3] = __builtin_amdgcn_mfma_f32_16x16x32_bf16(ah3, bl, acc0[3], 0, 0, 0);
            acc0[3] = __builtin_amdgcn_mfma_f32_16x16x32_bf16(al3, bh, acc0[3], 0, 0, 0);
        }
        if (c2b < 15) {
            int col = c2b*16 + lm;
            bf16x8 bh = *(const bf16x8*)&wbh[col*64 + lblk*8];
            bf16x8 bl = *(const bf16x8*)&wbl[col*64 + lblk*8];
            acc1[0] = __builtin_amdgcn_mfma_f32_16x16x32_bf16(ah0, bh, acc1[0], 0, 0, 0);
            acc1[0] = __builtin_amdgcn_mfma_f32_16x16x32_bf16(ah0, bl, acc1[0], 0, 0, 0);
            acc1[0] = __builtin_amdgcn_mfma_f32_16x16x32_bf16(al0, bh, acc1[0], 0, 0, 0);
            acc1[1] = __builtin_amdgcn_mfma_f32_16x16x32_bf16(ah1, bh, acc1[1], 0, 0, 0);
            acc1[1] = __builtin_amdgcn_mfma_f32_16x16x32_bf16(ah1, bl, acc1[1], 0, 0, 0);
            acc1[1] = __builtin_amdgcn_mfma_f32_16x16x32_bf16(al1, bh, acc1[1], 0, 0, 0);
            acc1[2] = __builtin_amdgcn_mfma_f32_16x16x32_bf16(ah2, bh, acc1[2], 0, 0, 0);
            acc1[2] = __builtin_amdgcn_mfma_f32_16x16x32_bf16(ah2, bl, acc1[2], 0, 0, 0);
            acc1[2] = __builtin_amdgcn_mfma_f32_16x16x32_bf16(al2, bh, acc1[2], 0, 0, 0);
            acc1[3] = __builtin_amdgcn_mfma_f32_16x16x32_bf16(ah3, bh, acc1[3], 0, 0, 0);
            acc1[3] = __builtin_amdgcn_mfma_f32_16x16x32_bf16(ah3, bl, acc1[3], 0, 0, 0);
            acc1[3] = __builtin_amdgcn_mfma_f32_16x16x32_bf16(al3, bh, acc1[3], 0, 0, 0);
        }
    }
    __syncthreads();

    {
        int col = c2a*16 + lm;
        if (c2a < 12) {
            #pragma unroll
            for (int t = 0; t < 4; t++)
                #pragma unroll
                for (int r = 0; r < 4; r++)
                    vt_s[(t*16 + lg*4 + r)*200 + col] = f2bf(acc0[t][r]);
        } else {
            int o = col - 192;
            #pragma unroll
            for (int t = 0; t < 4; t++)
                #pragma unroll
                for (int r = 0; r < 4; r++)
                    w0_s[(t*16 + lg*4 + r)*52 + o] = acc0[t][r];
        }
    }
    if (c2b < 15) {
        int col = c2b*16 + lm;
        if (c2b < 12) {
            #pragma unroll
            for (int t = 0; t < 4; t++)
                #pragma unroll
                for (int r = 0; r < 4; r++)
                    vt_s[(t*16 + lg*4 + r)*200 + col] = f2bf(acc1[t][r]);
        } else {
            int o = col - 192;
            #pragma unroll
            for (int t = 0; t < 4; t++)
                #pragma unroll
                for (int r = 0; r < 4; r++)
                    w0_s[(t*16 + lg*4 + r)*52 + o] = acc1[t][r];
        }
    }
    __syncthreads();

    {
        int px = tid >> 3, c8 = tid & 7;
        #pragma unroll
        for (int j = 0; j < 3; j++) {
            int ch = c8 + 8*j;
            uint4 v = *(const uint4*)&vt_s[px*200 + ch*8];
            *(uint4*)&vtb[(long)(pbase + px)*192 + ch*8] = v;
        }
        float* dst = w0v + (long)(pbase + px)*48 + c8*6;
        const float* src = w0_s + px*52 + c8*6;
        #pragma unroll
        for (int k = 0; k < 3; k++) {
            float2 v2 = *(const float2*)&src[k*2];
            *(float2*)&dst[k*2] = v2;
        }
    }
}

// ---- topk stage 1 (MFMA Gram, packed-key bubble selection, XCD-swizzled) ----
__global__ __launch_bounds__(512, 8) void topk_mfma(const u16* hht, const u16* hlt,
                                                    const float* sqp, u32* partk) {
    __shared__ u16 ca_hi[128*64];
    __shared__ u16 ca_lo[128*64];
    __shared__ float sq_s[128];

    int tid = threadIdx.x;
    int b = (blockIdx.x & 7) * 200 + (blockIdx.x >> 3);
    int chunk = b & 7, pg = (b >> 3) & 7, win = b >> 6;
    int wi = win / 5, wj = win % 5;
    int base = wi*32*WWID + wj*32;

    #pragma unroll
    for (int r = 0; r < 2; r++) {
        int task = r*512 + tid;
        int blk = task >> 7, row = task & 127;
        int swz = (blk ^ (row & 7)) * 8;
        int ml = chunk*128 + row;
        long gp = base + (ml>>5)*WWID + (ml&31);
        *(uint4*)&ca_hi[row*64 + swz] = *(const uint4*)&hht[gp*64 + blk*8];
        *(uint4*)&ca_lo[row*64 + swz] = *(const uint4*)&hlt[gp*64 + blk*8];
    }
    if (tid < 128) {
        int ml = chunk*128 + tid;
        sq_s[tid] = sqp[base + (ml>>5)*WWID + (ml&31)];
    }
    __syncthreads();

    int w = tid >> 6, lane = tid & 63;
    int lm = lane & 15, lg = lane >> 4;

    int nl = pg*128 + w*16 + lm;
    long gpx = base + (nl>>5)*WWID + (nl&31);

    f32x4 acc[8];
    #pragma unroll
    for (int t = 0; t < 8; t++) acc[t] = (f32x4){0.f, 0.f, 0.f, 0.f};

    #pragma unroll
    for (int s = 0; s < 2; s++) {
        int lblk = 4*s + lg;
        int ko = lblk * 8;
        bf16x8 bh = *(const bf16x8*)&hht[gpx*64 + ko];
        bf16x8 bl = *(const bf16x8*)&hlt[gpx*64 + ko];
        #pragma unroll
        for (int t = 0; t < 8; t++) {
            int aoff = (t*16 + lm)*64 + (lblk ^ (lm & 7))*8;
            bf16x8 ah = *(const bf16x8*)&ca_hi[aoff];
            bf16x8 al = *(const bf16x8*)&ca_lo[aoff];
            acc[t] = __builtin_amdgcn_mfma_f32_16x16x32_bf16(ah, bh, acc[t], 0, 0, 0);
            acc[t] = __builtin_amdgcn_mfma_f32_16x16x32_bf16(ah, bl, acc[t], 0, 0, 0);
            acc[t] = __builtin_amdgcn_mfma_f32_16x16x32_bf16(al, bh, acc[t], 0, 0, 0);
        }
    }

    int rn = nl >> 5, cn = nl & 31;
    int rowok[8], colok[8];
    #pragma unroll
    for (int t = 0; t < 8; t++) {
        int rm = chunk*4 + (t >> 1);
        int dr = rn - rm; dr = dr < 0 ? -dr : dr;
        rowok[t] = (dr <= 1);
    }
    #pragma unroll
    for (int j = 0; j < 8; j++) {
        int cm = (j >> 2)*16 + lg*4 + (j & 3);
        int dc = cn - cm; dc = dc < 0 ? -dc : dc;
        colok[j] = (dc <= 1);
    }

    u32 k8[8];
    #pragma unroll
    for (int s = 0; s < 8; s++) k8[s] = 0xFFFFFFFFu;

    #pragma unroll
    for (int t = 0; t < 8; t++) {
        #pragma unroll
        for (int r = 0; r < 4; r++) {
            int cl = t*16 + lg*4 + r;
            int ml = chunk*128 + cl;
            float d = fmaf(-2.0f, acc[t][r], sq_s[cl]);
            u32 u = __float_as_uint(d);
            u32 key = u ^ (0x80000000u | (u32)((int)u >> 31));
            key = (key & 0xFFFFFC00u) | (u32)ml;
            bool bad = rowok[t] && colok[(t & 1)*4 + r];
            key = bad ? 0xFFFFFFFFu : key;
            #pragma unroll
            for (int s = 0; s < 8; s++) {
                u32 lo = min(k8[s], key);
                u32 hi = max(k8[s], key);
                k8[s] = lo; key = hi;
            }
        }
    }

    #pragma unroll
    for (int st = 0; st < 2; st++) {
        int mk = (st == 0) ? 16 : 32;
        u32 o[8];
        #pragma unroll
        for (int s = 0; s < 8; s++) o[s] = (u32)__shfl_xor((int)k8[s], mk, 64);
        u32 c0 = min(k8[0], o[7]);
        u32 c1 = min(k8[1], o[6]);
        u32 c2 = min(k8[2], o[5]);
        u32 c3 = min(k8[3], o[4]);
        u32 c4 = min(k8[4], o[3]);
        u32 c5 = min(k8[5], o[2]);
        u32 c6 = min(k8[6], o[1]);
        u32 c7 = min(k8[7], o[0]);
        u32 a, bb;
        a = min(c0,c4); bb = max(c0,c4); c0 = a; c4 = bb;
        a = min(c1,c5); bb = max(c1,c5); c1 = a; c5 = bb;
        a = min(c2,c6); bb = max(c2,c6); c2 = a; c6 = bb;
        a = min(c3,c7); bb = max(c3,c7); c3 = a; c7 = bb;
        a = min(c0,c2); bb = max(c0,c2); c0 = a; c2 = bb;
        a = min(c1,c3); bb = max(c1,c3); c1 = a; c3 = bb;
        a = min(c4,c6); bb = max(c4,c6); c4 = a; c6 = bb;
        a = min(c5,c7); bb = max(c5,c7); c5 = a; c7 = bb;
        a = min(c0,c1); bb = max(c0,c1); c0 = a; c1 = bb;
        a = min(c2,c3); bb = max(c2,c3); c2 = a; c3 = bb;
        a = min(c4,c5); bb = max(c4,c5); c4 = a; c5 = bb;
        a = min(c6,c7); bb = max(c6,c7); c6 = a; c7 = bb;
        k8[0]=c0; k8[1]=c1; k8[2]=c2; k8[3]=c3; k8[4]=c4; k8[5]=c5; k8[6]=c6; k8[7]=c7;
    }

    {
        int n = base + (nl >> 5)*WWID + (nl & 31);
        u32 v0, v1;
        if      (lg == 0) { v0 = k8[0]; v1 = k8[1]; }
        else if (lg == 1) { v0 = k8[2]; v1 = k8[3]; }
        else if (lg == 2) { v0 = k8[4]; v1 = k8[5]; }
        else              { v0 = k8[6]; v1 = k8[7]; }
        u32* pk = partk + (long)chunk*8*NPIX + (long)(2*lg)*NPIX + n;
        pk[0]    = v0;
        pk[NPIX] = v1;
    }
}

// ---- ecc (fused chunk-merge): per-lane chunk list, shfl bitonic merge, rank mux ----
__global__ __launch_bounds__(128, 4) void ecc_kernel(const float* ws, const u32* partk,
                                                     const u16* vtb, u16* ubar) {
    const float* b0f = ws + OFF_B0;
    const float* bkf = ws + OFF_BK;
    const float* wkt = ws + OFF_WKT;
    const float* w0v = ws + OFF_W0V;
    const float* sqp = ws + OFF_SQP;

    __shared__ u16 th_s[128][50];

    int tid = threadIdx.x;
    int sb = (blockIdx.x & 7) * 200 + (blockIdx.x >> 3);
    int pix = tid >> 3, sh = tid & 7;
    int n = sb * 16 + pix;

    u32 k8[8];
    {
        const u32* pk = partk + (long)sh*8*NPIX + n;
        #pragma unroll
        for (int s = 0; s < 8; s++) k8[s] = pk[(long)s*NPIX];
    }
    #pragma unroll
    for (int st = 0; st < 3; st++) {
        int mk = 1 << st;
        u32 o[8];
        #pragma unroll
        for (int s = 0; s < 8; s++) o[s] = (u32)__shfl_xor((int)k8[s], mk, 64);
        u32 c0 = min(k8[0], o[7]);
        u32 c1 = min(k8[1], o[6]);
        u32 c2 = min(k8[2], o[5]);
        u32 c3 = min(k8[3], o[4]);
        u32 c4 = min(k8[4], o[3]);
        u32 c5 = min(k8[5], o[2]);
        u32 c6 = min(k8[6], o[1]);
        u32 c7 = min(k8[7], o[0]);
        u32 a, bb;
        a = min(c0,c4); bb = max(c0,c4); c0 = a; c4 = bb;
        a = min(c1,c5); bb = max(c1,c5); c1 = a; c5 = bb;
        a = min(c2,c6); bb = max(c2,c6); c2 = a; c6 = bb;
        a = min(c3,c7); bb = max(c3,c7); c3 = a; c7 = bb;
        a = min(c0,c2); bb = max(c0,c2); c0 = a; c2 = bb;
        a = min(c1,c3); bb = max(c1,c3); c1 = a; c3 = bb;
        a = min(c4,c6); bb = max(c4,c6); c4 = a; c6 = bb;
        a = min(c5,c7); bb = max(c5,c7); c5 = a; c7 = bb;
        a = min(c0,c1); bb = max(c0,c1); c0 = a; c1 = bb;
        a = min(c2,c3); bb = max(c2,c3); c2 = a; c3 = bb;
        a = min(c4,c5); bb = max(c4,c5); c4 = a; c5 = bb;
        a = min(c6,c7); bb = max(c6,c7); c6 = a; c7 = bb;
        k8[0]=c0; k8[1]=c1; k8[2]=c2; k8[3]=c3; k8[4]=c4; k8[5]=c5; k8[6]=c6; k8[7]=c7;
    }
    u32 key;
    {
        u32 m0 = (sh & 1) ? k8[1] : k8[0];
        u32 m1 = (sh & 1) ? k8[3] : k8[2];
        u32 m2 = (sh & 1) ? k8[5] : k8[4];
        u32 m3 = (sh & 1) ? k8[7] : k8[6];
        u32 n0 = (sh & 2) ? m1 : m0;
        u32 n1 = (sh & 2) ? m3 : m2;
        key = (sh & 4) ? n1 : n0;
    }
    int ml = (int)(key & 1023u);
    u32 uf = key & 0xFFFFFC00u;
    u32 uu = (uf & 0x80000000u) ? (uf ^ 0x80000000u) : ~uf;
    float d = __uint_as_float(uu);
    int y = n / WWID, x = n % WWID;
    int wy = (y >> 5) << 5, wx = (x >> 5) << 5;
    int m = (wy + (ml >> 5)) * WWID + (wx + (ml & 31));
    float gamma = expf(-(d + sqp[n]) * 0.1f);

    float th[48];
    {
        const float4* wm4 = (const float4*)(w0v + (long)m * 48);
        const float4* wn4 = (const float4*)(w0v + (long)n * 48);
        #pragma unroll
        for (int i = 0; i < 12; i++) {
            float4 a = wm4[i];
            float4 b = wn4[i];
            float x0 = a.x - b.x + b0f[4*i+0];
            float x1 = a.y - b.y + b0f[4*i+1];
            float x2 = a.z - b.z + b0f[4*i+2];
            float x3 = a.w - b.w + b0f[4*i+3];
            th[4*i+0] = (x0 >= 0.f) ? x0 : 0.01f * x0;
            th[4*i+1] = (x1 >= 0.f) ? x1 : 0.01f * x1;
            th[4*i+2] = (x2 >= 0.f) ? x2 : 0.01f * x2;
            th[4*i+3] = (x3 >= 0.f) ? x3 : 0.01f * x3;
        }
    }

    #pragma unroll
    for (int i = 0; i < 24; i++) {
        ushort2 pr;
        pr.x = f2bf(th[2*i]);
        pr.y = f2bf(th[2*i+1]);
        *(ushort2*)&th_s[tid][2*i] = pr;
    }

    float kap[12];
    #pragma unroll
    for (int r = 0; r < 12; r++) kap[r] = bkf[r];
    #pragma unroll
    for (int c = 0; c < 48; c++) {
        float t = th[c];
        const float* wkc = wkt + c*12;
        #pragma unroll
        for (int r = 0; r < 12; r++) kap[r] = fmaf(wkc[r], t, kap[r]);
    }

    float sr[12];
    #pragma unroll
    for (int r = 0; r < 12; r++) sr[r] = 0.f;
    const u16* vrow = vtb + (long)m * 192;
    #pragma unroll
    for (int j = 0; j < 24; j++) {
        uint4 vv = *(const uint4*)&vrow[j*8];
        #pragma unroll
        for (int half = 0; half < 2; half++) {
            int cp = 2*j + half;
            u32 w0_ = half ? vv.z : vv.x;
            u32 w1_ = half ? vv.w : vv.y;
            float vx = bf2f((u16)(w0_ & 0xffff));
            float vy = bf2f((u16)(w0_ >> 16));
            float vz = bf2f((u16)(w1_ & 0xffff));
            float vw = bf2f((u16)(w1_ >> 16));
            int i1 = (cp + 1 < 48) ? cp + 1 : cp - 47;
            int i2 = (cp + 2 < 48) ? cp + 2 : cp - 46;
            float t0 = th[cp], t1 = th[i1], t2 = th[i2];
            sr[0] = fmaf(t0, vx, sr[0]); sr[1]  = fmaf(t1, vx, sr[1]);  sr[2]  = fmaf(t2, vx, sr[2]);
            sr[3] = fmaf(t0, vy, sr[3]); sr[4]  = fmaf(t1, vy, sr[4]);  sr[5]  = fmaf(t2, vy, sr[5]);
            sr[6] = fmaf(t0, vz, sr[6]); sr[7]  = fmaf(t1, vz, sr[7]);  sr[8]  = fmaf(t2, vz, sr[8]);
            sr[9] = fmaf(t0, vw, sr[9]); sr[10] = fmaf(t1, vw, sr[10]); sr[11] = fmaf(t2, vw, sr[11]);
        }
    }

    float tmp[12];
    #pragma unroll
    for (int r = 0; r < 12; r++) tmp[r] = kap[r] * sr[r];

    __syncthreads();

    float acc0[6], acc1[6], acc2[6], acc3[6];
    #pragma unroll
    for (int j = 0; j < 6; j++) { acc0[j] = 0.f; acc1[j] = 0.f; acc2[j] = 0.f; acc3[j] = 0.f; }
    #pragma unroll 1
    for (int e = 0; e < 8; e++) {
        int srcl = (tid & 56) + e;
        int row  = (tid & 120) + e;
        float tm[12];
        #pragma unroll
        for (int r = 0; r < 12; r++) tm[r] = __shfl(tmp[r], srcl, 64);
        float ge = __shfl(gamma, srcl, 64);
        #pragma unroll
        for (int j = 0; j < 6; j++) {
            int cp = sh + 8*j;
            int i1 = (cp + 1 < 48) ? cp + 1 : cp - 47;
            int i2 = (cp + 2 < 48) ? cp + 2 : cp - 46;
            float t0 = bf2f(th_s[row][cp]);
            float t1 = bf2f(th_s[row][i1]);
            float t2 = bf2f(th_s[row][i2]);
            float u0 = tm[0]*t0 + tm[1]*t1 + tm[2]*t2;
            float u1 = tm[3]*t0 + tm[4]*t1 + tm[5]*t2;
            float u2 = tm[6]*t0 + tm[7]*t1 + tm[8]*t2;
            float u3 = tm[9]*t0 + tm[10]*t1 + tm[11]*t2;
            acc0[j] = fmaf(ge, u0, acc0[j]);
            acc1[j] = fmaf(ge, u1, acc1[j]);
            acc2[j] = fmaf(ge, u2, acc2[j]);
            acc3[j] = fmaf(ge, u3, acc3[j]);
        }
    }
    u16* ub = ubar + (long)n * 192;
    #pragma unroll
    for (int j = 0; j < 6; j++) {
        int cp = sh + 8*j;
        ushort4 st;
        st.x = f2bf(acc0[j]); st.y = f2bf(acc1[j]);
        st.z = f2bf(acc2[j]); st.w = f2bf(acc3[j]);
        *(ushort4*)&ub[cp*4] = st;
    }
}

// ---- wl via MFMA: out[48 x NPIX] = WL'[48 x 192] . Ubar^T; 64 px per block ----
__global__ __launch_bounds__(256) void wl_mfma(const float* ws, const u16* ubar, float* outp) {
    __shared__ __align__(16) char smem[25600];
    u16*   a_s = (u16*)smem;          // [64][200] u16 (phase 1)
    float* c_s = (float*)smem;        // [48][68] f32 (phase 2, 13056 B)

    const u16* wlh = (const u16*)(ws + OFF_WLH);
    const u16* wll = (const u16*)(ws + OFF_WLL);

    int tid = threadIdx.x;
    int pbase = blockIdx.x * 64;

    // stage A: 64 px x 192 u16, coalesced uint4 chunks
    #pragma unroll
    for (int i = 0; i < 6; i++) {
        int task = i*256 + tid;
        int px = task / 24, ch = task % 24;
        *(uint4*)&a_s[px*200 + ch*8] = *(const uint4*)&ubar[(long)(pbase + px)*192 + ch*8];
    }
    __syncthreads();

    int w = tid >> 6, lane = tid & 63;
    int lm = lane & 15, lg = lane >> 4;

    f32x4 acc[3];
    #pragma unroll
    for (int t = 0; t < 3; t++) acc[t] = (f32x4){0.f, 0.f, 0.f, 0.f};

    #pragma unroll
    for (int ks = 0; ks < 6; ks++) {
        bf16x8 a = *(const bf16x8*)&a_s[(w*16 + lm)*200 + ks*32 + lg*8];
        #pragma unroll
        for (int ct = 0; ct < 3; ct++) {
            int col = ct*16 + lm;
            bf16x8 bh = *(const bf16x8*)&wlh[col*192 + ks*32 + lg*8];
            bf16x8 bl = *(const bf16x8*)&wll[col*192 + ks*32 + lg*8];
            acc[ct] = __builtin_amdgcn_mfma_f32_16x16x32_bf16(a, bh, acc[ct], 0, 0, 0);
            acc[ct] = __builtin_amdgcn_mfma_f32_16x16x32_bf16(a, bl, acc[ct], 0, 0, 0);
        }
    }
    __syncthreads();   // a_s dead; re-purpose as c_s

    // C: col = o (ct*16+lm), row = px (w*16 + lg*4 + r); stage [o][px] for coalesced out
    #pragma unroll
    for (int ct = 0; ct < 3; ct++) {
        int o = ct*16 + lm;
        #pragma unroll
        for (int r = 0; r < 4; r++)
            c_s[o*68 + w*16 + lg*4 + r] = 0.0625f * acc[ct][r];   // 0.5 * (1/8)
    }
    __syncthreads();

    // write out: 48 x 64 floats, coalesced 64-px rows
    #pragma unroll
    for (int j = 0; j < 12; j++) {
        int idx = j*256 + tid;
        int o = idx >> 6, px = idx & 63;
        outp[(long)o*NPIX + pbase + px] = c_s[o*68 + px];
    }
}

// ---- conv 3x3 (reflect pad), OCH=4/thread, XCD-chunked swizzle, adds 0.5*hL + bias ----
#define OCH 4
__global__ __launch_bounds__(320) void conv_kernel(const float* h, const float* wc,
                                                   const float* bias, float* outp) {
    int sb = (blockIdx.x & 7) * 120 + (blockIdx.x >> 3);
    int og = sb % 12;
    int yp = sb / 12;
    int t  = threadIdx.x;
    int ty = t / 160;
    int x  = t % 160;
    int y  = yp * 2 + ty;

    int idx9[9];
    #pragma unroll
    for (int dy = 0; dy < 3; dy++) {
        int yy = y + dy - 1;
        yy = yy < 0 ? -yy : (yy >= HH ? 2*HH - 2 - yy : yy);
        #pragma unroll
        for (int dx = 0; dx < 3; dx++) {
            int xx = x + dx - 1;
            xx = xx < 0 ? -xx : (xx >= WWID ? 2*WWID - 2 - xx : xx);
            idx9[dy*3 + dx] = yy * WWID + xx;
        }
    }

    float acc[OCH];
    #pragma unroll
    for (int oi = 0; oi < OCH; oi++) acc[oi] = 0.f;

    const float* wbase = wc + og * OCH * 432;
    for (int c = 0; c < 48; c++) {
        float v[9];
        #pragma unroll
        for (int k = 0; k < 9; k++) v[k] = h[c*NPIX + idx9[k]];
        #pragma unroll
        for (int oi = 0; oi < OCH; oi++) {
            const float* w9 = wbase + oi*432 + c*9;
            float a = acc[oi];
            a = fmaf(v[0], w9[0], a);
            a = fmaf(v[1], w9[1], a);
            a = fmaf(v[2], w9[2], a);
            a = fmaf(v[3], w9[3], a);
            a = fmaf(v[4], w9[4], a);
            a = fmaf(v[5], w9[5], a);
            a = fmaf(v[6], w9[6], a);
            a = fmaf(v[7], w9[7], a);
            a = fmaf(v[8], w9[8], a);
            acc[oi] = a;
        }
    }

    int p = y * WWID + x;
    #pragma unroll
    for (int oi = 0; oi < OCH; oi++) {
        int o = og * OCH + oi;
        outp[o*NPIX + p] = outp[o*NPIX + p] + 0.5f * acc[oi] + bias[o];
    }
}

extern "C" void kernel_launch(void* const* d_in, const int* in_sizes, int n_in,
                              void* d_out, int out_size, void* d_ws, size_t ws_size,
                              hipStream_t stream) {
    const float* h    = (const float*)d_in[0];
    const float* W0   = (const float*)d_in[1];
    const float* b0   = (const float*)d_in[2];
    const float* WL   = (const float*)d_in[3];
    const float* WR   = (const float*)d_in[4];
    const float* Wk   = (const float*)d_in[5];
    const float* bk   = (const float*)d_in[6];
    const float* Wc   = (const float*)d_in[7];
    const float* bias = (const float*)d_in[8];

    float* ws     = (float*)d_ws;
    float* sqp    = ws + OFF_SQP;
    float* w0v    = ws + OFF_W0V;
    u16*   vtb    = (u16*)(ws + OFF_VTB);
    u16*   hht    = (u16*)(ws + OFF_HHT);
    u16*   hlt    = (u16*)(ws + OFF_HLT);
    u32*   partk  = (u32*)(ws + OFF_PARTK);
    u16*   ubar   = (u16*)(ws + OFF_UBAR);
    float* outp   = (float*)d_out;

    prep_kernel<<<dim3(16), dim3(256), 0, stream>>>(W0, b0, WL, WR, Wk, bk, ws);
    split_kernel<<<dim3(100), dim3(256), 0, stream>>>(h, sqp, hht, hlt);
    topk_mfma<<<dim3(1600), dim3(512), 0, stream>>>(hht, hlt, sqp, partk);
    pixvt_mfma<<<dim3(400), dim3(512), 0, stream>>>(hht, hlt, ws, w0v, vtb);
    ecc_kernel<<<dim3(1600), dim3(128), 0, stream>>>(ws, partk, vtb, ubar);
    wl_mfma<<<dim3(400), dim3(256), 0, stream>>>(ws, ubar, outp);
    conv_kernel<<<dim3(960), dim3(320), 0, stream>>>(h, Wc, bias, outp);
}